// Round 3
// baseline (1952.616 us; speedup 1.0000x reference)
//
#include <hip/hip_runtime.h>
#include <math.h>

// Problem dims (fixed by reference)
#define BB   64
#define SS   60
#define ENCD 1024
#define ED   512
#define HD   512
#define VD   32000
#define TT   20
#define KT   32   // fp32 GEMM k-tile

typedef unsigned short u16;
typedef __attribute__((ext_vector_type(8))) short short8v;   // 8 bf16 = 4 VGPR
typedef __attribute__((ext_vector_type(4))) float f32x4;

__device__ __forceinline__ u16 f2bf(float x) {   // RNE float->bf16
  unsigned int u = __float_as_uint(x);
  return (u16)((u + 0x7FFFu + ((u >> 16) & 1u)) >> 16);
}

// ---------------------------------------------------------------------------
// init: zero outputs[:,0,:] and h0/c0
// ---------------------------------------------------------------------------
__global__ __launch_bounds__(256) void init_kernel(float* __restrict__ out,
                                                   float* __restrict__ h,
                                                   float* __restrict__ c) {
  int i = blockIdx.x * 256 + threadIdx.x;
  if (i < BB * VD) {
    int b = i / VD, v = i - b * VD;
    out[(long)b * (TT * VD) + v] = 0.f;
  }
  if (i < BB * HD) { h[i] = 0.f; c[i] = 0.f; }
}

// ---------------------------------------------------------------------------
// Generic fp32 NT GEMM (proj / gates)
// ---------------------------------------------------------------------------
__global__ __launch_bounds__(256) void gemm_nt(
    const float* __restrict__ A, int lda,
    const float* __restrict__ Bw, int ldb,
    const float* __restrict__ bias,
    float* __restrict__ C, long ldc, long zstride,
    int kChunk) {
  __shared__ __align__(16) float As[KT][64];
  __shared__ __align__(16) float Ws[KT][64];
  const int tid = threadIdx.x;
  const int m0 = blockIdx.y * 64, n0 = blockIdx.x * 64;
  const int k0 = blockIdx.z * kChunk, k1 = k0 + kChunk;
  const int tm = tid & 15, tn = tid >> 4;
  const int lr = tid >> 3;
  const int lk = (tid & 7) * 4;
  float acc[4][4] = {};
  for (int kt = k0; kt < k1; kt += KT) {
    __syncthreads();
    #pragma unroll
    for (int p = 0; p < 2; ++p) {
      int m = p * 32 + lr;
      float4 av = *reinterpret_cast<const float4*>(A + (long)(m0 + m) * lda + kt + lk);
      As[lk + 0][m] = av.x; As[lk + 1][m] = av.y;
      As[lk + 2][m] = av.z; As[lk + 3][m] = av.w;
      float4 wv = *reinterpret_cast<const float4*>(Bw + (long)(n0 + m) * ldb + kt + lk);
      Ws[lk + 0][m] = wv.x; Ws[lk + 1][m] = wv.y;
      Ws[lk + 2][m] = wv.z; Ws[lk + 3][m] = wv.w;
    }
    __syncthreads();
    #pragma unroll
    for (int k = 0; k < KT; ++k) {
      float4 a = *reinterpret_cast<const float4*>(&As[k][tm * 4]);
      float4 w = *reinterpret_cast<const float4*>(&Ws[k][tn * 4]);
      acc[0][0] += a.x * w.x; acc[0][1] += a.x * w.y; acc[0][2] += a.x * w.z; acc[0][3] += a.x * w.w;
      acc[1][0] += a.y * w.x; acc[1][1] += a.y * w.y; acc[1][2] += a.y * w.z; acc[1][3] += a.y * w.w;
      acc[2][0] += a.z * w.x; acc[2][1] += a.z * w.y; acc[2][2] += a.z * w.z; acc[2][3] += a.z * w.w;
      acc[3][0] += a.w * w.x; acc[3][1] += a.w * w.y; acc[3][2] += a.w * w.z; acc[3][3] += a.w * w.w;
    }
  }
  float* Cz = C + (long)blockIdx.z * zstride;
  #pragma unroll
  for (int mi = 0; mi < 4; ++mi) {
    int row = m0 + tm * 4 + mi, col = n0 + tn * 4;
    float4 o;
    o.x = acc[mi][0]; o.y = acc[mi][1]; o.z = acc[mi][2]; o.w = acc[mi][3];
    if (bias) {
      o.x += bias[col]; o.y += bias[col + 1]; o.z += bias[col + 2]; o.w += bias[col + 3];
    }
    *reinterpret_cast<float4*>(Cz + (long)row * ldc + col) = o;
  }
}

// ---------------------------------------------------------------------------
// fc GEMM, bf16 MFMA, fp32 weights streamed + converted in-register.
// out[b][n] = sum_k h[b][k] * fcW[n][k] + bias[n];  M=64, N=64/block, K=512.
// No LDS, no barriers: each lane loads exactly its MFMA fragments.
// Fragment mapping (verified on HW in round 2): lane=64*wv.. frag row/col =
// lane&15, k-cluster = lane>>4; per mfma K=32 slice, lane's 8 elems at
// k0 = ks*32 + (lane>>4)*8. C/D: row = (lane>>4)*4 + reg.
// ---------------------------------------------------------------------------
__global__ __launch_bounds__(256) void fc_mfma_f32w(
    const u16* __restrict__ hb,        // [64][512] bf16 (tiny, L2-resident)
    const float* __restrict__ Wf,      // [32000][512] fp32
    const float* __restrict__ bias,
    float* __restrict__ outp) {        // base offset to column t+1; ldc = TT*VD
  const int tid = threadIdx.x;
  const int n0 = blockIdx.x * 64;
  const int wv = tid >> 6, lane = tid & 63;
  const int frow = lane & 15, fgrp = lane >> 4;

  const float* Wrow = Wf + (long)(n0 + wv * 16 + frow) * HD;
  const u16*   Arow = hb + frow * HD;

  f32x4 acc[4] = {{0.f,0.f,0.f,0.f},{0.f,0.f,0.f,0.f},{0.f,0.f,0.f,0.f},{0.f,0.f,0.f,0.f}};

  #pragma unroll
  for (int ks = 0; ks < 16; ++ks) {
    const int k0 = ks * 32 + fgrp * 8;
    float4 w0 = *reinterpret_cast<const float4*>(Wrow + k0);
    float4 w1 = *reinterpret_cast<const float4*>(Wrow + k0 + 4);
    union { short8v v; u16 s[8]; } bf;
    bf.s[0] = f2bf(w0.x); bf.s[1] = f2bf(w0.y); bf.s[2] = f2bf(w0.z); bf.s[3] = f2bf(w0.w);
    bf.s[4] = f2bf(w1.x); bf.s[5] = f2bf(w1.y); bf.s[6] = f2bf(w1.z); bf.s[7] = f2bf(w1.w);
    #pragma unroll
    for (int m = 0; m < 4; ++m) {
      short8v afr = *reinterpret_cast<const short8v*>(Arow + m * 16 * HD + k0);
      acc[m] = __builtin_amdgcn_mfma_f32_16x16x32_bf16(afr, bf.v, acc[m], 0, 0, 0);
    }
  }

  const int col = n0 + wv * 16 + frow;
  const float bv = bias[col];
  #pragma unroll
  for (int m = 0; m < 4; ++m) {
    #pragma unroll
    for (int r = 0; r < 4; ++r) {
      int row = m * 16 + fgrp * 4 + r;
      outp[(long)row * ((long)TT * VD) + col] = acc[m][r] + bv;
    }
  }
}

// ---------------------------------------------------------------------------
// Attention step
// ---------------------------------------------------------------------------
__global__ __launch_bounds__(512) void attention_step(
    const float* __restrict__ proj, const float* __restrict__ h,
    const float* __restrict__ enc, float* __restrict__ attn_out,
    float* __restrict__ ctx) {
  int b = blockIdx.x;
  __shared__ float sh[HD];
  __shared__ float sc[64];
  __shared__ float sw[64];
  int tid = threadIdx.x;
  sh[tid] = h[b * HD + tid];
  __syncthreads();
  int wave = tid >> 6, lane = tid & 63;
  for (int s = wave; s < SS; s += 8) {
    const float* pr = proj + ((long)b * SS + s) * HD;
    float acc = 0.f;
    #pragma unroll
    for (int k = 0; k < HD / 64; ++k) acc += pr[lane + k * 64] * sh[lane + k * 64];
    #pragma unroll
    for (int off = 32; off; off >>= 1) acc += __shfl_down(acc, off);
    if (lane == 0) sc[s] = acc;
  }
  __syncthreads();
  if (wave == 0) {
    float v = (lane < SS) ? sc[lane] : -INFINITY;
    float m = v;
    #pragma unroll
    for (int off = 32; off; off >>= 1) m = fmaxf(m, __shfl_down(m, off));
    m = __shfl(m, 0);
    float e = (lane < SS) ? __expf(v - m) : 0.f;
    float sum = e;
    #pragma unroll
    for (int off = 32; off; off >>= 1) sum += __shfl_down(sum, off);
    sum = __shfl(sum, 0);
    float w = e / sum;
    if (lane < SS) { sw[lane] = w; attn_out[b * SS + lane] = w; }
  }
  __syncthreads();
  for (int e0 = tid; e0 < ENCD; e0 += 512) {
    float acc = 0.f;
    const float* eb = enc + (long)b * SS * ENCD + e0;
    #pragma unroll
    for (int s = 0; s < SS; ++s) acc += sw[s] * eb[(long)s * ENCD];
    ctx[b * ENCD + e0] = acc;
  }
}

// ---------------------------------------------------------------------------
// Build x[b][0:2048] = [emb_table[word_b], ctx[b], h[b]]
// ---------------------------------------------------------------------------
__global__ __launch_bounds__(256) void build_x(
    const float* __restrict__ emb, const int* __restrict__ caps, int t,
    const float* __restrict__ ctx, const float* __restrict__ h,
    float* __restrict__ x) {
  int b = blockIdx.x;
  int word = caps[b * TT + t];
  const float* er = emb + (long)word * ED;
  for (int k = threadIdx.x; k < ED + ENCD + HD; k += 256) {
    float v;
    if (k < ED) v = er[k];
    else if (k < ED + ENCD) v = ctx[b * ENCD + (k - ED)];
    else v = h[b * HD + (k - ED - ENCD)];
    x[b * 2048 + k] = v;
  }
}

// ---------------------------------------------------------------------------
// LSTM pointwise: reduce 8 split-K partials, gate math, update h,c, emit bf16 h
// ---------------------------------------------------------------------------
__global__ __launch_bounds__(256) void lstm_pointwise(
    const float* __restrict__ P, const float* __restrict__ b_ih,
    const float* __restrict__ b_hh, float* __restrict__ h,
    float* __restrict__ c, u16* __restrict__ hb) {
  int idx = blockIdx.x * 256 + threadIdx.x;  // 0..32767
  int b = idx >> 9, u = idx & 511;
  float gi = b_ih[u]        + b_hh[u];
  float gf = b_ih[u + 512]  + b_hh[u + 512];
  float gg = b_ih[u + 1024] + b_hh[u + 1024];
  float go = b_ih[u + 1536] + b_hh[u + 1536];
  #pragma unroll
  for (int ks = 0; ks < 8; ++ks) {
    const float* p = P + ((long)ks * BB + b) * 2048;
    gi += p[u]; gf += p[u + 512]; gg += p[u + 1024]; go += p[u + 1536];
  }
  float si = 1.f / (1.f + __expf(-gi));
  float sf = 1.f / (1.f + __expf(-gf));
  float so = 1.f / (1.f + __expf(-go));
  float tg = tanhf(gg);
  float c2 = sf * c[idx] + si * tg;
  float h2 = so * tanhf(c2);
  c[idx] = c2;
  h[idx] = h2;
  hb[idx] = f2bf(h2);
}

// ---------------------------------------------------------------------------
extern "C" void kernel_launch(void* const* d_in, const int* in_sizes, int n_in,
                              void* d_out_, int out_size, void* d_ws, size_t ws_size,
                              hipStream_t stream) {
  const float* enc   = (const float*)d_in[0];
  const int*   caps  = (const int*)d_in[1];
  const float* emb   = (const float*)d_in[2];
  const float* attnW = (const float*)d_in[3];
  const float* attnB = (const float*)d_in[4];
  const float* W_ih  = (const float*)d_in[5];
  const float* W_hh  = (const float*)d_in[6];
  const float* b_ih  = (const float*)d_in[7];
  const float* b_hh  = (const float*)d_in[8];
  const float* fcW   = (const float*)d_in[9];
  const float* fcb   = (const float*)d_in[10];

  float* out   = (float*)d_out_;                       // [B][T][V]
  float* attns = out + (long)BB * TT * VD;             // [T-1][B][S]

  // workspace layout (~13.2 MB — same footprint the fallback proved in all passes)
  float* ws   = (float*)d_ws;
  float* proj = ws;                                    // [B*S][H]
  float* h    = proj + (long)BB * SS * HD;
  float* c    = h + BB * HD;
  float* ctx  = c + BB * HD;
  float* x    = ctx + BB * ENCD;
  float* P    = x + BB * 2048;                         // [8][B][2048]
  u16*   hbf  = (u16*)(P + (long)8 * BB * 2048);       // [B][H] bf16

  init_kernel<<<(BB * VD + 255) / 256, 256, 0, stream>>>(out, h, c);

  // proj = enc @ attn_W^T + attn_b : M=3840, N=512, K=1024
  gemm_nt<<<dim3(8, 60, 1), 256, 0, stream>>>(enc, ENCD, attnW, ENCD, attnB,
                                              proj, HD, 0, ENCD);

  for (int t = 0; t < TT - 1; ++t) {
    attention_step<<<BB, 512, 0, stream>>>(proj, h, enc,
                                           attns + (long)t * BB * SS, ctx);
    build_x<<<BB, 256, 0, stream>>>(emb, caps, t, ctx, h, x);
    gemm_nt<<<dim3(32, 1, 6), 256, 0, stream>>>(x, 2048, W_ih, 1536, nullptr,
                                                P, 2048, (long)BB * 2048, 256);
    gemm_nt<<<dim3(32, 1, 2), 256, 0, stream>>>(x + 1536, 2048, W_hh, 512, nullptr,
                                                P + (long)6 * BB * 2048, 2048,
                                                (long)BB * 2048, 256);
    lstm_pointwise<<<128, 256, 0, stream>>>(P, b_ih, b_hh, h, c, hbf);
    fc_mfma_f32w<<<VD / 64, 256, 0, stream>>>(hbf, fcW, fcb,
                                              out + (long)(t + 1) * VD);
  }
}

// Round 4
// 1921.804 us; speedup vs baseline: 1.0160x; 1.0160x over previous
//
#include <hip/hip_runtime.h>
#include <math.h>

// Problem dims (fixed by reference)
#define BB   64
#define SS   60
#define ENCD 1024
#define ED   512
#define HD   512
#define VD   32000
#define TT   20
#define KT   32   // fp32 GEMM k-tile

typedef unsigned short u16;
typedef __attribute__((ext_vector_type(8))) short short8v;   // 8 bf16 = 4 VGPR
typedef __attribute__((ext_vector_type(4))) float f32x4;

__device__ __forceinline__ u16 f2bf(float x) {   // RNE float->bf16
  unsigned int u = __float_as_uint(x);
  return (u16)((u + 0x7FFFu + ((u >> 16) & 1u)) >> 16);
}

// ---------------------------------------------------------------------------
// init: zero outputs[:,0,:] and h0/c0
// ---------------------------------------------------------------------------
__global__ __launch_bounds__(256) void init_kernel(float* __restrict__ out,
                                                   float* __restrict__ h,
                                                   float* __restrict__ c) {
  int i = blockIdx.x * 256 + threadIdx.x;
  if (i < BB * VD) {
    int b = i / VD, v = i - b * VD;
    out[(long)b * (TT * VD) + v] = 0.f;
  }
  if (i < BB * HD) { h[i] = 0.f; c[i] = 0.f; }
}

// ---------------------------------------------------------------------------
// fp32->bf16 bulk convert (8 elems/thread)
// ---------------------------------------------------------------------------
__global__ __launch_bounds__(256) void convert_bf16_k(const float* __restrict__ src,
                                                      u16* __restrict__ dst, long n) {
  long i = ((long)blockIdx.x * 256 + threadIdx.x) * 8;
  if (i + 8 <= n) {
    float4 a = *reinterpret_cast<const float4*>(src + i);
    float4 b = *reinterpret_cast<const float4*>(src + i + 4);
    uint4 o;
    o.x = (unsigned)f2bf(a.x) | ((unsigned)f2bf(a.y) << 16);
    o.y = (unsigned)f2bf(a.z) | ((unsigned)f2bf(a.w) << 16);
    o.z = (unsigned)f2bf(b.x) | ((unsigned)f2bf(b.y) << 16);
    o.w = (unsigned)f2bf(b.z) | ((unsigned)f2bf(b.w) << 16);
    *reinterpret_cast<uint4*>(dst + i) = o;
  }
}

// ---------------------------------------------------------------------------
// Generic fp32 NT GEMM (proj / gates)
// ---------------------------------------------------------------------------
__global__ __launch_bounds__(256) void gemm_nt(
    const float* __restrict__ A, int lda,
    const float* __restrict__ Bw, int ldb,
    const float* __restrict__ bias,
    float* __restrict__ C, long ldc, long zstride,
    int kChunk) {
  __shared__ __align__(16) float As[KT][64];
  __shared__ __align__(16) float Ws[KT][64];
  const int tid = threadIdx.x;
  const int m0 = blockIdx.y * 64, n0 = blockIdx.x * 64;
  const int k0 = blockIdx.z * kChunk, k1 = k0 + kChunk;
  const int tm = tid & 15, tn = tid >> 4;
  const int lr = tid >> 3;
  const int lk = (tid & 7) * 4;
  float acc[4][4] = {};
  for (int kt = k0; kt < k1; kt += KT) {
    __syncthreads();
    #pragma unroll
    for (int p = 0; p < 2; ++p) {
      int m = p * 32 + lr;
      float4 av = *reinterpret_cast<const float4*>(A + (long)(m0 + m) * lda + kt + lk);
      As[lk + 0][m] = av.x; As[lk + 1][m] = av.y;
      As[lk + 2][m] = av.z; As[lk + 3][m] = av.w;
      float4 wv = *reinterpret_cast<const float4*>(Bw + (long)(n0 + m) * ldb + kt + lk);
      Ws[lk + 0][m] = wv.x; Ws[lk + 1][m] = wv.y;
      Ws[lk + 2][m] = wv.z; Ws[lk + 3][m] = wv.w;
    }
    __syncthreads();
    #pragma unroll
    for (int k = 0; k < KT; ++k) {
      float4 a = *reinterpret_cast<const float4*>(&As[k][tm * 4]);
      float4 w = *reinterpret_cast<const float4*>(&Ws[k][tn * 4]);
      acc[0][0] += a.x * w.x; acc[0][1] += a.x * w.y; acc[0][2] += a.x * w.z; acc[0][3] += a.x * w.w;
      acc[1][0] += a.y * w.x; acc[1][1] += a.y * w.y; acc[1][2] += a.y * w.z; acc[1][3] += a.y * w.w;
      acc[2][0] += a.z * w.x; acc[2][1] += a.z * w.y; acc[2][2] += a.z * w.z; acc[2][3] += a.z * w.w;
      acc[3][0] += a.w * w.x; acc[3][1] += a.w * w.y; acc[3][2] += a.w * w.z; acc[3][3] += a.w * w.w;
    }
  }
  float* Cz = C + (long)blockIdx.z * zstride;
  #pragma unroll
  for (int mi = 0; mi < 4; ++mi) {
    int row = m0 + tm * 4 + mi, col = n0 + tn * 4;
    float4 o;
    o.x = acc[mi][0]; o.y = acc[mi][1]; o.z = acc[mi][2]; o.w = acc[mi][3];
    if (bias) {
      o.x += bias[col]; o.y += bias[col + 1]; o.z += bias[col + 2]; o.w += bias[col + 3];
    }
    *reinterpret_cast<float4*>(Cz + (long)row * ldc + col) = o;
  }
}

// ---------------------------------------------------------------------------
// fc GEMM v2, bf16 MFMA, k-split across wave pairs.
// out[b][n] = sum_k h[b][k]*W[n][k] + bias[n]; M=64, N=64/block, K=512.
// 512 threads = 8 waves: wave = (kv, wq); kv = k-half (0/1), wq = 16-col strip.
// Per wave: 8 W-loads (bf16x8) + 32 A-loads + 32 MFMA over K=256.
// kv=1 dumps acc to LDS; kv=0 adds, +bias, stores.
// Fragment mapping HW-verified (rounds 2/3 passed): A lane row = lane&15,
// k = ks*32 + (lane>>4)*8; C/D row = (lane>>4)*4 + reg, col = lane&15.
// ---------------------------------------------------------------------------
__global__ __launch_bounds__(512) void fc_mfma_v2(
    const u16* __restrict__ hb,        // [64][512] bf16 (L2/L3-hot)
    const u16* __restrict__ Wb,        // [32000][512] bf16
    const float* __restrict__ bias,
    float* __restrict__ outp) {        // base offset to column t+1; ldc = TT*VD
  __shared__ float part[4][64][16];
  const int tid = threadIdx.x;
  const int n0 = blockIdx.x * 64;
  const int w = tid >> 6, lane = tid & 63;
  const int kv = w >> 2, wq = w & 3;
  const int frow = lane & 15, fgrp = lane >> 4;

  const u16* Wrow = Wb + (long)(n0 + wq * 16 + frow) * HD + kv * 256;
  const u16* Arow = hb + frow * HD + kv * 256;

  f32x4 acc[4] = {{0.f,0.f,0.f,0.f},{0.f,0.f,0.f,0.f},{0.f,0.f,0.f,0.f},{0.f,0.f,0.f,0.f}};

  #pragma unroll 4
  for (int ks = 0; ks < 8; ++ks) {
    const int k0 = ks * 32 + fgrp * 8;
    short8v bfr = *reinterpret_cast<const short8v*>(Wrow + k0);
    #pragma unroll
    for (int m = 0; m < 4; ++m) {
      short8v afr = *reinterpret_cast<const short8v*>(Arow + m * 16 * HD + k0);
      acc[m] = __builtin_amdgcn_mfma_f32_16x16x32_bf16(afr, bfr, acc[m], 0, 0, 0);
    }
  }

  if (kv == 1) {
    #pragma unroll
    for (int m = 0; m < 4; ++m)
      #pragma unroll
      for (int r = 0; r < 4; ++r)
        part[wq][m * 16 + fgrp * 4 + r][frow] = acc[m][r];
  }
  __syncthreads();
  if (kv == 0) {
    const int col = n0 + wq * 16 + frow;
    const float bv = bias[col];
    #pragma unroll
    for (int m = 0; m < 4; ++m) {
      #pragma unroll
      for (int r = 0; r < 4; ++r) {
        int row = m * 16 + fgrp * 4 + r;
        outp[(long)row * ((long)TT * VD) + col] = acc[m][r] + part[wq][row][frow] + bv;
      }
    }
  }
}

// ---------------------------------------------------------------------------
// fc GEMM fallback: fp32 weights streamed + converted in-register (slow but
// ws-independent). Kept only for the ws_size guard.
// ---------------------------------------------------------------------------
__global__ __launch_bounds__(256) void fc_mfma_f32w(
    const u16* __restrict__ hb, const float* __restrict__ Wf,
    const float* __restrict__ bias, float* __restrict__ outp) {
  const int tid = threadIdx.x;
  const int n0 = blockIdx.x * 64;
  const int wv = tid >> 6, lane = tid & 63;
  const int frow = lane & 15, fgrp = lane >> 4;
  const float* Wrow = Wf + (long)(n0 + wv * 16 + frow) * HD;
  const u16*   Arow = hb + frow * HD;
  f32x4 acc[4] = {{0.f,0.f,0.f,0.f},{0.f,0.f,0.f,0.f},{0.f,0.f,0.f,0.f},{0.f,0.f,0.f,0.f}};
  #pragma unroll 2
  for (int ks = 0; ks < 16; ++ks) {
    const int k0 = ks * 32 + fgrp * 8;
    float4 w0 = *reinterpret_cast<const float4*>(Wrow + k0);
    float4 w1 = *reinterpret_cast<const float4*>(Wrow + k0 + 4);
    union { short8v v; u16 s[8]; } bf;
    bf.s[0] = f2bf(w0.x); bf.s[1] = f2bf(w0.y); bf.s[2] = f2bf(w0.z); bf.s[3] = f2bf(w0.w);
    bf.s[4] = f2bf(w1.x); bf.s[5] = f2bf(w1.y); bf.s[6] = f2bf(w1.z); bf.s[7] = f2bf(w1.w);
    #pragma unroll
    for (int m = 0; m < 4; ++m) {
      short8v afr = *reinterpret_cast<const short8v*>(Arow + m * 16 * HD + k0);
      acc[m] = __builtin_amdgcn_mfma_f32_16x16x32_bf16(afr, bf.v, acc[m], 0, 0, 0);
    }
  }
  const int col = n0 + wv * 16 + frow;
  const float bv = bias[col];
  #pragma unroll
  for (int m = 0; m < 4; ++m)
    #pragma unroll
    for (int r = 0; r < 4; ++r)
      outp[(long)(m * 16 + fgrp * 4 + r) * ((long)TT * VD) + col] = acc[m][r] + bv;
}

// ---------------------------------------------------------------------------
// Attention step
// ---------------------------------------------------------------------------
__global__ __launch_bounds__(512) void attention_step(
    const float* __restrict__ proj, const float* __restrict__ h,
    const float* __restrict__ enc, float* __restrict__ attn_out,
    float* __restrict__ ctx) {
  int b = blockIdx.x;
  __shared__ float sh[HD];
  __shared__ float sc[64];
  __shared__ float sw[64];
  int tid = threadIdx.x;
  sh[tid] = h[b * HD + tid];
  __syncthreads();
  int wave = tid >> 6, lane = tid & 63;
  for (int s = wave; s < SS; s += 8) {
    const float* pr = proj + ((long)b * SS + s) * HD;
    float acc = 0.f;
    #pragma unroll
    for (int k = 0; k < HD / 64; ++k) acc += pr[lane + k * 64] * sh[lane + k * 64];
    #pragma unroll
    for (int off = 32; off; off >>= 1) acc += __shfl_down(acc, off);
    if (lane == 0) sc[s] = acc;
  }
  __syncthreads();
  if (wave == 0) {
    float v = (lane < SS) ? sc[lane] : -INFINITY;
    float m = v;
    #pragma unroll
    for (int off = 32; off; off >>= 1) m = fmaxf(m, __shfl_down(m, off));
    m = __shfl(m, 0);
    float e = (lane < SS) ? __expf(v - m) : 0.f;
    float sum = e;
    #pragma unroll
    for (int off = 32; off; off >>= 1) sum += __shfl_down(sum, off);
    sum = __shfl(sum, 0);
    float w = e / sum;
    if (lane < SS) { sw[lane] = w; attn_out[b * SS + lane] = w; }
  }
  __syncthreads();
  for (int e0 = tid; e0 < ENCD; e0 += 512) {
    float acc = 0.f;
    const float* eb = enc + (long)b * SS * ENCD + e0;
    #pragma unroll
    for (int s = 0; s < SS; ++s) acc += sw[s] * eb[(long)s * ENCD];
    ctx[b * ENCD + e0] = acc;
  }
}

// ---------------------------------------------------------------------------
// Build x[b][0:2048] = [emb_table[word_b], ctx[b], h[b]]
// ---------------------------------------------------------------------------
__global__ __launch_bounds__(256) void build_x(
    const float* __restrict__ emb, const int* __restrict__ caps, int t,
    const float* __restrict__ ctx, const float* __restrict__ h,
    float* __restrict__ x) {
  int b = blockIdx.x;
  int word = caps[b * TT + t];
  const float* er = emb + (long)word * ED;
  for (int k = threadIdx.x; k < ED + ENCD + HD; k += 256) {
    float v;
    if (k < ED) v = er[k];
    else if (k < ED + ENCD) v = ctx[b * ENCD + (k - ED)];
    else v = h[b * HD + (k - ED - ENCD)];
    x[b * 2048 + k] = v;
  }
}

// ---------------------------------------------------------------------------
// LSTM pointwise: reduce 8 split-K partials, gate math, update h,c, emit bf16 h
// ---------------------------------------------------------------------------
__global__ __launch_bounds__(256) void lstm_pointwise(
    const float* __restrict__ P, const float* __restrict__ b_ih,
    const float* __restrict__ b_hh, float* __restrict__ h,
    float* __restrict__ c, u16* __restrict__ hb) {
  int idx = blockIdx.x * 256 + threadIdx.x;  // 0..32767
  int b = idx >> 9, u = idx & 511;
  float gi = b_ih[u]        + b_hh[u];
  float gf = b_ih[u + 512]  + b_hh[u + 512];
  float gg = b_ih[u + 1024] + b_hh[u + 1024];
  float go = b_ih[u + 1536] + b_hh[u + 1536];
  #pragma unroll
  for (int ks = 0; ks < 8; ++ks) {
    const float* p = P + ((long)ks * BB + b) * 2048;
    gi += p[u]; gf += p[u + 512]; gg += p[u + 1024]; go += p[u + 1536];
  }
  float si = 1.f / (1.f + __expf(-gi));
  float sf = 1.f / (1.f + __expf(-gf));
  float so = 1.f / (1.f + __expf(-go));
  float tg = tanhf(gg);
  float c2 = sf * c[idx] + si * tg;
  float h2 = so * tanhf(c2);
  c[idx] = c2;
  h[idx] = h2;
  hb[idx] = f2bf(h2);
}

// ---------------------------------------------------------------------------
extern "C" void kernel_launch(void* const* d_in, const int* in_sizes, int n_in,
                              void* d_out_, int out_size, void* d_ws, size_t ws_size,
                              hipStream_t stream) {
  const float* enc   = (const float*)d_in[0];
  const int*   caps  = (const int*)d_in[1];
  const float* emb   = (const float*)d_in[2];
  const float* attnW = (const float*)d_in[3];
  const float* attnB = (const float*)d_in[4];
  const float* W_ih  = (const float*)d_in[5];
  const float* W_hh  = (const float*)d_in[6];
  const float* b_ih  = (const float*)d_in[7];
  const float* b_hh  = (const float*)d_in[8];
  const float* fcW   = (const float*)d_in[9];
  const float* fcb   = (const float*)d_in[10];

  float* out   = (float*)d_out_;                       // [B][T][V]
  float* attns = out + (long)BB * TT * VD;             // [T-1][B][S]

  // workspace layout
  float* ws   = (float*)d_ws;
  float* proj = ws;                                    // [B*S][H]
  float* h    = proj + (long)BB * SS * HD;
  float* c    = h + BB * HD;
  float* ctx  = c + BB * HD;
  float* x    = ctx + BB * ENCD;
  float* P    = x + BB * 2048;                         // [8][B][2048]
  u16*   hbf  = (u16*)(P + (long)8 * BB * 2048);       // [B][H] bf16
  u16*   Wbf  = hbf + (long)BB * HD;                   // [V][H] bf16
  size_t need = (size_t)((char*)(Wbf + (long)VD * HD) - (char*)d_ws);
  const bool use_wbf = (ws_size >= need);              // evidence: true in all passes

  init_kernel<<<(BB * VD + 255) / 256, 256, 0, stream>>>(out, h, c);

  if (use_wbf) {
    long n = (long)VD * HD;
    convert_bf16_k<<<(int)(n / 2048), 256, 0, stream>>>(fcW, Wbf, n);
  }

  // proj = enc @ attn_W^T + attn_b : M=3840, N=512, K=1024
  gemm_nt<<<dim3(8, 60, 1), 256, 0, stream>>>(enc, ENCD, attnW, ENCD, attnB,
                                              proj, HD, 0, ENCD);

  for (int t = 0; t < TT - 1; ++t) {
    attention_step<<<BB, 512, 0, stream>>>(proj, h, enc,
                                           attns + (long)t * BB * SS, ctx);
    build_x<<<BB, 256, 0, stream>>>(emb, caps, t, ctx, h, x);
    gemm_nt<<<dim3(32, 1, 6), 256, 0, stream>>>(x, 2048, W_ih, 1536, nullptr,
                                                P, 2048, (long)BB * 2048, 256);
    gemm_nt<<<dim3(32, 1, 2), 256, 0, stream>>>(x + 1536, 2048, W_hh, 512, nullptr,
                                                P + (long)6 * BB * 2048, 2048,
                                                (long)BB * 2048, 256);
    lstm_pointwise<<<128, 256, 0, stream>>>(P, b_ih, b_hh, h, c, hbf);
    if (use_wbf) {
      fc_mfma_v2<<<VD / 64, 512, 0, stream>>>(hbf, Wbf, fcb,
                                              out + (long)(t + 1) * VD);
    } else {
      fc_mfma_f32w<<<VD / 64, 256, 0, stream>>>(hbf, fcW, fcb,
                                                out + (long)(t + 1) * VD);
    }
  }
}

// Round 5
// 1761.691 us; speedup vs baseline: 1.1084x; 1.0909x over previous
//
#include <hip/hip_runtime.h>
#include <math.h>

// Problem dims (fixed by reference)
#define BB   64
#define SS   60
#define ENCD 1024
#define ED   512
#define HD   512
#define VD   32000
#define TT   20
#define KT   32   // fp32 GEMM k-tile

typedef unsigned short u16;
typedef __attribute__((ext_vector_type(8))) short short8v;   // 8 bf16 = 4 VGPR
typedef __attribute__((ext_vector_type(4))) float f32x4;

__device__ __forceinline__ u16 f2bf(float x) {   // RNE float->bf16
  unsigned int u = __float_as_uint(x);
  return (u16)((u + 0x7FFFu + ((u >> 16) & 1u)) >> 16);
}

// ---------------------------------------------------------------------------
// init: zero outputs[:,0,:] and h0/c0
// ---------------------------------------------------------------------------
__global__ __launch_bounds__(256) void init_kernel(float* __restrict__ out,
                                                   float* __restrict__ h,
                                                   float* __restrict__ c) {
  int i = blockIdx.x * 256 + threadIdx.x;
  if (i < BB * VD) {
    int b = i / VD, v = i - b * VD;
    out[(long)b * (TT * VD) + v] = 0.f;
  }
  if (i < BB * HD) { h[i] = 0.f; c[i] = 0.f; }
}

// ---------------------------------------------------------------------------
// fp32->bf16 bulk convert (8 elems/thread)
// ---------------------------------------------------------------------------
__global__ __launch_bounds__(256) void convert_bf16_k(const float* __restrict__ src,
                                                      u16* __restrict__ dst, long n) {
  long i = ((long)blockIdx.x * 256 + threadIdx.x) * 8;
  if (i + 8 <= n) {
    float4 a = *reinterpret_cast<const float4*>(src + i);
    float4 b = *reinterpret_cast<const float4*>(src + i + 4);
    uint4 o;
    o.x = (unsigned)f2bf(a.x) | ((unsigned)f2bf(a.y) << 16);
    o.y = (unsigned)f2bf(a.z) | ((unsigned)f2bf(a.w) << 16);
    o.z = (unsigned)f2bf(b.x) | ((unsigned)f2bf(b.y) << 16);
    o.w = (unsigned)f2bf(b.z) | ((unsigned)f2bf(b.w) << 16);
    *reinterpret_cast<uint4*>(dst + i) = o;
  }
}

// ---------------------------------------------------------------------------
// Generic fp32 NT GEMM (proj / gates)
// ---------------------------------------------------------------------------
__global__ __launch_bounds__(256) void gemm_nt(
    const float* __restrict__ A, int lda,
    const float* __restrict__ Bw, int ldb,
    const float* __restrict__ bias,
    float* __restrict__ C, long ldc, long zstride,
    int kChunk) {
  __shared__ __align__(16) float As[KT][64];
  __shared__ __align__(16) float Ws[KT][64];
  const int tid = threadIdx.x;
  const int m0 = blockIdx.y * 64, n0 = blockIdx.x * 64;
  const int k0 = blockIdx.z * kChunk, k1 = k0 + kChunk;
  const int tm = tid & 15, tn = tid >> 4;
  const int lr = tid >> 3;
  const int lk = (tid & 7) * 4;
  float acc[4][4] = {};
  for (int kt = k0; kt < k1; kt += KT) {
    __syncthreads();
    #pragma unroll
    for (int p = 0; p < 2; ++p) {
      int m = p * 32 + lr;
      float4 av = *reinterpret_cast<const float4*>(A + (long)(m0 + m) * lda + kt + lk);
      As[lk + 0][m] = av.x; As[lk + 1][m] = av.y;
      As[lk + 2][m] = av.z; As[lk + 3][m] = av.w;
      float4 wv = *reinterpret_cast<const float4*>(Bw + (long)(n0 + m) * ldb + kt + lk);
      Ws[lk + 0][m] = wv.x; Ws[lk + 1][m] = wv.y;
      Ws[lk + 2][m] = wv.z; Ws[lk + 3][m] = wv.w;
    }
    __syncthreads();
    #pragma unroll
    for (int k = 0; k < KT; ++k) {
      float4 a = *reinterpret_cast<const float4*>(&As[k][tm * 4]);
      float4 w = *reinterpret_cast<const float4*>(&Ws[k][tn * 4]);
      acc[0][0] += a.x * w.x; acc[0][1] += a.x * w.y; acc[0][2] += a.x * w.z; acc[0][3] += a.x * w.w;
      acc[1][0] += a.y * w.x; acc[1][1] += a.y * w.y; acc[1][2] += a.y * w.z; acc[1][3] += a.y * w.w;
      acc[2][0] += a.z * w.x; acc[2][1] += a.z * w.y; acc[2][2] += a.z * w.z; acc[2][3] += a.z * w.w;
      acc[3][0] += a.w * w.x; acc[3][1] += a.w * w.y; acc[3][2] += a.w * w.z; acc[3][3] += a.w * w.w;
    }
  }
  float* Cz = C + (long)blockIdx.z * zstride;
  #pragma unroll
  for (int mi = 0; mi < 4; ++mi) {
    int row = m0 + tm * 4 + mi, col = n0 + tn * 4;
    float4 o;
    o.x = acc[mi][0]; o.y = acc[mi][1]; o.z = acc[mi][2]; o.w = acc[mi][3];
    if (bias) {
      o.x += bias[col]; o.y += bias[col + 1]; o.z += bias[col + 2]; o.w += bias[col + 3];
    }
    *reinterpret_cast<float4*>(Cz + (long)row * ldc + col) = o;
  }
}

// ---------------------------------------------------------------------------
// Batched fc GEMM over all 19 steps, bf16 MFMA, no LDS.
// out[b][t+1][n] = sum_k hbuf[t][b][k] * Wb[n][k] + bias[n]
// grid = (19, 500): blockIdx.x = t (fastest -> 19 consecutive blocks share
// the same 64KB W-tile in L2), blockIdx.y = 64-col n-tile.
// Fragment mapping HW-verified (rounds 2-4 passed): A row = lane&15,
// k = ks*32 + (lane>>4)*8; C/D row = (lane>>4)*4 + reg, col = lane&15.
// ---------------------------------------------------------------------------
__global__ __launch_bounds__(256) void fc_batched(
    const u16* __restrict__ hbuf,      // [19][64][512] bf16
    const u16* __restrict__ Wb,        // [32000][512] bf16
    const float* __restrict__ bias,
    float* __restrict__ out) {         // full [B][T][V] base
  const int t  = blockIdx.x;
  const int n0 = blockIdx.y * 64;
  const int tid = threadIdx.x;
  const int wv = tid >> 6, lane = tid & 63;
  const int frow = lane & 15, fgrp = lane >> 4;

  const u16* Wrow = Wb + (long)(n0 + wv * 16 + frow) * HD;
  const u16* Arow = hbuf + ((long)t * BB + frow) * HD;

  f32x4 acc[4] = {{0.f,0.f,0.f,0.f},{0.f,0.f,0.f,0.f},{0.f,0.f,0.f,0.f},{0.f,0.f,0.f,0.f}};

  #pragma unroll 4
  for (int ks = 0; ks < 16; ++ks) {
    const int k0 = ks * 32 + fgrp * 8;
    short8v bfr = *reinterpret_cast<const short8v*>(Wrow + k0);
    #pragma unroll
    for (int m = 0; m < 4; ++m) {
      short8v afr = *reinterpret_cast<const short8v*>(Arow + m * 16 * HD + k0);
      acc[m] = __builtin_amdgcn_mfma_f32_16x16x32_bf16(afr, bfr, acc[m], 0, 0, 0);
    }
  }

  const int col = n0 + wv * 16 + frow;
  const float bv = bias[col];
  #pragma unroll
  for (int m = 0; m < 4; ++m) {
    #pragma unroll
    for (int r = 0; r < 4; ++r) {
      int b = m * 16 + fgrp * 4 + r;
      out[((long)b * TT + (t + 1)) * VD + col] = acc[m][r] + bv;
    }
  }
}

// ---------------------------------------------------------------------------
// fc fallback (per-step): fp32 weights streamed + converted in-register.
// Only used if ws_size can't hold Wbf.
// ---------------------------------------------------------------------------
__global__ __launch_bounds__(256) void fc_mfma_f32w(
    const u16* __restrict__ hb, const float* __restrict__ Wf,
    const float* __restrict__ bias, float* __restrict__ outp) {
  const int tid = threadIdx.x;
  const int n0 = blockIdx.x * 64;
  const int wv = tid >> 6, lane = tid & 63;
  const int frow = lane & 15, fgrp = lane >> 4;
  const float* Wrow = Wf + (long)(n0 + wv * 16 + frow) * HD;
  const u16*   Arow = hb + frow * HD;
  f32x4 acc[4] = {{0.f,0.f,0.f,0.f},{0.f,0.f,0.f,0.f},{0.f,0.f,0.f,0.f},{0.f,0.f,0.f,0.f}};
  #pragma unroll 2
  for (int ks = 0; ks < 16; ++ks) {
    const int k0 = ks * 32 + fgrp * 8;
    float4 w0 = *reinterpret_cast<const float4*>(Wrow + k0);
    float4 w1 = *reinterpret_cast<const float4*>(Wrow + k0 + 4);
    union { short8v v; u16 s[8]; } bf;
    bf.s[0] = f2bf(w0.x); bf.s[1] = f2bf(w0.y); bf.s[2] = f2bf(w0.z); bf.s[3] = f2bf(w0.w);
    bf.s[4] = f2bf(w1.x); bf.s[5] = f2bf(w1.y); bf.s[6] = f2bf(w1.z); bf.s[7] = f2bf(w1.w);
    #pragma unroll
    for (int m = 0; m < 4; ++m) {
      short8v afr = *reinterpret_cast<const short8v*>(Arow + m * 16 * HD + k0);
      acc[m] = __builtin_amdgcn_mfma_f32_16x16x32_bf16(afr, bf.v, acc[m], 0, 0, 0);
    }
  }
  const int col = n0 + wv * 16 + frow;
  const float bv = bias[col];
  #pragma unroll
  for (int m = 0; m < 4; ++m)
    #pragma unroll
    for (int r = 0; r < 4; ++r)
      outp[(long)(m * 16 + fgrp * 4 + r) * ((long)TT * VD) + col] = acc[m][r] + bv;
}

// ---------------------------------------------------------------------------
// Fused attention + build_x: scores, softmax, attns out, and writes
// x[b] = [emb(512) | ctx(1024) | h(512)] directly (ctx never materialized).
// ---------------------------------------------------------------------------
__global__ __launch_bounds__(512) void attn_build_x(
    const float* __restrict__ proj, const float* __restrict__ h,
    const float* __restrict__ enc, const float* __restrict__ emb,
    const int* __restrict__ caps, int t,
    float* __restrict__ attn_out, float* __restrict__ x) {
  int b = blockIdx.x;
  __shared__ float sh[HD];
  __shared__ float sc[64];
  __shared__ float sw[64];
  int tid = threadIdx.x;
  sh[tid] = h[b * HD + tid];
  __syncthreads();
  int wave = tid >> 6, lane = tid & 63;
  for (int s = wave; s < SS; s += 8) {
    const float* pr = proj + ((long)b * SS + s) * HD;
    float acc = 0.f;
    #pragma unroll
    for (int k = 0; k < HD / 64; ++k) acc += pr[lane + k * 64] * sh[lane + k * 64];
    #pragma unroll
    for (int off = 32; off; off >>= 1) acc += __shfl_down(acc, off);
    if (lane == 0) sc[s] = acc;
  }
  __syncthreads();
  if (wave == 0) {
    float v = (lane < SS) ? sc[lane] : -INFINITY;
    float m = v;
    #pragma unroll
    for (int off = 32; off; off >>= 1) m = fmaxf(m, __shfl_down(m, off));
    m = __shfl(m, 0);
    float e = (lane < SS) ? __expf(v - m) : 0.f;
    float sum = e;
    #pragma unroll
    for (int off = 32; off; off >>= 1) sum += __shfl_down(sum, off);
    sum = __shfl(sum, 0);
    float w = e / sum;
    if (lane < SS) { sw[lane] = w; attn_out[b * SS + lane] = w; }
  }
  __syncthreads();
  float* xb = x + (long)b * 2048;
  // ctx segment
  for (int e0 = tid; e0 < ENCD; e0 += 512) {
    float acc = 0.f;
    const float* eb = enc + (long)b * SS * ENCD + e0;
    #pragma unroll
    for (int s = 0; s < SS; ++s) acc += sw[s] * eb[(long)s * ENCD];
    xb[ED + e0] = acc;
  }
  // emb + h segments (tid covers 0..511 = ED = HD)
  int word = caps[b * TT + t];
  xb[tid] = emb[(long)word * ED + tid];
  xb[1536 + tid] = sh[tid];
}

// ---------------------------------------------------------------------------
// LSTM pointwise: reduce 8 split-K partials, gate math, update h,c, emit bf16 h
// ---------------------------------------------------------------------------
__global__ __launch_bounds__(256) void lstm_pointwise(
    const float* __restrict__ P, const float* __restrict__ b_ih,
    const float* __restrict__ b_hh, float* __restrict__ h,
    float* __restrict__ c, u16* __restrict__ hb) {
  int idx = blockIdx.x * 256 + threadIdx.x;  // 0..32767
  int b = idx >> 9, u = idx & 511;
  float gi = b_ih[u]        + b_hh[u];
  float gf = b_ih[u + 512]  + b_hh[u + 512];
  float gg = b_ih[u + 1024] + b_hh[u + 1024];
  float go = b_ih[u + 1536] + b_hh[u + 1536];
  #pragma unroll
  for (int ks = 0; ks < 8; ++ks) {
    const float* p = P + ((long)ks * BB + b) * 2048;
    gi += p[u]; gf += p[u + 512]; gg += p[u + 1024]; go += p[u + 1536];
  }
  float si = 1.f / (1.f + __expf(-gi));
  float sf = 1.f / (1.f + __expf(-gf));
  float so = 1.f / (1.f + __expf(-go));
  float tg = tanhf(gg);
  float c2 = sf * c[idx] + si * tg;
  float h2 = so * tanhf(c2);
  c[idx] = c2;
  h[idx] = h2;
  hb[idx] = f2bf(h2);
}

// ---------------------------------------------------------------------------
extern "C" void kernel_launch(void* const* d_in, const int* in_sizes, int n_in,
                              void* d_out_, int out_size, void* d_ws, size_t ws_size,
                              hipStream_t stream) {
  const float* enc   = (const float*)d_in[0];
  const int*   caps  = (const int*)d_in[1];
  const float* emb   = (const float*)d_in[2];
  const float* attnW = (const float*)d_in[3];
  const float* attnB = (const float*)d_in[4];
  const float* W_ih  = (const float*)d_in[5];
  const float* W_hh  = (const float*)d_in[6];
  const float* b_ih  = (const float*)d_in[7];
  const float* b_hh  = (const float*)d_in[8];
  const float* fcW   = (const float*)d_in[9];
  const float* fcb   = (const float*)d_in[10];

  float* out   = (float*)d_out_;                       // [B][T][V]
  float* attns = out + (long)BB * TT * VD;             // [T-1][B][S]

  // workspace layout
  float* ws   = (float*)d_ws;
  float* proj = ws;                                    // [B*S][H]
  float* h    = proj + (long)BB * SS * HD;
  float* c    = h + BB * HD;
  float* x    = c + BB * HD;                           // [B][2048]
  float* P    = x + BB * 2048;                         // [8][B][2048]
  u16*   hbuf = (u16*)(P + (long)8 * BB * 2048);       // [19][B][H] bf16
  u16*   Wbf  = hbuf + (long)(TT - 1) * BB * HD;       // [V][H] bf16
  size_t need = (size_t)((char*)(Wbf + (long)VD * HD) - (char*)d_ws);
  const bool use_wbf = (ws_size >= need);              // true in all observed passes

  init_kernel<<<(BB * VD + 255) / 256, 256, 0, stream>>>(out, h, c);

  if (use_wbf) {
    long n = (long)VD * HD;
    convert_bf16_k<<<(int)(n / 2048), 256, 0, stream>>>(fcW, Wbf, n);
  }

  // proj = enc @ attn_W^T + attn_b : M=3840, N=512, K=1024
  gemm_nt<<<dim3(8, 60, 1), 256, 0, stream>>>(enc, ENCD, attnW, ENCD, attnB,
                                              proj, HD, 0, ENCD);

  for (int t = 0; t < TT - 1; ++t) {
    attn_build_x<<<BB, 512, 0, stream>>>(proj, h, enc, emb, caps, t,
                                         attns + (long)t * BB * SS, x);
    gemm_nt<<<dim3(32, 1, 6), 256, 0, stream>>>(x, 2048, W_ih, 1536, nullptr,
                                                P, 2048, (long)BB * 2048, 256);
    gemm_nt<<<dim3(32, 1, 2), 256, 0, stream>>>(x + 1536, 2048, W_hh, 512, nullptr,
                                                P + (long)6 * BB * 2048, 2048,
                                                (long)BB * 2048, 256);
    lstm_pointwise<<<128, 256, 0, stream>>>(P, b_ih, b_hh, h, c,
                                            hbuf + (long)t * BB * HD);
    if (!use_wbf) {
      fc_mfma_f32w<<<VD / 64, 256, 0, stream>>>(hbuf + (long)t * BB * HD, fcW, fcb,
                                                out + (long)(t + 1) * VD);
    }
  }

  if (use_wbf) {
    fc_batched<<<dim3(TT - 1, VD / 64), 256, 0, stream>>>(hbuf, Wbf, fcb, out);
  }
}

// Round 6
// 1497.345 us; speedup vs baseline: 1.3041x; 1.1765x over previous
//
#include <hip/hip_runtime.h>
#include <math.h>

// Problem dims (fixed by reference)
#define BB   64
#define SS   60
#define ENCD 1024
#define ED   512
#define HD   512
#define VD   32000
#define TT   20
#define KT   32   // fp32 GEMM k-tile

typedef unsigned short u16;
typedef __attribute__((ext_vector_type(8))) short short8v;   // 8 bf16 = 4 VGPR
typedef __attribute__((ext_vector_type(4))) float f32x4;

__device__ __forceinline__ u16 f2bf(float x) {   // RNE float->bf16
  unsigned int u = __float_as_uint(x);
  return (u16)((u + 0x7FFFu + ((u >> 16) & 1u)) >> 16);
}

// ---------------------------------------------------------------------------
// init: zero outputs[:,0,:] and h0/c0
// ---------------------------------------------------------------------------
__global__ __launch_bounds__(256) void init_kernel(float* __restrict__ out,
                                                   float* __restrict__ h,
                                                   float* __restrict__ c) {
  int i = blockIdx.x * 256 + threadIdx.x;
  if (i < BB * VD) {
    int b = i / VD, v = i - b * VD;
    out[(long)b * (TT * VD) + v] = 0.f;
  }
  if (i < BB * HD) { h[i] = 0.f; c[i] = 0.f; }
}

// ---------------------------------------------------------------------------
// fp32->bf16 bulk convert (8 elems/thread)
// ---------------------------------------------------------------------------
__global__ __launch_bounds__(256) void convert_bf16_k(const float* __restrict__ src,
                                                      u16* __restrict__ dst, long n) {
  long i = ((long)blockIdx.x * 256 + threadIdx.x) * 8;
  if (i + 8 <= n) {
    float4 a = *reinterpret_cast<const float4*>(src + i);
    float4 b = *reinterpret_cast<const float4*>(src + i + 4);
    uint4 o;
    o.x = (unsigned)f2bf(a.x) | ((unsigned)f2bf(a.y) << 16);
    o.y = (unsigned)f2bf(a.z) | ((unsigned)f2bf(a.w) << 16);
    o.z = (unsigned)f2bf(b.x) | ((unsigned)f2bf(b.y) << 16);
    o.w = (unsigned)f2bf(b.z) | ((unsigned)f2bf(b.w) << 16);
    *reinterpret_cast<uint4*>(dst + i) = o;
  }
}

// ---------------------------------------------------------------------------
// Generic fp32 NT GEMM (proj)
// ---------------------------------------------------------------------------
__global__ __launch_bounds__(256) void gemm_nt(
    const float* __restrict__ A, int lda,
    const float* __restrict__ Bw, int ldb,
    const float* __restrict__ bias,
    float* __restrict__ C, long ldc, long zstride,
    int kChunk) {
  __shared__ __align__(16) float As[KT][64];
  __shared__ __align__(16) float Ws[KT][64];
  const int tid = threadIdx.x;
  const int m0 = blockIdx.y * 64, n0 = blockIdx.x * 64;
  const int k0 = blockIdx.z * kChunk, k1 = k0 + kChunk;
  const int tm = tid & 15, tn = tid >> 4;
  const int lr = tid >> 3;
  const int lk = (tid & 7) * 4;
  float acc[4][4] = {};
  for (int kt = k0; kt < k1; kt += KT) {
    __syncthreads();
    #pragma unroll
    for (int p = 0; p < 2; ++p) {
      int m = p * 32 + lr;
      float4 av = *reinterpret_cast<const float4*>(A + (long)(m0 + m) * lda + kt + lk);
      As[lk + 0][m] = av.x; As[lk + 1][m] = av.y;
      As[lk + 2][m] = av.z; As[lk + 3][m] = av.w;
      float4 wv = *reinterpret_cast<const float4*>(Bw + (long)(n0 + m) * ldb + kt + lk);
      Ws[lk + 0][m] = wv.x; Ws[lk + 1][m] = wv.y;
      Ws[lk + 2][m] = wv.z; Ws[lk + 3][m] = wv.w;
    }
    __syncthreads();
    #pragma unroll
    for (int k = 0; k < KT; ++k) {
      float4 a = *reinterpret_cast<const float4*>(&As[k][tm * 4]);
      float4 w = *reinterpret_cast<const float4*>(&Ws[k][tn * 4]);
      acc[0][0] += a.x * w.x; acc[0][1] += a.x * w.y; acc[0][2] += a.x * w.z; acc[0][3] += a.x * w.w;
      acc[1][0] += a.y * w.x; acc[1][1] += a.y * w.y; acc[1][2] += a.y * w.z; acc[1][3] += a.y * w.w;
      acc[2][0] += a.z * w.x; acc[2][1] += a.z * w.y; acc[2][2] += a.z * w.z; acc[2][3] += a.z * w.w;
      acc[3][0] += a.w * w.x; acc[3][1] += a.w * w.y; acc[3][2] += a.w * w.z; acc[3][3] += a.w * w.w;
    }
  }
  float* Cz = C + (long)blockIdx.z * zstride;
  #pragma unroll
  for (int mi = 0; mi < 4; ++mi) {
    int row = m0 + tm * 4 + mi, col = n0 + tn * 4;
    float4 o;
    o.x = acc[mi][0]; o.y = acc[mi][1]; o.z = acc[mi][2]; o.w = acc[mi][3];
    if (bias) {
      o.x += bias[col]; o.y += bias[col + 1]; o.z += bias[col + 2]; o.w += bias[col + 3];
    }
    *reinterpret_cast<float4*>(Cz + (long)row * ldc + col) = o;
  }
}

// ---------------------------------------------------------------------------
// Merged gates GEMM: one launch for x[:,:1536]@W_ih^T and x[:,1536:]@W_hh^T.
// grid (32, 1, 8); z<6 -> W_ih chunk z, z>=6 -> W_hh chunk z-6. kChunk=256.
// Writes partials P[z][64][2048]; lstm_pointwise reduces all 8.
// ---------------------------------------------------------------------------
__global__ __launch_bounds__(256) void gemm_gates(
    const float* __restrict__ x,       // [64][2048] = [emb|ctx|h]
    const float* __restrict__ Wih,     // [2048][1536]
    const float* __restrict__ Whh,     // [2048][512]
    float* __restrict__ P) {           // [8][64][2048]
  __shared__ __align__(16) float As[KT][64];
  __shared__ __align__(16) float Ws[KT][64];
  const int tid = threadIdx.x;
  const int bz = blockIdx.z;
  const int n0 = blockIdx.x * 64;
  const float* A;
  const float* Bw;
  int ldb, k0;
  if (bz < 6) { A = x;        Bw = Wih; ldb = 1536; k0 = bz * 256; }
  else        { A = x + 1536; Bw = Whh; ldb = 512;  k0 = (bz - 6) * 256; }
  const int k1 = k0 + 256;
  const int tm = tid & 15, tn = tid >> 4;
  const int lr = tid >> 3;
  const int lk = (tid & 7) * 4;
  float acc[4][4] = {};
  for (int kt = k0; kt < k1; kt += KT) {
    __syncthreads();
    #pragma unroll
    for (int p = 0; p < 2; ++p) {
      int m = p * 32 + lr;
      float4 av = *reinterpret_cast<const float4*>(A + (long)m * 2048 + kt + lk);
      As[lk + 0][m] = av.x; As[lk + 1][m] = av.y;
      As[lk + 2][m] = av.z; As[lk + 3][m] = av.w;
      float4 wv = *reinterpret_cast<const float4*>(Bw + (long)(n0 + m) * ldb + kt + lk);
      Ws[lk + 0][m] = wv.x; Ws[lk + 1][m] = wv.y;
      Ws[lk + 2][m] = wv.z; Ws[lk + 3][m] = wv.w;
    }
    __syncthreads();
    #pragma unroll
    for (int k = 0; k < KT; ++k) {
      float4 a = *reinterpret_cast<const float4*>(&As[k][tm * 4]);
      float4 w = *reinterpret_cast<const float4*>(&Ws[k][tn * 4]);
      acc[0][0] += a.x * w.x; acc[0][1] += a.x * w.y; acc[0][2] += a.x * w.z; acc[0][3] += a.x * w.w;
      acc[1][0] += a.y * w.x; acc[1][1] += a.y * w.y; acc[1][2] += a.y * w.z; acc[1][3] += a.y * w.w;
      acc[2][0] += a.z * w.x; acc[2][1] += a.z * w.y; acc[2][2] += a.z * w.z; acc[2][3] += a.z * w.w;
      acc[3][0] += a.w * w.x; acc[3][1] += a.w * w.y; acc[3][2] += a.w * w.z; acc[3][3] += a.w * w.w;
    }
  }
  float* Cz = P + (long)bz * (BB * 2048);
  #pragma unroll
  for (int mi = 0; mi < 4; ++mi) {
    int row = tm * 4 + mi, col = n0 + tn * 4;
    float4 o;
    o.x = acc[mi][0]; o.y = acc[mi][1]; o.z = acc[mi][2]; o.w = acc[mi][3];
    *reinterpret_cast<float4*>(Cz + (long)row * 2048 + col) = o;
  }
}

// ---------------------------------------------------------------------------
// fc GEMM over all 19 steps, v2: W-tile resident in VGPRs.
// grid = 500 (one 64-col n-tile per block). W read from HBM exactly once
// (64 VGPRs/lane); loop t reading hbuf (2.4 MB, L2-resident) and storing.
// Same MFMA order as before -> bit-identical output.
// ---------------------------------------------------------------------------
__global__ __launch_bounds__(256) void fc_batched_v2(
    const u16* __restrict__ hbuf,      // [19][64][512] bf16
    const u16* __restrict__ Wb,        // [32000][512] bf16
    const float* __restrict__ bias,
    float* __restrict__ out) {         // full [B][T][V] base
  const int n0 = blockIdx.x * 64;
  const int tid = threadIdx.x;
  const int wv = tid >> 6, lane = tid & 63;
  const int frow = lane & 15, fgrp = lane >> 4;

  const u16* Wrow = Wb + (long)(n0 + wv * 16 + frow) * HD;
  short8v wfr[16];
  #pragma unroll
  for (int ks = 0; ks < 16; ++ks)
    wfr[ks] = *reinterpret_cast<const short8v*>(Wrow + ks * 32 + fgrp * 8);

  const int col = n0 + wv * 16 + frow;
  const float bv = bias[col];

  for (int t = 0; t < TT - 1; ++t) {
    const u16* Arow = hbuf + ((long)t * BB + frow) * HD;
    f32x4 acc[4] = {{0.f,0.f,0.f,0.f},{0.f,0.f,0.f,0.f},{0.f,0.f,0.f,0.f},{0.f,0.f,0.f,0.f}};
    #pragma unroll 4
    for (int ks = 0; ks < 16; ++ks) {
      const int k0 = ks * 32 + fgrp * 8;
      #pragma unroll
      for (int m = 0; m < 4; ++m) {
        short8v afr = *reinterpret_cast<const short8v*>(Arow + m * 16 * HD + k0);
        acc[m] = __builtin_amdgcn_mfma_f32_16x16x32_bf16(afr, wfr[ks], acc[m], 0, 0, 0);
      }
    }
    #pragma unroll
    for (int m = 0; m < 4; ++m) {
      #pragma unroll
      for (int r = 0; r < 4; ++r) {
        int b = m * 16 + fgrp * 4 + r;
        out[((long)b * TT + (t + 1)) * VD + col] = acc[m][r] + bv;
      }
    }
  }
}

// ---------------------------------------------------------------------------
// fc fallback (per-step): fp32 weights streamed + converted in-register.
// Only used if ws_size can't hold Wbf.
// ---------------------------------------------------------------------------
__global__ __launch_bounds__(256) void fc_mfma_f32w(
    const u16* __restrict__ hb, const float* __restrict__ Wf,
    const float* __restrict__ bias, float* __restrict__ outp) {
  const int tid = threadIdx.x;
  const int n0 = blockIdx.x * 64;
  const int wv = tid >> 6, lane = tid & 63;
  const int frow = lane & 15, fgrp = lane >> 4;
  const float* Wrow = Wf + (long)(n0 + wv * 16 + frow) * HD;
  const u16*   Arow = hb + frow * HD;
  f32x4 acc[4] = {{0.f,0.f,0.f,0.f},{0.f,0.f,0.f,0.f},{0.f,0.f,0.f,0.f},{0.f,0.f,0.f,0.f}};
  #pragma unroll 2
  for (int ks = 0; ks < 16; ++ks) {
    const int k0 = ks * 32 + fgrp * 8;
    float4 w0 = *reinterpret_cast<const float4*>(Wrow + k0);
    float4 w1 = *reinterpret_cast<const float4*>(Wrow + k0 + 4);
    union { short8v v; u16 s[8]; } bf;
    bf.s[0] = f2bf(w0.x); bf.s[1] = f2bf(w0.y); bf.s[2] = f2bf(w0.z); bf.s[3] = f2bf(w0.w);
    bf.s[4] = f2bf(w1.x); bf.s[5] = f2bf(w1.y); bf.s[6] = f2bf(w1.z); bf.s[7] = f2bf(w1.w);
    #pragma unroll
    for (int m = 0; m < 4; ++m) {
      short8v afr = *reinterpret_cast<const short8v*>(Arow + m * 16 * HD + k0);
      acc[m] = __builtin_amdgcn_mfma_f32_16x16x32_bf16(afr, bf.v, acc[m], 0, 0, 0);
    }
  }
  const int col = n0 + wv * 16 + frow;
  const float bv = bias[col];
  #pragma unroll
  for (int m = 0; m < 4; ++m)
    #pragma unroll
    for (int r = 0; r < 4; ++r)
      outp[(long)(m * 16 + fgrp * 4 + r) * ((long)TT * VD) + col] = acc[m][r] + bv;
}

// ---------------------------------------------------------------------------
// Fused attention + build_x: scores, softmax, attns out, and writes
// x[b] = [emb(512) | ctx(1024) | h(512)] directly.
// ---------------------------------------------------------------------------
__global__ __launch_bounds__(512) void attn_build_x(
    const float* __restrict__ proj, const float* __restrict__ h,
    const float* __restrict__ enc, const float* __restrict__ emb,
    const int* __restrict__ caps, int t,
    float* __restrict__ attn_out, float* __restrict__ x) {
  int b = blockIdx.x;
  __shared__ float sh[HD];
  __shared__ float sc[64];
  __shared__ float sw[64];
  int tid = threadIdx.x;
  sh[tid] = h[b * HD + tid];
  __syncthreads();
  int wave = tid >> 6, lane = tid & 63;
  for (int s = wave; s < SS; s += 8) {
    const float* pr = proj + ((long)b * SS + s) * HD;
    float acc = 0.f;
    #pragma unroll
    for (int k = 0; k < HD / 64; ++k) acc += pr[lane + k * 64] * sh[lane + k * 64];
    #pragma unroll
    for (int off = 32; off; off >>= 1) acc += __shfl_down(acc, off);
    if (lane == 0) sc[s] = acc;
  }
  __syncthreads();
  if (wave == 0) {
    float v = (lane < SS) ? sc[lane] : -INFINITY;
    float m = v;
    #pragma unroll
    for (int off = 32; off; off >>= 1) m = fmaxf(m, __shfl_down(m, off));
    m = __shfl(m, 0);
    float e = (lane < SS) ? __expf(v - m) : 0.f;
    float sum = e;
    #pragma unroll
    for (int off = 32; off; off >>= 1) sum += __shfl_down(sum, off);
    sum = __shfl(sum, 0);
    float w = e / sum;
    if (lane < SS) { sw[lane] = w; attn_out[b * SS + lane] = w; }
  }
  __syncthreads();
  float* xb = x + (long)b * 2048;
  // ctx segment
  for (int e0 = tid; e0 < ENCD; e0 += 512) {
    float acc = 0.f;
    const float* eb = enc + (long)b * SS * ENCD + e0;
    #pragma unroll
    for (int s = 0; s < SS; ++s) acc += sw[s] * eb[(long)s * ENCD];
    xb[ED + e0] = acc;
  }
  // emb + h segments (tid covers 0..511 = ED = HD)
  int word = caps[b * TT + t];
  xb[tid] = emb[(long)word * ED + tid];
  xb[1536 + tid] = sh[tid];
}

// ---------------------------------------------------------------------------
// LSTM pointwise: reduce 8 split-K partials, gate math, update h,c, emit bf16 h
// ---------------------------------------------------------------------------
__global__ __launch_bounds__(256) void lstm_pointwise(
    const float* __restrict__ P, const float* __restrict__ b_ih,
    const float* __restrict__ b_hh, float* __restrict__ h,
    float* __restrict__ c, u16* __restrict__ hb) {
  int idx = blockIdx.x * 256 + threadIdx.x;  // 0..32767
  int b = idx >> 9, u = idx & 511;
  float gi = b_ih[u]        + b_hh[u];
  float gf = b_ih[u + 512]  + b_hh[u + 512];
  float gg = b_ih[u + 1024] + b_hh[u + 1024];
  float go = b_ih[u + 1536] + b_hh[u + 1536];
  #pragma unroll
  for (int ks = 0; ks < 8; ++ks) {
    const float* p = P + ((long)ks * BB + b) * 2048;
    gi += p[u]; gf += p[u + 512]; gg += p[u + 1024]; go += p[u + 1536];
  }
  float si = 1.f / (1.f + __expf(-gi));
  float sf = 1.f / (1.f + __expf(-gf));
  float so = 1.f / (1.f + __expf(-go));
  float tg = tanhf(gg);
  float c2 = sf * c[idx] + si * tg;
  float h2 = so * tanhf(c2);
  c[idx] = c2;
  h[idx] = h2;
  hb[idx] = f2bf(h2);
}

// ---------------------------------------------------------------------------
extern "C" void kernel_launch(void* const* d_in, const int* in_sizes, int n_in,
                              void* d_out_, int out_size, void* d_ws, size_t ws_size,
                              hipStream_t stream) {
  const float* enc   = (const float*)d_in[0];
  const int*   caps  = (const int*)d_in[1];
  const float* emb   = (const float*)d_in[2];
  const float* attnW = (const float*)d_in[3];
  const float* attnB = (const float*)d_in[4];
  const float* W_ih  = (const float*)d_in[5];
  const float* W_hh  = (const float*)d_in[6];
  const float* b_ih  = (const float*)d_in[7];
  const float* b_hh  = (const float*)d_in[8];
  const float* fcW   = (const float*)d_in[9];
  const float* fcb   = (const float*)d_in[10];

  float* out   = (float*)d_out_;                       // [B][T][V]
  float* attns = out + (long)BB * TT * VD;             // [T-1][B][S]

  // workspace layout
  float* ws   = (float*)d_ws;
  float* proj = ws;                                    // [B*S][H]
  float* h    = proj + (long)BB * SS * HD;
  float* c    = h + BB * HD;
  float* x    = c + BB * HD;                           // [B][2048]
  float* P    = x + BB * 2048;                         // [8][B][2048]
  u16*   hbuf = (u16*)(P + (long)8 * BB * 2048);       // [19][B][H] bf16
  u16*   Wbf  = hbuf + (long)(TT - 1) * BB * HD;       // [V][H] bf16
  size_t need = (size_t)((char*)(Wbf + (long)VD * HD) - (char*)d_ws);
  const bool use_wbf = (ws_size >= need);              // true in all observed passes

  init_kernel<<<(BB * VD + 255) / 256, 256, 0, stream>>>(out, h, c);

  if (use_wbf) {
    long n = (long)VD * HD;
    convert_bf16_k<<<(int)(n / 2048), 256, 0, stream>>>(fcW, Wbf, n);
  }

  // proj = enc @ attn_W^T + attn_b : M=3840, N=512, K=1024
  gemm_nt<<<dim3(8, 60, 1), 256, 0, stream>>>(enc, ENCD, attnW, ENCD, attnB,
                                              proj, HD, 0, ENCD);

  for (int t = 0; t < TT - 1; ++t) {
    attn_build_x<<<BB, 512, 0, stream>>>(proj, h, enc, emb, caps, t,
                                         attns + (long)t * BB * SS, x);
    gemm_gates<<<dim3(32, 1, 8), 256, 0, stream>>>(x, W_ih, W_hh, P);
    lstm_pointwise<<<128, 256, 0, stream>>>(P, b_ih, b_hh, h, c,
                                            hbuf + (long)t * BB * HD);
    if (!use_wbf) {
      fc_mfma_f32w<<<VD / 64, 256, 0, stream>>>(hbuf + (long)t * BB * HD, fcW, fcb,
                                                out + (long)(t + 1) * VD);
    }
  }

  if (use_wbf) {
    fc_batched_v2<<<500, 256, 0, stream>>>(hbuf, Wbf, fcb, out);
  }
}

// Round 7
// 1185.020 us; speedup vs baseline: 1.6477x; 1.2636x over previous
//
#include <hip/hip_runtime.h>
#include <math.h>

// Problem dims (fixed by reference)
#define BB   64
#define SS   60
#define ENCD 1024
#define ED   512
#define HD   512
#define VD   32000
#define TT   20
#define KT   32   // fp32 GEMM k-tile

typedef unsigned short u16;
typedef __attribute__((ext_vector_type(8))) short short8v;   // 8 bf16 = 4 VGPR
typedef __attribute__((ext_vector_type(4))) float f32x4;

__device__ __forceinline__ u16 f2bf(float x) {   // RNE float->bf16
  unsigned int u = __float_as_uint(x);
  return (u16)((u + 0x7FFFu + ((u >> 16) & 1u)) >> 16);
}

// ---------------------------------------------------------------------------
// init: zero outputs[:,0,:] and h0/c0
// ---------------------------------------------------------------------------
__global__ __launch_bounds__(256) void init_kernel(float* __restrict__ out,
                                                   float* __restrict__ h,
                                                   float* __restrict__ c) {
  int i = blockIdx.x * 256 + threadIdx.x;
  if (i < BB * VD) {
    int b = i / VD, v = i - b * VD;
    out[(long)b * (TT * VD) + v] = 0.f;
  }
  if (i < BB * HD) { h[i] = 0.f; c[i] = 0.f; }
}

// ---------------------------------------------------------------------------
// fp32->bf16 bulk convert (8 elems/thread)
// ---------------------------------------------------------------------------
__global__ __launch_bounds__(256) void convert_bf16_k(const float* __restrict__ src,
                                                      u16* __restrict__ dst, long n) {
  long i = ((long)blockIdx.x * 256 + threadIdx.x) * 8;
  if (i + 8 <= n) {
    float4 a = *reinterpret_cast<const float4*>(src + i);
    float4 b = *reinterpret_cast<const float4*>(src + i + 4);
    uint4 o;
    o.x = (unsigned)f2bf(a.x) | ((unsigned)f2bf(a.y) << 16);
    o.y = (unsigned)f2bf(a.z) | ((unsigned)f2bf(a.w) << 16);
    o.z = (unsigned)f2bf(b.x) | ((unsigned)f2bf(b.y) << 16);
    o.w = (unsigned)f2bf(b.z) | ((unsigned)f2bf(b.w) << 16);
    *reinterpret_cast<uint4*>(dst + i) = o;
  }
}

// ---------------------------------------------------------------------------
// Generic fp32 NT GEMM (proj)
// ---------------------------------------------------------------------------
__global__ __launch_bounds__(256) void gemm_nt(
    const float* __restrict__ A, int lda,
    const float* __restrict__ Bw, int ldb,
    const float* __restrict__ bias,
    float* __restrict__ C, long ldc, long zstride,
    int kChunk) {
  __shared__ __align__(16) float As[KT][64];
  __shared__ __align__(16) float Ws[KT][64];
  const int tid = threadIdx.x;
  const int m0 = blockIdx.y * 64, n0 = blockIdx.x * 64;
  const int k0 = blockIdx.z * kChunk, k1 = k0 + kChunk;
  const int tm = tid & 15, tn = tid >> 4;
  const int lr = tid >> 3;
  const int lk = (tid & 7) * 4;
  float acc[4][4] = {};
  for (int kt = k0; kt < k1; kt += KT) {
    __syncthreads();
    #pragma unroll
    for (int p = 0; p < 2; ++p) {
      int m = p * 32 + lr;
      float4 av = *reinterpret_cast<const float4*>(A + (long)(m0 + m) * lda + kt + lk);
      As[lk + 0][m] = av.x; As[lk + 1][m] = av.y;
      As[lk + 2][m] = av.z; As[lk + 3][m] = av.w;
      float4 wv = *reinterpret_cast<const float4*>(Bw + (long)(n0 + m) * ldb + kt + lk);
      Ws[lk + 0][m] = wv.x; Ws[lk + 1][m] = wv.y;
      Ws[lk + 2][m] = wv.z; Ws[lk + 3][m] = wv.w;
    }
    __syncthreads();
    #pragma unroll
    for (int k = 0; k < KT; ++k) {
      float4 a = *reinterpret_cast<const float4*>(&As[k][tm * 4]);
      float4 w = *reinterpret_cast<const float4*>(&Ws[k][tn * 4]);
      acc[0][0] += a.x * w.x; acc[0][1] += a.x * w.y; acc[0][2] += a.x * w.z; acc[0][3] += a.x * w.w;
      acc[1][0] += a.y * w.x; acc[1][1] += a.y * w.y; acc[1][2] += a.y * w.z; acc[1][3] += a.y * w.w;
      acc[2][0] += a.z * w.x; acc[2][1] += a.z * w.y; acc[2][2] += a.z * w.z; acc[2][3] += a.z * w.w;
      acc[3][0] += a.w * w.x; acc[3][1] += a.w * w.y; acc[3][2] += a.w * w.z; acc[3][3] += a.w * w.w;
    }
  }
  float* Cz = C + (long)blockIdx.z * zstride;
  #pragma unroll
  for (int mi = 0; mi < 4; ++mi) {
    int row = m0 + tm * 4 + mi, col = n0 + tn * 4;
    float4 o;
    o.x = acc[mi][0]; o.y = acc[mi][1]; o.z = acc[mi][2]; o.w = acc[mi][3];
    if (bias) {
      o.x += bias[col]; o.y += bias[col + 1]; o.z += bias[col + 2]; o.w += bias[col + 3];
    }
    *reinterpret_cast<float4*>(Cz + (long)row * ldc + col) = o;
  }
}

// ---------------------------------------------------------------------------
// Merged gates GEMM: one launch for x[:,:1536]@W_ih^T and x[:,1536:]@W_hh^T.
// grid (32, 1, 8); z<6 -> W_ih chunk z, z>=6 -> W_hh chunk z-6. kChunk=256.
// ---------------------------------------------------------------------------
__global__ __launch_bounds__(256) void gemm_gates(
    const float* __restrict__ x,       // [64][2048] = [emb|ctx|h]
    const float* __restrict__ Wih,     // [2048][1536]
    const float* __restrict__ Whh,     // [2048][512]
    float* __restrict__ P) {           // [8][64][2048]
  __shared__ __align__(16) float As[KT][64];
  __shared__ __align__(16) float Ws[KT][64];
  const int tid = threadIdx.x;
  const int bz = blockIdx.z;
  const int n0 = blockIdx.x * 64;
  const float* A;
  const float* Bw;
  int ldb, k0;
  if (bz < 6) { A = x;        Bw = Wih; ldb = 1536; k0 = bz * 256; }
  else        { A = x + 1536; Bw = Whh; ldb = 512;  k0 = (bz - 6) * 256; }
  const int k1 = k0 + 256;
  const int tm = tid & 15, tn = tid >> 4;
  const int lr = tid >> 3;
  const int lk = (tid & 7) * 4;
  float acc[4][4] = {};
  for (int kt = k0; kt < k1; kt += KT) {
    __syncthreads();
    #pragma unroll
    for (int p = 0; p < 2; ++p) {
      int m = p * 32 + lr;
      float4 av = *reinterpret_cast<const float4*>(A + (long)m * 2048 + kt + lk);
      As[lk + 0][m] = av.x; As[lk + 1][m] = av.y;
      As[lk + 2][m] = av.z; As[lk + 3][m] = av.w;
      float4 wv = *reinterpret_cast<const float4*>(Bw + (long)(n0 + m) * ldb + kt + lk);
      Ws[lk + 0][m] = wv.x; Ws[lk + 1][m] = wv.y;
      Ws[lk + 2][m] = wv.z; Ws[lk + 3][m] = wv.w;
    }
    __syncthreads();
    #pragma unroll
    for (int k = 0; k < KT; ++k) {
      float4 a = *reinterpret_cast<const float4*>(&As[k][tm * 4]);
      float4 w = *reinterpret_cast<const float4*>(&Ws[k][tn * 4]);
      acc[0][0] += a.x * w.x; acc[0][1] += a.x * w.y; acc[0][2] += a.x * w.z; acc[0][3] += a.x * w.w;
      acc[1][0] += a.y * w.x; acc[1][1] += a.y * w.y; acc[1][2] += a.y * w.z; acc[1][3] += a.y * w.w;
      acc[2][0] += a.z * w.x; acc[2][1] += a.z * w.y; acc[2][2] += a.z * w.z; acc[2][3] += a.z * w.w;
      acc[3][0] += a.w * w.x; acc[3][1] += a.w * w.y; acc[3][2] += a.w * w.z; acc[3][3] += a.w * w.w;
    }
  }
  float* Cz = P + (long)bz * (BB * 2048);
  #pragma unroll
  for (int mi = 0; mi < 4; ++mi) {
    int row = tm * 4 + mi, col = n0 + tn * 4;
    float4 o;
    o.x = acc[mi][0]; o.y = acc[mi][1]; o.z = acc[mi][2]; o.w = acc[mi][3];
    *reinterpret_cast<float4*>(Cz + (long)row * 2048 + col) = o;
  }
}

// ---------------------------------------------------------------------------
// fc GEMM, m97-style: 64M x 256N tile, K-step 64, double-buffered LDS via
// global_load_lds(16B), inverse-swizzled source + XOR-swizzled ds_read_b128.
// grid = 2375 flat (125 n-tiles x 19 t), bijective chunked XCD swizzle (m204)
// so all 19 t-blocks of one n-tile live on one XCD's L2 -> W HBM-read ~once.
// Same MFMA K-order as rounds 2-6 -> bit-identical output.
// LDS 80 KB: A[2] @ 0/8K (64x64 bf16), W[2] @ 16K/48K (256x64 bf16).
// ---------------------------------------------------------------------------
__global__ __launch_bounds__(256) void fc_tiled(
    const u16* __restrict__ hbuf,      // [19][64][512] bf16
    const u16* __restrict__ Wb,        // [32000][512] bf16
    const float* __restrict__ bias,
    float* __restrict__ out) {         // full [B][T][V] base
  __shared__ __align__(16) u16 lds[40960];   // 80 KB
  const int tid = threadIdx.x;
  const int bid = blockIdx.x;
  // m204 bijective chunked swizzle: nwg=2375=8*296+7 -> xcd<7 chunk 297, xcd7 296
  const int xcd = bid & 7, loc = bid >> 3;
  const int wg = (xcd < 7) ? (xcd * 297 + loc) : (2079 + loc);
  const int n_tile = wg / 19, t = wg - n_tile * 19;
  const int n0 = n_tile * 256;

  const u16* Ab = hbuf + (long)t * (BB * HD);
  const u16* Wbase = Wb + (long)n0 * HD;

  const int w = tid >> 6, lane = tid & 63;
  const int frow = lane & 15, fgrp = lane >> 4;
  const int srow = tid >> 3, sslot = tid & 7;
  const int scol = (sslot ^ (srow & 7)) * 8;   // inverse-swizzled source col
  char* ldsb = (char*)lds;

#define FC_STAGE(buf, kc) do {                                                    \
    _Pragma("unroll")                                                             \
    for (int ii = 0; ii < 2; ++ii) {                                              \
      __builtin_amdgcn_global_load_lds(                                           \
        (const __attribute__((address_space(1))) void*)(Ab + (ii * 32 + srow) * HD + (kc) + scol), \
        (__attribute__((address_space(3))) void*)(ldsb + (buf) * 8192 + ii * 4096 + tid * 16), \
        16, 0, 0);                                                                \
    }                                                                             \
    _Pragma("unroll")                                                             \
    for (int ii = 0; ii < 8; ++ii) {                                              \
      __builtin_amdgcn_global_load_lds(                                           \
        (const __attribute__((address_space(1))) void*)(Wbase + (long)(ii * 32 + srow) * HD + (kc) + scol), \
        (__attribute__((address_space(3))) void*)(ldsb + 16384 + (buf) * 32768 + ii * 4096 + tid * 16), \
        16, 0, 0);                                                                \
    }                                                                             \
  } while (0)

  f32x4 acc[4][4] = {};

  FC_STAGE(0, 0);
  asm volatile("s_waitcnt vmcnt(0)");
  __syncthreads();

  for (int kc = 0; kc < 8; ++kc) {
    const int cur = kc & 1;
    if (kc < 7) FC_STAGE(cur ^ 1, (kc + 1) * 64);
    const char* Abuf = ldsb + cur * 8192;
    const char* Wbuf = ldsb + 16384 + cur * 32768;
    #pragma unroll
    for (int ks = 0; ks < 2; ++ks) {
      const int slot = ((ks * 4 + fgrp) ^ (frow & 7)) * 16;
      short8v af[4], wf[4];
      #pragma unroll
      for (int m = 0; m < 4; ++m)
        af[m] = *reinterpret_cast<const short8v*>(Abuf + (m * 16 + frow) * 128 + slot);
      #pragma unroll
      for (int n = 0; n < 4; ++n)
        wf[n] = *reinterpret_cast<const short8v*>(Wbuf + (w * 64 + n * 16 + frow) * 128 + slot);
      #pragma unroll
      for (int m = 0; m < 4; ++m)
        #pragma unroll
        for (int n = 0; n < 4; ++n)
          acc[m][n] = __builtin_amdgcn_mfma_f32_16x16x32_bf16(af[m], wf[n], acc[m][n], 0, 0, 0);
    }
    asm volatile("s_waitcnt vmcnt(0)");
    __syncthreads();
  }

  #pragma unroll
  for (int n = 0; n < 4; ++n) {
    const int col = n0 + w * 64 + n * 16 + frow;
    const float bv = bias[col];
    #pragma unroll
    for (int m = 0; m < 4; ++m) {
      #pragma unroll
      for (int r = 0; r < 4; ++r) {
        int b = m * 16 + fgrp * 4 + r;
        out[((long)b * TT + (t + 1)) * VD + col] = acc[m][n][r] + bv;
      }
    }
  }
#undef FC_STAGE
}

// ---------------------------------------------------------------------------
// fc fallback (per-step): fp32 weights streamed + converted in-register.
// Only used if ws_size can't hold Wbf (never observed).
// ---------------------------------------------------------------------------
__global__ __launch_bounds__(256) void fc_mfma_f32w(
    const u16* __restrict__ hb, const float* __restrict__ Wf,
    const float* __restrict__ bias, float* __restrict__ outp) {
  const int tid = threadIdx.x;
  const int n0 = blockIdx.x * 64;
  const int wv = tid >> 6, lane = tid & 63;
  const int frow = lane & 15, fgrp = lane >> 4;
  const float* Wrow = Wf + (long)(n0 + wv * 16 + frow) * HD;
  const u16*   Arow = hb + frow * HD;
  f32x4 acc[4] = {{0.f,0.f,0.f,0.f},{0.f,0.f,0.f,0.f},{0.f,0.f,0.f,0.f},{0.f,0.f,0.f,0.f}};
  #pragma unroll 2
  for (int ks = 0; ks < 16; ++ks) {
    const int k0 = ks * 32 + fgrp * 8;
    float4 w0 = *reinterpret_cast<const float4*>(Wrow + k0);
    float4 w1 = *reinterpret_cast<const float4*>(Wrow + k0 + 4);
    union { short8v v; u16 s[8]; } bf;
    bf.s[0] = f2bf(w0.x); bf.s[1] = f2bf(w0.y); bf.s[2] = f2bf(w0.z); bf.s[3] = f2bf(w0.w);
    bf.s[4] = f2bf(w1.x); bf.s[5] = f2bf(w1.y); bf.s[6] = f2bf(w1.z); bf.s[7] = f2bf(w1.w);
    #pragma unroll
    for (int m = 0; m < 4; ++m) {
      short8v afr = *reinterpret_cast<const short8v*>(Arow + m * 16 * HD + k0);
      acc[m] = __builtin_amdgcn_mfma_f32_16x16x32_bf16(afr, bf.v, acc[m], 0, 0, 0);
    }
  }
  const int col = n0 + wv * 16 + frow;
  const float bv = bias[col];
  #pragma unroll
  for (int m = 0; m < 4; ++m)
    #pragma unroll
    for (int r = 0; r < 4; ++r)
      outp[(long)(m * 16 + fgrp * 4 + r) * ((long)TT * VD) + col] = acc[m][r] + bv;
}

// ---------------------------------------------------------------------------
// Fused LSTM(t-1) + attention(t) + build_x(t). grid 64 (one block per b),
// 512 threads. For t>0: reduce P partials, gate math, update c, h -> sh/hbuf.
// Then attention with sh, write attns and x = [emb|ctx|h].
// ---------------------------------------------------------------------------
__global__ __launch_bounds__(512) void fused_attn_lstm(
    const float* __restrict__ proj, const float* __restrict__ enc,
    const float* __restrict__ emb, const int* __restrict__ caps, int t,
    const float* __restrict__ P, const float* __restrict__ b_ih,
    const float* __restrict__ b_hh, float* __restrict__ c,
    u16* __restrict__ hbuf_prev,       // hbuf + (t-1)*B*H (unused for t=0)
    float* __restrict__ attn_out, float* __restrict__ x) {
  int b = blockIdx.x;
  __shared__ float sh[HD];
  __shared__ float sc[64];
  __shared__ float sw[64];
  int tid = threadIdx.x;
  if (t > 0) {
    int u = tid;                        // 512 threads = HD units
    float gi = b_ih[u]        + b_hh[u];
    float gf = b_ih[u + 512]  + b_hh[u + 512];
    float gg = b_ih[u + 1024] + b_hh[u + 1024];
    float go = b_ih[u + 1536] + b_hh[u + 1536];
    #pragma unroll
    for (int ks = 0; ks < 8; ++ks) {
      const float* p = P + ((long)ks * BB + b) * 2048;
      gi += p[u]; gf += p[u + 512]; gg += p[u + 1024]; go += p[u + 1536];
    }
    float si = 1.f / (1.f + __expf(-gi));
    float sf = 1.f / (1.f + __expf(-gf));
    float so = 1.f / (1.f + __expf(-go));
    float tg = tanhf(gg);
    float c2 = sf * c[b * HD + u] + si * tg;
    float h2 = so * tanhf(c2);
    c[b * HD + u] = c2;
    sh[u] = h2;
    hbuf_prev[b * HD + u] = f2bf(h2);
  } else {
    sh[tid] = 0.f;
  }
  __syncthreads();
  int wave = tid >> 6, lane = tid & 63;
  for (int s = wave; s < SS; s += 8) {
    const float* pr = proj + ((long)b * SS + s) * HD;
    float acc = 0.f;
    #pragma unroll
    for (int k = 0; k < HD / 64; ++k) acc += pr[lane + k * 64] * sh[lane + k * 64];
    #pragma unroll
    for (int off = 32; off; off >>= 1) acc += __shfl_down(acc, off);
    if (lane == 0) sc[s] = acc;
  }
  __syncthreads();
  if (wave == 0) {
    float v = (lane < SS) ? sc[lane] : -INFINITY;
    float m = v;
    #pragma unroll
    for (int off = 32; off; off >>= 1) m = fmaxf(m, __shfl_down(m, off));
    m = __shfl(m, 0);
    float e = (lane < SS) ? __expf(v - m) : 0.f;
    float sum = e;
    #pragma unroll
    for (int off = 32; off; off >>= 1) sum += __shfl_down(sum, off);
    sum = __shfl(sum, 0);
    float wv = e / sum;
    if (lane < SS) { sw[lane] = wv; attn_out[b * SS + lane] = wv; }
  }
  __syncthreads();
  float* xb = x + (long)b * 2048;
  for (int e0 = tid; e0 < ENCD; e0 += 512) {
    float acc = 0.f;
    const float* eb = enc + (long)b * SS * ENCD + e0;
    #pragma unroll
    for (int s = 0; s < SS; ++s) acc += sw[s] * eb[(long)s * ENCD];
    xb[ED + e0] = acc;
  }
  int word = caps[b * TT + t];
  xb[tid] = emb[(long)word * ED + tid];
  xb[1536 + tid] = sh[tid];
}

// ---------------------------------------------------------------------------
// LSTM pointwise (final step only): reduce partials, update h,c, emit bf16 h
// ---------------------------------------------------------------------------
__global__ __launch_bounds__(256) void lstm_pointwise(
    const float* __restrict__ P, const float* __restrict__ b_ih,
    const float* __restrict__ b_hh, float* __restrict__ h,
    float* __restrict__ c, u16* __restrict__ hb) {
  int idx = blockIdx.x * 256 + threadIdx.x;  // 0..32767
  int b = idx >> 9, u = idx & 511;
  float gi = b_ih[u]        + b_hh[u];
  float gf = b_ih[u + 512]  + b_hh[u + 512];
  float gg = b_ih[u + 1024] + b_hh[u + 1024];
  float go = b_ih[u + 1536] + b_hh[u + 1536];
  #pragma unroll
  for (int ks = 0; ks < 8; ++ks) {
    const float* p = P + ((long)ks * BB + b) * 2048;
    gi += p[u]; gf += p[u + 512]; gg += p[u + 1024]; go += p[u + 1536];
  }
  float si = 1.f / (1.f + __expf(-gi));
  float sf = 1.f / (1.f + __expf(-gf));
  float so = 1.f / (1.f + __expf(-go));
  float tg = tanhf(gg);
  float c2 = sf * c[idx] + si * tg;
  float h2 = so * tanhf(c2);
  c[idx] = c2;
  h[idx] = h2;
  hb[idx] = f2bf(h2);
}

// ---------------------------------------------------------------------------
extern "C" void kernel_launch(void* const* d_in, const int* in_sizes, int n_in,
                              void* d_out_, int out_size, void* d_ws, size_t ws_size,
                              hipStream_t stream) {
  const float* enc   = (const float*)d_in[0];
  const int*   caps  = (const int*)d_in[1];
  const float* emb   = (const float*)d_in[2];
  const float* attnW = (const float*)d_in[3];
  const float* attnB = (const float*)d_in[4];
  const float* W_ih  = (const float*)d_in[5];
  const float* W_hh  = (const float*)d_in[6];
  const float* b_ih  = (const float*)d_in[7];
  const float* b_hh  = (const float*)d_in[8];
  const float* fcW   = (const float*)d_in[9];
  const float* fcb   = (const float*)d_in[10];

  float* out   = (float*)d_out_;                       // [B][T][V]
  float* attns = out + (long)BB * TT * VD;             // [T-1][B][S]

  // workspace layout
  float* ws   = (float*)d_ws;
  float* proj = ws;                                    // [B*S][H]
  float* h    = proj + (long)BB * SS * HD;
  float* c    = h + BB * HD;
  float* x    = c + BB * HD;                           // [B][2048]
  float* P    = x + BB * 2048;                         // [8][B][2048]
  u16*   hbuf = (u16*)(P + (long)8 * BB * 2048);       // [19][B][H] bf16
  u16*   Wbf  = hbuf + (long)(TT - 1) * BB * HD;       // [V][H] bf16
  size_t need = (size_t)((char*)(Wbf + (long)VD * HD) - (char*)d_ws);
  const bool use_wbf = (ws_size >= need);              // true in all observed passes

  init_kernel<<<(BB * VD + 255) / 256, 256, 0, stream>>>(out, h, c);

  if (use_wbf) {
    long n = (long)VD * HD;
    convert_bf16_k<<<(int)(n / 2048), 256, 0, stream>>>(fcW, Wbf, n);
  }

  // proj = enc @ attn_W^T + attn_b : M=3840, N=512, K=1024
  gemm_nt<<<dim3(8, 60, 1), 256, 0, stream>>>(enc, ENCD, attnW, ENCD, attnB,
                                              proj, HD, 0, ENCD);

  for (int t = 0; t < TT - 1; ++t) {
    u16* hbp = hbuf + (long)(t > 0 ? t - 1 : 0) * BB * HD;
    fused_attn_lstm<<<BB, 512, 0, stream>>>(proj, enc, emb, caps, t,
                                            P, b_ih, b_hh, c, hbp,
                                            attns + (long)t * BB * SS, x);
    gemm_gates<<<dim3(32, 1, 8), 256, 0, stream>>>(x, W_ih, W_hh, P);
  }
  // final LSTM step (t = 18) -> hbuf[18]
  lstm_pointwise<<<128, 256, 0, stream>>>(P, b_ih, b_hh, h, c,
                                          hbuf + (long)(TT - 2) * BB * HD);

  if (use_wbf) {
    fc_tiled<<<125 * 19, 256, 0, stream>>>(hbuf, Wbf, fcb, out);
  } else {
    for (int t = 0; t < TT - 1; ++t)
      fc_mfma_f32w<<<VD / 64, 256, 0, stream>>>(hbuf + (long)t * BB * HD, fcW, fcb,
                                                out + (long)(t + 1) * VD);
  }
}

// Round 8
// 1013.676 us; speedup vs baseline: 1.9263x; 1.1690x over previous
//
#include <hip/hip_runtime.h>
#include <math.h>

// Problem dims (fixed by reference)
#define BB   64
#define SS   60
#define ENCD 1024
#define ED   512
#define HD   512
#define VD   32000
#define TT   20
#define KT   32   // fp32 GEMM k-tile

typedef unsigned short u16;
typedef __attribute__((ext_vector_type(8))) short short8v;   // 8 bf16 = 4 VGPR
typedef __attribute__((ext_vector_type(4))) float f32x4;

__device__ __forceinline__ u16 f2bf(float x) {   // RNE float->bf16
  unsigned int u = __float_as_uint(x);
  return (u16)((u + 0x7FFFu + ((u >> 16) & 1u)) >> 16);
}
__device__ __forceinline__ float bf2f(u16 b) {
  return __uint_as_float((unsigned)b << 16);
}

// ---------------------------------------------------------------------------
// init: zero outputs[:,0,:] and h0/c0
// ---------------------------------------------------------------------------
__global__ __launch_bounds__(256) void init_kernel(float* __restrict__ out,
                                                   float* __restrict__ h,
                                                   float* __restrict__ c) {
  int i = blockIdx.x * 256 + threadIdx.x;
  if (i < BB * VD) {
    int b = i / VD, v = i - b * VD;
    out[(long)b * (TT * VD) + v] = 0.f;
  }
  if (i < BB * HD) { h[i] = 0.f; c[i] = 0.f; }
}

// ---------------------------------------------------------------------------
// fp32->bf16 bulk convert (8 elems/thread)
// ---------------------------------------------------------------------------
__global__ __launch_bounds__(256) void convert_bf16_k(const float* __restrict__ src,
                                                      u16* __restrict__ dst, long n) {
  long i = ((long)blockIdx.x * 256 + threadIdx.x) * 8;
  if (i + 8 <= n) {
    float4 a = *reinterpret_cast<const float4*>(src + i);
    float4 b = *reinterpret_cast<const float4*>(src + i + 4);
    uint4 o;
    o.x = (unsigned)f2bf(a.x) | ((unsigned)f2bf(a.y) << 16);
    o.y = (unsigned)f2bf(a.z) | ((unsigned)f2bf(a.w) << 16);
    o.z = (unsigned)f2bf(b.x) | ((unsigned)f2bf(b.y) << 16);
    o.w = (unsigned)f2bf(b.z) | ((unsigned)f2bf(b.w) << 16);
    *reinterpret_cast<uint4*>(dst + i) = o;
  }
}

// ---------------------------------------------------------------------------
// Build combined gates weight split: Wg[n][k] = k<1536 ? W_ih[n][k]
//                                              : W_hh[n][k-1536]
// wb = bf16(W), we = bf16(W - fp32(wb)).  grid 2048 x 256thr (8 cols/thr).
// ---------------------------------------------------------------------------
__global__ __launch_bounds__(256) void split_wg_k(
    const float* __restrict__ Wih, const float* __restrict__ Whh,
    u16* __restrict__ wb, u16* __restrict__ we) {
  int n = blockIdx.x;
  int k0 = threadIdx.x * 8;
  #pragma unroll
  for (int j = 0; j < 8; ++j) {
    int k = k0 + j;
    float v = (k < 1536) ? Wih[(long)n * 1536 + k] : Whh[(long)n * 512 + (k - 1536)];
    u16 b = f2bf(v);
    wb[(long)n * 2048 + k] = b;
    we[(long)n * 2048 + k] = f2bf(v - bf2f(b));
  }
}

// ---------------------------------------------------------------------------
// Generic fp32 NT GEMM (proj; also gates fallback)
// ---------------------------------------------------------------------------
__global__ __launch_bounds__(256) void gemm_nt(
    const float* __restrict__ A, int lda,
    const float* __restrict__ Bw, int ldb,
    const float* __restrict__ bias,
    float* __restrict__ C, long ldc, long zstride,
    int kChunk) {
  __shared__ __align__(16) float As[KT][64];
  __shared__ __align__(16) float Ws[KT][64];
  const int tid = threadIdx.x;
  const int m0 = blockIdx.y * 64, n0 = blockIdx.x * 64;
  const int k0 = blockIdx.z * kChunk, k1 = k0 + kChunk;
  const int tm = tid & 15, tn = tid >> 4;
  const int lr = tid >> 3;
  const int lk = (tid & 7) * 4;
  float acc[4][4] = {};
  for (int kt = k0; kt < k1; kt += KT) {
    __syncthreads();
    #pragma unroll
    for (int p = 0; p < 2; ++p) {
      int m = p * 32 + lr;
      float4 av = *reinterpret_cast<const float4*>(A + (long)(m0 + m) * lda + kt + lk);
      As[lk + 0][m] = av.x; As[lk + 1][m] = av.y;
      As[lk + 2][m] = av.z; As[lk + 3][m] = av.w;
      float4 wv = *reinterpret_cast<const float4*>(Bw + (long)(n0 + m) * ldb + kt + lk);
      Ws[lk + 0][m] = wv.x; Ws[lk + 1][m] = wv.y;
      Ws[lk + 2][m] = wv.z; Ws[lk + 3][m] = wv.w;
    }
    __syncthreads();
    #pragma unroll
    for (int k = 0; k < KT; ++k) {
      float4 a = *reinterpret_cast<const float4*>(&As[k][tm * 4]);
      float4 w = *reinterpret_cast<const float4*>(&Ws[k][tn * 4]);
      acc[0][0] += a.x * w.x; acc[0][1] += a.x * w.y; acc[0][2] += a.x * w.z; acc[0][3] += a.x * w.w;
      acc[1][0] += a.y * w.x; acc[1][1] += a.y * w.y; acc[1][2] += a.y * w.z; acc[1][3] += a.y * w.w;
      acc[2][0] += a.z * w.x; acc[2][1] += a.z * w.y; acc[2][2] += a.z * w.z; acc[2][3] += a.z * w.w;
      acc[3][0] += a.w * w.x; acc[3][1] += a.w * w.y; acc[3][2] += a.w * w.z; acc[3][3] += a.w * w.w;
    }
  }
  float* Cz = C + (long)blockIdx.z * zstride;
  #pragma unroll
  for (int mi = 0; mi < 4; ++mi) {
    int row = m0 + tm * 4 + mi, col = n0 + tn * 4;
    float4 o;
    o.x = acc[mi][0]; o.y = acc[mi][1]; o.z = acc[mi][2]; o.w = acc[mi][3];
    if (bias) {
      o.x += bias[col]; o.y += bias[col + 1]; o.z += bias[col + 2]; o.w += bias[col + 3];
    }
    *reinterpret_cast<float4*>(Cz + (long)row * ldc + col) = o;
  }
}

// ---------------------------------------------------------------------------
// Gates fallback (fp32 vector GEMM), exact R7 path.
// ---------------------------------------------------------------------------
__global__ __launch_bounds__(256) void gemm_gates(
    const float* __restrict__ x,
    const float* __restrict__ Wih,
    const float* __restrict__ Whh,
    float* __restrict__ P) {
  __shared__ __align__(16) float As[KT][64];
  __shared__ __align__(16) float Ws[KT][64];
  const int tid = threadIdx.x;
  const int bz = blockIdx.z;
  const int n0 = blockIdx.x * 64;
  const float* A;
  const float* Bw;
  int ldb, k0;
  if (bz < 6) { A = x;        Bw = Wih; ldb = 1536; k0 = bz * 256; }
  else        { A = x + 1536; Bw = Whh; ldb = 512;  k0 = (bz - 6) * 256; }
  const int k1 = k0 + 256;
  const int tm = tid & 15, tn = tid >> 4;
  const int lr = tid >> 3;
  const int lk = (tid & 7) * 4;
  float acc[4][4] = {};
  for (int kt = k0; kt < k1; kt += KT) {
    __syncthreads();
    #pragma unroll
    for (int p = 0; p < 2; ++p) {
      int m = p * 32 + lr;
      float4 av = *reinterpret_cast<const float4*>(A + (long)m * 2048 + kt + lk);
      As[lk + 0][m] = av.x; As[lk + 1][m] = av.y;
      As[lk + 2][m] = av.z; As[lk + 3][m] = av.w;
      float4 wv = *reinterpret_cast<const float4*>(Bw + (long)(n0 + m) * ldb + kt + lk);
      Ws[lk + 0][m] = wv.x; Ws[lk + 1][m] = wv.y;
      Ws[lk + 2][m] = wv.z; Ws[lk + 3][m] = wv.w;
    }
    __syncthreads();
    #pragma unroll
    for (int k = 0; k < KT; ++k) {
      float4 a = *reinterpret_cast<const float4*>(&As[k][tm * 4]);
      float4 w = *reinterpret_cast<const float4*>(&Ws[k][tn * 4]);
      acc[0][0] += a.x * w.x; acc[0][1] += a.x * w.y; acc[0][2] += a.x * w.z; acc[0][3] += a.x * w.w;
      acc[1][0] += a.y * w.x; acc[1][1] += a.y * w.y; acc[1][2] += a.y * w.z; acc[1][3] += a.y * w.w;
      acc[2][0] += a.z * w.x; acc[2][1] += a.z * w.y; acc[2][2] += a.z * w.z; acc[2][3] += a.z * w.w;
      acc[3][0] += a.w * w.x; acc[3][1] += a.w * w.y; acc[3][2] += a.w * w.z; acc[3][3] += a.w * w.w;
    }
  }
  float* Cz = P + (long)bz * (BB * 2048);
  #pragma unroll
  for (int mi = 0; mi < 4; ++mi) {
    int row = tm * 4 + mi, col = n0 + tn * 4;
    float4 o;
    o.x = acc[mi][0]; o.y = acc[mi][1]; o.z = acc[mi][2]; o.w = acc[mi][3];
    *reinterpret_cast<float4*>(Cz + (long)row * 2048 + col) = o;
  }
}

// ---------------------------------------------------------------------------
// Gates GEMM, split-bf16 MFMA: P[z] = xb.Wb + xe.Wb + xb.We  (K-chunk 256)
// Structure cloned from fc_tiled (proven): 64Mx64N tile, K-step 64,
// double-buffered global_load_lds(16B), inverse-swizzled source +
// XOR-swizzled ds_read_b128.  grid (32, 1, 8), 256 thr.
// LDS 64KB: Abf/Aer/Bbf/Ber each [2][64x64 bf16] at 0/16K/32K/48K.
// ---------------------------------------------------------------------------
__global__ __launch_bounds__(256) void gates_mfma(
    const u16* __restrict__ xb, const u16* __restrict__ xe,   // [64][2048]
    const u16* __restrict__ wb, const u16* __restrict__ we,   // [2048][2048]
    float* __restrict__ P) {                                  // [8][64][2048]
  __shared__ __align__(16) u16 lds[32768];   // 64 KB
  const int tid = threadIdx.x;
  const int n0 = blockIdx.x * 64;
  const int kz = blockIdx.z * 256;
  const int w = tid >> 6, lane = tid & 63;
  const int frow = lane & 15, fgrp = lane >> 4;
  const int srow = tid >> 3, sslot = tid & 7;
  const int scol = (sslot ^ (srow & 7)) * 8;
  char* L = (char*)lds;

#define GT_STAGE(buf, kc) do {                                                     \
    _Pragma("unroll")                                                              \
    for (int ii = 0; ii < 2; ++ii) {                                               \
      int r_ = ii * 32 + srow;                                                     \
      __builtin_amdgcn_global_load_lds(                                            \
        (const __attribute__((address_space(1))) void*)(xb + (long)r_ * 2048 + (kc) + scol), \
        (__attribute__((address_space(3))) void*)(L + (buf) * 8192 + ii * 4096 + tid * 16), 16, 0, 0); \
      __builtin_amdgcn_global_load_lds(                                            \
        (const __attribute__((address_space(1))) void*)(xe + (long)r_ * 2048 + (kc) + scol), \
        (__attribute__((address_space(3))) void*)(L + 16384 + (buf) * 8192 + ii * 4096 + tid * 16), 16, 0, 0); \
      __builtin_amdgcn_global_load_lds(                                            \
        (const __attribute__((address_space(1))) void*)(wb + (long)(n0 + r_) * 2048 + (kc) + scol), \
        (__attribute__((address_space(3))) void*)(L + 32768 + (buf) * 8192 + ii * 4096 + tid * 16), 16, 0, 0); \
      __builtin_amdgcn_global_load_lds(                                            \
        (const __attribute__((address_space(1))) void*)(we + (long)(n0 + r_) * 2048 + (kc) + scol), \
        (__attribute__((address_space(3))) void*)(L + 49152 + (buf) * 8192 + ii * 4096 + tid * 16), 16, 0, 0); \
    }                                                                              \
  } while (0)

  f32x4 acc[4] = {{0.f,0.f,0.f,0.f},{0.f,0.f,0.f,0.f},{0.f,0.f,0.f,0.f},{0.f,0.f,0.f,0.f}};

  GT_STAGE(0, kz);
  asm volatile("s_waitcnt vmcnt(0)");
  __syncthreads();

  for (int kc = 0; kc < 4; ++kc) {
    const int cur = kc & 1;
    if (kc < 3) GT_STAGE(cur ^ 1, kz + (kc + 1) * 64);
    const char* Ab = L + cur * 8192;
    const char* Ae = L + 16384 + cur * 8192;
    const char* Bb = L + 32768 + cur * 8192;
    const char* Be = L + 49152 + cur * 8192;
    #pragma unroll
    for (int ks = 0; ks < 2; ++ks) {
      const int slot = ((ks * 4 + fgrp) ^ (frow & 7)) * 16;
      const int brow = (w * 16 + frow) * 128 + slot;
      short8v bbf = *reinterpret_cast<const short8v*>(Bb + brow);
      short8v bef = *reinterpret_cast<const short8v*>(Be + brow);
      #pragma unroll
      for (int m = 0; m < 4; ++m) {
        const int arow = (m * 16 + frow) * 128 + slot;
        short8v abf = *reinterpret_cast<const short8v*>(Ab + arow);
        short8v aef = *reinterpret_cast<const short8v*>(Ae + arow);
        acc[m] = __builtin_amdgcn_mfma_f32_16x16x32_bf16(abf, bbf, acc[m], 0, 0, 0);
        acc[m] = __builtin_amdgcn_mfma_f32_16x16x32_bf16(aef, bbf, acc[m], 0, 0, 0);
        acc[m] = __builtin_amdgcn_mfma_f32_16x16x32_bf16(abf, bef, acc[m], 0, 0, 0);
      }
    }
    asm volatile("s_waitcnt vmcnt(0)");
    __syncthreads();
  }

  float* Pz = P + (long)blockIdx.z * (BB * 2048);
  const int col = n0 + w * 16 + frow;
  #pragma unroll
  for (int m = 0; m < 4; ++m)
    #pragma unroll
    for (int r = 0; r < 4; ++r)
      Pz[(long)(m * 16 + fgrp * 4 + r) * 2048 + col] = acc[m][r];
#undef GT_STAGE
}

// ---------------------------------------------------------------------------
// fc GEMM, m97-style (unchanged from R7, proven).
// ---------------------------------------------------------------------------
__global__ __launch_bounds__(256) void fc_tiled(
    const u16* __restrict__ hbuf, const u16* __restrict__ Wb,
    const float* __restrict__ bias, float* __restrict__ out) {
  __shared__ __align__(16) u16 lds[40960];   // 80 KB
  const int tid = threadIdx.x;
  const int bid = blockIdx.x;
  const int xcd = bid & 7, loc = bid >> 3;
  const int wg = (xcd < 7) ? (xcd * 297 + loc) : (2079 + loc);
  const int n_tile = wg / 19, t = wg - n_tile * 19;
  const int n0 = n_tile * 256;

  const u16* Ab = hbuf + (long)t * (BB * HD);
  const u16* Wbase = Wb + (long)n0 * HD;

  const int w = tid >> 6, lane = tid & 63;
  const int frow = lane & 15, fgrp = lane >> 4;
  const int srow = tid >> 3, sslot = tid & 7;
  const int scol = (sslot ^ (srow & 7)) * 8;
  char* ldsb = (char*)lds;

#define FC_STAGE(buf, kc) do {                                                    \
    _Pragma("unroll")                                                             \
    for (int ii = 0; ii < 2; ++ii) {                                              \
      __builtin_amdgcn_global_load_lds(                                           \
        (const __attribute__((address_space(1))) void*)(Ab + (ii * 32 + srow) * HD + (kc) + scol), \
        (__attribute__((address_space(3))) void*)(ldsb + (buf) * 8192 + ii * 4096 + tid * 16), \
        16, 0, 0);                                                                \
    }                                                                             \
    _Pragma("unroll")                                                             \
    for (int ii = 0; ii < 8; ++ii) {                                              \
      __builtin_amdgcn_global_load_lds(                                           \
        (const __attribute__((address_space(1))) void*)(Wbase + (long)(ii * 32 + srow) * HD + (kc) + scol), \
        (__attribute__((address_space(3))) void*)(ldsb + 16384 + (buf) * 32768 + ii * 4096 + tid * 16), \
        16, 0, 0);                                                                \
    }                                                                             \
  } while (0)

  f32x4 acc[4][4] = {};

  FC_STAGE(0, 0);
  asm volatile("s_waitcnt vmcnt(0)");
  __syncthreads();

  for (int kc = 0; kc < 8; ++kc) {
    const int cur = kc & 1;
    if (kc < 7) FC_STAGE(cur ^ 1, (kc + 1) * 64);
    const char* Abuf = ldsb + cur * 8192;
    const char* Wbuf = ldsb + 16384 + cur * 32768;
    #pragma unroll
    for (int ks = 0; ks < 2; ++ks) {
      const int slot = ((ks * 4 + fgrp) ^ (frow & 7)) * 16;
      short8v af[4], wf[4];
      #pragma unroll
      for (int m = 0; m < 4; ++m)
        af[m] = *reinterpret_cast<const short8v*>(Abuf + (m * 16 + frow) * 128 + slot);
      #pragma unroll
      for (int n = 0; n < 4; ++n)
        wf[n] = *reinterpret_cast<const short8v*>(Wbuf + (w * 64 + n * 16 + frow) * 128 + slot);
      #pragma unroll
      for (int m = 0; m < 4; ++m)
        #pragma unroll
        for (int n = 0; n < 4; ++n)
          acc[m][n] = __builtin_amdgcn_mfma_f32_16x16x32_bf16(af[m], wf[n], acc[m][n], 0, 0, 0);
    }
    asm volatile("s_waitcnt vmcnt(0)");
    __syncthreads();
  }

  #pragma unroll
  for (int n = 0; n < 4; ++n) {
    const int col = n0 + w * 64 + n * 16 + frow;
    const float bv = bias[col];
    #pragma unroll
    for (int m = 0; m < 4; ++m) {
      #pragma unroll
      for (int r = 0; r < 4; ++r) {
        int b = m * 16 + fgrp * 4 + r;
        out[((long)b * TT + (t + 1)) * VD + col] = acc[m][n][r] + bv;
      }
    }
  }
#undef FC_STAGE
}

// ---------------------------------------------------------------------------
// fc fallback (per-step) — only if ws can't hold Wbf (never observed).
// ---------------------------------------------------------------------------
__global__ __launch_bounds__(256) void fc_mfma_f32w(
    const u16* __restrict__ hb, const float* __restrict__ Wf,
    const float* __restrict__ bias, float* __restrict__ outp) {
  const int tid = threadIdx.x;
  const int n0 = blockIdx.x * 64;
  const int wv = tid >> 6, lane = tid & 63;
  const int frow = lane & 15, fgrp = lane >> 4;
  const float* Wrow = Wf + (long)(n0 + wv * 16 + frow) * HD;
  const u16*   Arow = hb + frow * HD;
  f32x4 acc[4] = {{0.f,0.f,0.f,0.f},{0.f,0.f,0.f,0.f},{0.f,0.f,0.f,0.f},{0.f,0.f,0.f,0.f}};
  #pragma unroll 2
  for (int ks = 0; ks < 16; ++ks) {
    const int k0 = ks * 32 + fgrp * 8;
    float4 w0 = *reinterpret_cast<const float4*>(Wrow + k0);
    float4 w1 = *reinterpret_cast<const float4*>(Wrow + k0 + 4);
    union { short8v v; u16 s[8]; } bf;
    bf.s[0] = f2bf(w0.x); bf.s[1] = f2bf(w0.y); bf.s[2] = f2bf(w0.z); bf.s[3] = f2bf(w0.w);
    bf.s[4] = f2bf(w1.x); bf.s[5] = f2bf(w1.y); bf.s[6] = f2bf(w1.z); bf.s[7] = f2bf(w1.w);
    #pragma unroll
    for (int m = 0; m < 4; ++m) {
      short8v afr = *reinterpret_cast<const short8v*>(Arow + m * 16 * HD + k0);
      acc[m] = __builtin_amdgcn_mfma_f32_16x16x32_bf16(afr, bf.v, acc[m], 0, 0, 0);
    }
  }
  const int col = n0 + wv * 16 + frow;
  const float bv = bias[col];
  #pragma unroll
  for (int m = 0; m < 4; ++m)
    #pragma unroll
    for (int r = 0; r < 4; ++r)
      outp[(long)(m * 16 + fgrp * 4 + r) * ((long)TT * VD) + col] = acc[m][r] + bv;
}

// ---------------------------------------------------------------------------
// Fused LSTM(t-1) + attention(t) + build_x(t); also emits x split (bf16 pair).
// ---------------------------------------------------------------------------
__global__ __launch_bounds__(512) void fused_attn_lstm(
    const float* __restrict__ proj, const float* __restrict__ enc,
    const float* __restrict__ emb, const int* __restrict__ caps, int t,
    const float* __restrict__ P, const float* __restrict__ b_ih,
    const float* __restrict__ b_hh, float* __restrict__ c,
    u16* __restrict__ hbuf_prev,
    float* __restrict__ attn_out, float* __restrict__ x,
    u16* __restrict__ xs_bf, u16* __restrict__ xs_er) {
  int b = blockIdx.x;
  __shared__ float sh[HD];
  __shared__ float sc[64];
  __shared__ float sw[64];
  int tid = threadIdx.x;
  if (t > 0) {
    int u = tid;
    float gi = b_ih[u]        + b_hh[u];
    float gf = b_ih[u + 512]  + b_hh[u + 512];
    float gg = b_ih[u + 1024] + b_hh[u + 1024];
    float go = b_ih[u + 1536] + b_hh[u + 1536];
    #pragma unroll
    for (int ks = 0; ks < 8; ++ks) {
      const float* p = P + ((long)ks * BB + b) * 2048;
      gi += p[u]; gf += p[u + 512]; gg += p[u + 1024]; go += p[u + 1536];
    }
    float si = 1.f / (1.f + __expf(-gi));
    float sf = 1.f / (1.f + __expf(-gf));
    float so = 1.f / (1.f + __expf(-go));
    float tg = tanhf(gg);
    float c2 = sf * c[b * HD + u] + si * tg;
    float h2 = so * tanhf(c2);
    c[b * HD + u] = c2;
    sh[u] = h2;
    hbuf_prev[b * HD + u] = f2bf(h2);
  } else {
    sh[tid] = 0.f;
  }
  __syncthreads();
  int wave = tid >> 6, lane = tid & 63;
  for (int s = wave; s < SS; s += 8) {
    const float* pr = proj + ((long)b * SS + s) * HD;
    float acc = 0.f;
    #pragma unroll
    for (int k = 0; k < HD / 64; ++k) acc += pr[lane + k * 64] * sh[lane + k * 64];
    #pragma unroll
    for (int off = 32; off; off >>= 1) acc += __shfl_down(acc, off);
    if (lane == 0) sc[s] = acc;
  }
  __syncthreads();
  if (wave == 0) {
    float v = (lane < SS) ? sc[lane] : -INFINITY;
    float m = v;
    #pragma unroll
    for (int off = 32; off; off >>= 1) m = fmaxf(m, __shfl_down(m, off));
    m = __shfl(m, 0);
    float e = (lane < SS) ? __expf(v - m) : 0.f;
    float sum = e;
    #pragma unroll
    for (int off = 32; off; off >>= 1) sum += __shfl_down(sum, off);
    sum = __shfl(sum, 0);
    float wv = e / sum;
    if (lane < SS) { sw[lane] = wv; attn_out[b * SS + lane] = wv; }
  }
  __syncthreads();
  float* xb = x + (long)b * 2048;
  u16* sb = xs_bf ? xs_bf + (long)b * 2048 : nullptr;
  u16* se = xs_er ? xs_er + (long)b * 2048 : nullptr;
  // ctx segment
  for (int e0 = tid; e0 < ENCD; e0 += 512) {
    float acc = 0.f;
    const float* eb = enc + (long)b * SS * ENCD + e0;
    #pragma unroll
    for (int s = 0; s < SS; ++s) acc += sw[s] * eb[(long)s * ENCD];
    xb[ED + e0] = acc;
    if (sb) {
      u16 bb = f2bf(acc);
      sb[ED + e0] = bb;
      se[ED + e0] = f2bf(acc - bf2f(bb));
    }
  }
  // emb + h segments
  int word = caps[b * TT + t];
  float ev = emb[(long)word * ED + tid];
  float hv = sh[tid];
  xb[tid] = ev;
  xb[1536 + tid] = hv;
  if (sb) {
    u16 eb16 = f2bf(ev);
    sb[tid] = eb16;
    se[tid] = f2bf(ev - bf2f(eb16));
    u16 hb16 = f2bf(hv);
    sb[1536 + tid] = hb16;
    se[1536 + tid] = f2bf(hv - bf2f(hb16));
  }
}

// ---------------------------------------------------------------------------
// LSTM pointwise (final step only)
// ---------------------------------------------------------------------------
__global__ __launch_bounds__(256) void lstm_pointwise(
    const float* __restrict__ P, const float* __restrict__ b_ih,
    const float* __restrict__ b_hh, float* __restrict__ h,
    float* __restrict__ c, u16* __restrict__ hb) {
  int idx = blockIdx.x * 256 + threadIdx.x;
  int b = idx >> 9, u = idx & 511;
  float gi = b_ih[u]        + b_hh[u];
  float gf = b_ih[u + 512]  + b_hh[u + 512];
  float gg = b_ih[u + 1024] + b_hh[u + 1024];
  float go = b_ih[u + 1536] + b_hh[u + 1536];
  #pragma unroll
  for (int ks = 0; ks < 8; ++ks) {
    const float* p = P + ((long)ks * BB + b) * 2048;
    gi += p[u]; gf += p[u + 512]; gg += p[u + 1024]; go += p[u + 1536];
  }
  float si = 1.f / (1.f + __expf(-gi));
  float sf = 1.f / (1.f + __expf(-gf));
  float so = 1.f / (1.f + __expf(-go));
  float tg = tanhf(gg);
  float c2 = sf * c[idx] + si * tg;
  float h2 = so * tanhf(c2);
  c[idx] = c2;
  h[idx] = h2;
  hb[idx] = f2bf(h2);
}

// ---------------------------------------------------------------------------
extern "C" void kernel_launch(void* const* d_in, const int* in_sizes, int n_in,
                              void* d_out_, int out_size, void* d_ws, size_t ws_size,
                              hipStream_t stream) {
  const float* enc   = (const float*)d_in[0];
  const int*   caps  = (const int*)d_in[1];
  const float* emb   = (const float*)d_in[2];
  const float* attnW = (const float*)d_in[3];
  const float* attnB = (const float*)d_in[4];
  const float* W_ih  = (const float*)d_in[5];
  const float* W_hh  = (const float*)d_in[6];
  const float* b_ih  = (const float*)d_in[7];
  const float* b_hh  = (const float*)d_in[8];
  const float* fcW   = (const float*)d_in[9];
  const float* fcb   = (const float*)d_in[10];

  float* out   = (float*)d_out_;                       // [B][T][V]
  float* attns = out + (long)BB * TT * VD;             // [T-1][B][S]

  // workspace layout (floats)
  float* ws    = (float*)d_ws;
  float* proj  = ws;                                   // 1,966,080
  float* h     = proj + (long)BB * SS * HD;
  float* c     = h + BB * HD;
  float* x     = c + BB * HD;                          // [64][2048]
  float* P     = x + BB * 2048;                        // [8][64][2048]
  u16*   hbuf  = (u16*)(P + (long)8 * BB * 2048);      // [19][64][512]
  u16*   Wbf   = hbuf + (long)(TT - 1) * BB * HD;      // [V][H]
  u16*   xs_bf = Wbf + (long)VD * HD;                  // [64][2048]
  u16*   xs_er = xs_bf + (long)BB * 2048;              // [64][2048]
  u16*   Wg_bf = xs_er + (long)BB * 2048;              // [2048][2048]
  u16*   Wg_er = Wg_bf + (long)2048 * 2048;            // [2048][2048]
  size_t need1 = (size_t)((char*)xs_bf - (char*)d_ws);           // R7 footprint
  size_t need2 = (size_t)((char*)(Wg_er + (long)2048 * 2048) - (char*)d_ws);
  const bool use_wbf   = (ws_size >= need1);
  const bool use_split = (ws_size >= need2);

  init_kernel<<<(BB * VD + 255) / 256, 256, 0, stream>>>(out, h, c);

  if (use_wbf) {
    long n = (long)VD * HD;
    convert_bf16_k<<<(int)(n / 2048), 256, 0, stream>>>(fcW, Wbf, n);
  }
  if (use_split) {
    split_wg_k<<<2048, 256, 0, stream>>>(W_ih, W_hh, Wg_bf, Wg_er);
  }

  // proj = enc @ attn_W^T + attn_b : M=3840, N=512, K=1024
  gemm_nt<<<dim3(8, 60, 1), 256, 0, stream>>>(enc, ENCD, attnW, ENCD, attnB,
                                              proj, HD, 0, ENCD);

  for (int t = 0; t < TT - 1; ++t) {
    u16* hbp = hbuf + (long)(t > 0 ? t - 1 : 0) * BB * HD;
    fused_attn_lstm<<<BB, 512, 0, stream>>>(proj, enc, emb, caps, t,
                                            P, b_ih, b_hh, c, hbp,
                                            attns + (long)t * BB * SS, x,
                                            use_split ? xs_bf : nullptr,
                                            use_split ? xs_er : nullptr);
    if (use_split) {
      gates_mfma<<<dim3(32, 1, 8), 256, 0, stream>>>(xs_bf, xs_er, Wg_bf, Wg_er, P);
    } else {
      gemm_gates<<<dim3(32, 1, 8), 256, 0, stream>>>(x, W_ih, W_hh, P);
    }
  }
  // final LSTM step (t = 18) -> hbuf[18]
  lstm_pointwise<<<128, 256, 0, stream>>>(P, b_ih, b_hh, h, c,
                                          hbuf + (long)(TT - 2) * BB * HD);

  if (use_wbf) {
    fc_tiled<<<125 * 19, 256, 0, stream>>>(hbuf, Wbf, fcb, out);
  } else {
    for (int t = 0; t < TT - 1; ++t)
      fc_mfma_f32w<<<VD / 64, 256, 0, stream>>>(hbuf + (long)t * BB * HD, fcW, fcb,
                                                out + (long)(t + 1) * VD);
  }
}

// Round 9
// 948.562 us; speedup vs baseline: 2.0585x; 1.0686x over previous
//
#include <hip/hip_runtime.h>
#include <math.h>

// Problem dims (fixed by reference)
#define BB   64
#define SS   60
#define ENCD 1024
#define ED   512
#define HD   512
#define VD   32000
#define TT   20
#define KT   32   // fp32 GEMM k-tile

typedef unsigned short u16;
typedef __attribute__((ext_vector_type(8))) short short8v;   // 8 bf16 = 4 VGPR
typedef __attribute__((ext_vector_type(4))) float f32x4;

__device__ __forceinline__ u16 f2bf(float x) {   // RNE float->bf16
  unsigned int u = __float_as_uint(x);
  return (u16)((u + 0x7FFFu + ((u >> 16) & 1u)) >> 16);
}
__device__ __forceinline__ float bf2f(u16 b) {
  return __uint_as_float((unsigned)b << 16);
}

// ---------------------------------------------------------------------------
// init: zero outputs[:,0,:] and h0/c0
// ---------------------------------------------------------------------------
__global__ __launch_bounds__(256) void init_kernel(float* __restrict__ out,
                                                   float* __restrict__ h,
                                                   float* __restrict__ c) {
  int i = blockIdx.x * 256 + threadIdx.x;
  if (i < BB * VD) {
    int b = i / VD, v = i - b * VD;
    out[(long)b * (TT * VD) + v] = 0.f;
  }
  if (i < BB * HD) { h[i] = 0.f; c[i] = 0.f; }
}

// ---------------------------------------------------------------------------
// fp32->bf16 bulk convert (8 elems/thread)
// ---------------------------------------------------------------------------
__global__ __launch_bounds__(256) void convert_bf16_k(const float* __restrict__ src,
                                                      u16* __restrict__ dst, long n) {
  long i = ((long)blockIdx.x * 256 + threadIdx.x) * 8;
  if (i + 8 <= n) {
    float4 a = *reinterpret_cast<const float4*>(src + i);
    float4 b = *reinterpret_cast<const float4*>(src + i + 4);
    uint4 o;
    o.x = (unsigned)f2bf(a.x) | ((unsigned)f2bf(a.y) << 16);
    o.y = (unsigned)f2bf(a.z) | ((unsigned)f2bf(a.w) << 16);
    o.z = (unsigned)f2bf(b.x) | ((unsigned)f2bf(b.y) << 16);
    o.w = (unsigned)f2bf(b.z) | ((unsigned)f2bf(b.w) << 16);
    *reinterpret_cast<uint4*>(dst + i) = o;
  }
}

// ---------------------------------------------------------------------------
// fp32 -> (bf16, bf16 err) split, 8 elems/thread
// ---------------------------------------------------------------------------
__global__ __launch_bounds__(256) void split_pair_k(const float* __restrict__ src,
                                                    u16* __restrict__ bf,
                                                    u16* __restrict__ er, long n) {
  long i = ((long)blockIdx.x * 256 + threadIdx.x) * 8;
  if (i + 8 <= n) {
    #pragma unroll
    for (int j = 0; j < 8; ++j) {
      float v = src[i + j];
      u16 b = f2bf(v);
      bf[i + j] = b;
      er[i + j] = f2bf(v - bf2f(b));
    }
  }
}

// ---------------------------------------------------------------------------
// Build combined gates weight split: Wg[n][k] = k<1536 ? W_ih[n][k]
//                                              : W_hh[n][k-1536]
// ---------------------------------------------------------------------------
__global__ __launch_bounds__(256) void split_wg_k(
    const float* __restrict__ Wih, const float* __restrict__ Whh,
    u16* __restrict__ wb, u16* __restrict__ we) {
  int n = blockIdx.x;
  int k0 = threadIdx.x * 8;
  #pragma unroll
  for (int j = 0; j < 8; ++j) {
    int k = k0 + j;
    float v = (k < 1536) ? Wih[(long)n * 1536 + k] : Whh[(long)n * 512 + (k - 1536)];
    u16 b = f2bf(v);
    wb[(long)n * 2048 + k] = b;
    we[(long)n * 2048 + k] = f2bf(v - bf2f(b));
  }
}

// ---------------------------------------------------------------------------
// Generic fp32 NT GEMM (proj fallback; gates fallback)
// ---------------------------------------------------------------------------
__global__ __launch_bounds__(256) void gemm_nt(
    const float* __restrict__ A, int lda,
    const float* __restrict__ Bw, int ldb,
    const float* __restrict__ bias,
    float* __restrict__ C, long ldc, long zstride,
    int kChunk) {
  __shared__ __align__(16) float As[KT][64];
  __shared__ __align__(16) float Ws[KT][64];
  const int tid = threadIdx.x;
  const int m0 = blockIdx.y * 64, n0 = blockIdx.x * 64;
  const int k0 = blockIdx.z * kChunk, k1 = k0 + kChunk;
  const int tm = tid & 15, tn = tid >> 4;
  const int lr = tid >> 3;
  const int lk = (tid & 7) * 4;
  float acc[4][4] = {};
  for (int kt = k0; kt < k1; kt += KT) {
    __syncthreads();
    #pragma unroll
    for (int p = 0; p < 2; ++p) {
      int m = p * 32 + lr;
      float4 av = *reinterpret_cast<const float4*>(A + (long)(m0 + m) * lda + kt + lk);
      As[lk + 0][m] = av.x; As[lk + 1][m] = av.y;
      As[lk + 2][m] = av.z; As[lk + 3][m] = av.w;
      float4 wv = *reinterpret_cast<const float4*>(Bw + (long)(n0 + m) * ldb + kt + lk);
      Ws[lk + 0][m] = wv.x; Ws[lk + 1][m] = wv.y;
      Ws[lk + 2][m] = wv.z; Ws[lk + 3][m] = wv.w;
    }
    __syncthreads();
    #pragma unroll
    for (int k = 0; k < KT; ++k) {
      float4 a = *reinterpret_cast<const float4*>(&As[k][tm * 4]);
      float4 w = *reinterpret_cast<const float4*>(&Ws[k][tn * 4]);
      acc[0][0] += a.x * w.x; acc[0][1] += a.x * w.y; acc[0][2] += a.x * w.z; acc[0][3] += a.x * w.w;
      acc[1][0] += a.y * w.x; acc[1][1] += a.y * w.y; acc[1][2] += a.y * w.z; acc[1][3] += a.y * w.w;
      acc[2][0] += a.z * w.x; acc[2][1] += a.z * w.y; acc[2][2] += a.z * w.z; acc[2][3] += a.z * w.w;
      acc[3][0] += a.w * w.x; acc[3][1] += a.w * w.y; acc[3][2] += a.w * w.z; acc[3][3] += a.w * w.w;
    }
  }
  float* Cz = C + (long)blockIdx.z * zstride;
  #pragma unroll
  for (int mi = 0; mi < 4; ++mi) {
    int row = m0 + tm * 4 + mi, col = n0 + tn * 4;
    float4 o;
    o.x = acc[mi][0]; o.y = acc[mi][1]; o.z = acc[mi][2]; o.w = acc[mi][3];
    if (bias) {
      o.x += bias[col]; o.y += bias[col + 1]; o.z += bias[col + 2]; o.w += bias[col + 3];
    }
    *reinterpret_cast<float4*>(Cz + (long)row * ldc + col) = o;
  }
}

// ---------------------------------------------------------------------------
// Gates fallback (fp32 vector GEMM)
// ---------------------------------------------------------------------------
__global__ __launch_bounds__(256) void gemm_gates(
    const float* __restrict__ x,
    const float* __restrict__ Wih,
    const float* __restrict__ Whh,
    float* __restrict__ P) {
  __shared__ __align__(16) float As[KT][64];
  __shared__ __align__(16) float Ws[KT][64];
  const int tid = threadIdx.x;
  const int bz = blockIdx.z;
  const int n0 = blockIdx.x * 64;
  const float* A;
  const float* Bw;
  int ldb, k0;
  if (bz < 6) { A = x;        Bw = Wih; ldb = 1536; k0 = bz * 256; }
  else        { A = x + 1536; Bw = Whh; ldb = 512;  k0 = (bz - 6) * 256; }
  const int k1 = k0 + 256;
  const int tm = tid & 15, tn = tid >> 4;
  const int lr = tid >> 3;
  const int lk = (tid & 7) * 4;
  float acc[4][4] = {};
  for (int kt = k0; kt < k1; kt += KT) {
    __syncthreads();
    #pragma unroll
    for (int p = 0; p < 2; ++p) {
      int m = p * 32 + lr;
      float4 av = *reinterpret_cast<const float4*>(A + (long)m * 2048 + kt + lk);
      As[lk + 0][m] = av.x; As[lk + 1][m] = av.y;
      As[lk + 2][m] = av.z; As[lk + 3][m] = av.w;
      float4 wv = *reinterpret_cast<const float4*>(Bw + (long)(n0 + m) * ldb + kt + lk);
      Ws[lk + 0][m] = wv.x; Ws[lk + 1][m] = wv.y;
      Ws[lk + 2][m] = wv.z; Ws[lk + 3][m] = wv.w;
    }
    __syncthreads();
    #pragma unroll
    for (int k = 0; k < KT; ++k) {
      float4 a = *reinterpret_cast<const float4*>(&As[k][tm * 4]);
      float4 w = *reinterpret_cast<const float4*>(&Ws[k][tn * 4]);
      acc[0][0] += a.x * w.x; acc[0][1] += a.x * w.y; acc[0][2] += a.x * w.z; acc[0][3] += a.x * w.w;
      acc[1][0] += a.y * w.x; acc[1][1] += a.y * w.y; acc[1][2] += a.y * w.z; acc[1][3] += a.y * w.w;
      acc[2][0] += a.z * w.x; acc[2][1] += a.z * w.y; acc[2][2] += a.z * w.z; acc[2][3] += a.z * w.w;
      acc[3][0] += a.w * w.x; acc[3][1] += a.w * w.y; acc[3][2] += a.w * w.z; acc[3][3] += a.w * w.w;
    }
  }
  float* Cz = P + (long)bz * (BB * 2048);
  #pragma unroll
  for (int mi = 0; mi < 4; ++mi) {
    int row = tm * 4 + mi, col = n0 + tn * 4;
    float4 o;
    o.x = acc[mi][0]; o.y = acc[mi][1]; o.z = acc[mi][2]; o.w = acc[mi][3];
    *reinterpret_cast<float4*>(Cz + (long)row * 2048 + col) = o;
  }
}

// ---------------------------------------------------------------------------
// Gates GEMM, split-bf16 MFMA (proven in R8).
// ---------------------------------------------------------------------------
__global__ __launch_bounds__(256) void gates_mfma(
    const u16* __restrict__ xb, const u16* __restrict__ xe,   // [64][2048]
    const u16* __restrict__ wb, const u16* __restrict__ we,   // [2048][2048]
    float* __restrict__ P) {                                  // [8][64][2048]
  __shared__ __align__(16) u16 lds[32768];   // 64 KB
  const int tid = threadIdx.x;
  const int n0 = blockIdx.x * 64;
  const int kz = blockIdx.z * 256;
  const int w = tid >> 6, lane = tid & 63;
  const int frow = lane & 15, fgrp = lane >> 4;
  const int srow = tid >> 3, sslot = tid & 7;
  const int scol = (sslot ^ (srow & 7)) * 8;
  char* L = (char*)lds;

#define GT_STAGE(buf, kc) do {                                                     \
    _Pragma("unroll")                                                              \
    for (int ii = 0; ii < 2; ++ii) {                                               \
      int r_ = ii * 32 + srow;                                                     \
      __builtin_amdgcn_global_load_lds(                                            \
        (const __attribute__((address_space(1))) void*)(xb + (long)r_ * 2048 + (kc) + scol), \
        (__attribute__((address_space(3))) void*)(L + (buf) * 8192 + ii * 4096 + tid * 16), 16, 0, 0); \
      __builtin_amdgcn_global_load_lds(                                            \
        (const __attribute__((address_space(1))) void*)(xe + (long)r_ * 2048 + (kc) + scol), \
        (__attribute__((address_space(3))) void*)(L + 16384 + (buf) * 8192 + ii * 4096 + tid * 16), 16, 0, 0); \
      __builtin_amdgcn_global_load_lds(                                            \
        (const __attribute__((address_space(1))) void*)(wb + (long)(n0 + r_) * 2048 + (kc) + scol), \
        (__attribute__((address_space(3))) void*)(L + 32768 + (buf) * 8192 + ii * 4096 + tid * 16), 16, 0, 0); \
      __builtin_amdgcn_global_load_lds(                                            \
        (const __attribute__((address_space(1))) void*)(we + (long)(n0 + r_) * 2048 + (kc) + scol), \
        (__attribute__((address_space(3))) void*)(L + 49152 + (buf) * 8192 + ii * 4096 + tid * 16), 16, 0, 0); \
    }                                                                              \
  } while (0)

  f32x4 acc[4] = {{0.f,0.f,0.f,0.f},{0.f,0.f,0.f,0.f},{0.f,0.f,0.f,0.f},{0.f,0.f,0.f,0.f}};

  GT_STAGE(0, kz);
  asm volatile("s_waitcnt vmcnt(0)");
  __syncthreads();

  for (int kc = 0; kc < 4; ++kc) {
    const int cur = kc & 1;
    if (kc < 3) GT_STAGE(cur ^ 1, kz + (kc + 1) * 64);
    const char* Ab = L + cur * 8192;
    const char* Ae = L + 16384 + cur * 8192;
    const char* Bb = L + 32768 + cur * 8192;
    const char* Be = L + 49152 + cur * 8192;
    #pragma unroll
    for (int ks = 0; ks < 2; ++ks) {
      const int slot = ((ks * 4 + fgrp) ^ (frow & 7)) * 16;
      const int brow = (w * 16 + frow) * 128 + slot;
      short8v bbf = *reinterpret_cast<const short8v*>(Bb + brow);
      short8v bef = *reinterpret_cast<const short8v*>(Be + brow);
      #pragma unroll
      for (int m = 0; m < 4; ++m) {
        const int arow = (m * 16 + frow) * 128 + slot;
        short8v abf = *reinterpret_cast<const short8v*>(Ab + arow);
        short8v aef = *reinterpret_cast<const short8v*>(Ae + arow);
        acc[m] = __builtin_amdgcn_mfma_f32_16x16x32_bf16(abf, bbf, acc[m], 0, 0, 0);
        acc[m] = __builtin_amdgcn_mfma_f32_16x16x32_bf16(aef, bbf, acc[m], 0, 0, 0);
        acc[m] = __builtin_amdgcn_mfma_f32_16x16x32_bf16(abf, bef, acc[m], 0, 0, 0);
      }
    }
    asm volatile("s_waitcnt vmcnt(0)");
    __syncthreads();
  }

  float* Pz = P + (long)blockIdx.z * (BB * 2048);
  const int col = n0 + w * 16 + frow;
  #pragma unroll
  for (int m = 0; m < 4; ++m)
    #pragma unroll
    for (int r = 0; r < 4; ++r)
      Pz[(long)(m * 16 + fgrp * 4 + r) * 2048 + col] = acc[m][r];
#undef GT_STAGE
}

// ---------------------------------------------------------------------------
// proj GEMM, split-bf16 MFMA: proj = enc @ attn_W^T + attn_b
// M=3840, N=512, K=1024.  Clone of gates_mfma structure.
// grid (8 n-tiles, 60 m-tiles), 256 thr, LDS 64 KB, K-step 64 x 16.
// ---------------------------------------------------------------------------
__global__ __launch_bounds__(256) void proj_mfma(
    const u16* __restrict__ eb, const u16* __restrict__ ee,   // [3840][1024]
    const u16* __restrict__ wb, const u16* __restrict__ we,   // [512][1024]
    const float* __restrict__ bias,
    float* __restrict__ proj) {                               // [3840][512]
  __shared__ __align__(16) u16 lds[32768];   // 64 KB
  const int tid = threadIdx.x;
  const int n0 = blockIdx.x * 64;
  const int m0 = blockIdx.y * 64;
  const int w = tid >> 6, lane = tid & 63;
  const int frow = lane & 15, fgrp = lane >> 4;
  const int srow = tid >> 3, sslot = tid & 7;
  const int scol = (sslot ^ (srow & 7)) * 8;
  char* L = (char*)lds;

#define PJ_STAGE(buf, kc) do {                                                     \
    _Pragma("unroll")                                                              \
    for (int ii = 0; ii < 2; ++ii) {                                               \
      int r_ = ii * 32 + srow;                                                     \
      __builtin_amdgcn_global_load_lds(                                            \
        (const __attribute__((address_space(1))) void*)(eb + (long)(m0 + r_) * ENCD + (kc) + scol), \
        (__attribute__((address_space(3))) void*)(L + (buf) * 8192 + ii * 4096 + tid * 16), 16, 0, 0); \
      __builtin_amdgcn_global_load_lds(                                            \
        (const __attribute__((address_space(1))) void*)(ee + (long)(m0 + r_) * ENCD + (kc) + scol), \
        (__attribute__((address_space(3))) void*)(L + 16384 + (buf) * 8192 + ii * 4096 + tid * 16), 16, 0, 0); \
      __builtin_amdgcn_global_load_lds(                                            \
        (const __attribute__((address_space(1))) void*)(wb + (long)(n0 + r_) * ENCD + (kc) + scol), \
        (__attribute__((address_space(3))) void*)(L + 32768 + (buf) * 8192 + ii * 4096 + tid * 16), 16, 0, 0); \
      __builtin_amdgcn_global_load_lds(                                            \
        (const __attribute__((address_space(1))) void*)(we + (long)(n0 + r_) * ENCD + (kc) + scol), \
        (__attribute__((address_space(3))) void*)(L + 49152 + (buf) * 8192 + ii * 4096 + tid * 16), 16, 0, 0); \
    }                                                                              \
  } while (0)

  f32x4 acc[4] = {{0.f,0.f,0.f,0.f},{0.f,0.f,0.f,0.f},{0.f,0.f,0.f,0.f},{0.f,0.f,0.f,0.f}};

  PJ_STAGE(0, 0);
  asm volatile("s_waitcnt vmcnt(0)");
  __syncthreads();

  for (int kc = 0; kc < 16; ++kc) {
    const int cur = kc & 1;
    if (kc < 15) PJ_STAGE(cur ^ 1, (kc + 1) * 64);
    const char* Ab = L + cur * 8192;
    const char* Ae = L + 16384 + cur * 8192;
    const char* Bb = L + 32768 + cur * 8192;
    const char* Be = L + 49152 + cur * 8192;
    #pragma unroll
    for (int ks = 0; ks < 2; ++ks) {
      const int slot = ((ks * 4 + fgrp) ^ (frow & 7)) * 16;
      const int brow = (w * 16 + frow) * 128 + slot;
      short8v bbf = *reinterpret_cast<const short8v*>(Bb + brow);
      short8v bef = *reinterpret_cast<const short8v*>(Be + brow);
      #pragma unroll
      for (int m = 0; m < 4; ++m) {
        const int arow = (m * 16 + frow) * 128 + slot;
        short8v abf = *reinterpret_cast<const short8v*>(Ab + arow);
        short8v aef = *reinterpret_cast<const short8v*>(Ae + arow);
        acc[m] = __builtin_amdgcn_mfma_f32_16x16x32_bf16(abf, bbf, acc[m], 0, 0, 0);
        acc[m] = __builtin_amdgcn_mfma_f32_16x16x32_bf16(aef, bbf, acc[m], 0, 0, 0);
        acc[m] = __builtin_amdgcn_mfma_f32_16x16x32_bf16(abf, bef, acc[m], 0, 0, 0);
      }
    }
    asm volatile("s_waitcnt vmcnt(0)");
    __syncthreads();
  }

  const int col = n0 + w * 16 + frow;
  const float bv = bias[col];
  #pragma unroll
  for (int m = 0; m < 4; ++m)
    #pragma unroll
    for (int r = 0; r < 4; ++r)
      proj[(long)(m0 + m * 16 + fgrp * 4 + r) * HD + col] = acc[m][r] + bv;
#undef PJ_STAGE
}

// ---------------------------------------------------------------------------
// fc GEMM, m97-style (unchanged from R7, proven).
// ---------------------------------------------------------------------------
__global__ __launch_bounds__(256) void fc_tiled(
    const u16* __restrict__ hbuf, const u16* __restrict__ Wb,
    const float* __restrict__ bias, float* __restrict__ out) {
  __shared__ __align__(16) u16 lds[40960];   // 80 KB
  const int tid = threadIdx.x;
  const int bid = blockIdx.x;
  const int xcd = bid & 7, loc = bid >> 3;
  const int wg = (xcd < 7) ? (xcd * 297 + loc) : (2079 + loc);
  const int n_tile = wg / 19, t = wg - n_tile * 19;
  const int n0 = n_tile * 256;

  const u16* Ab = hbuf + (long)t * (BB * HD);
  const u16* Wbase = Wb + (long)n0 * HD;

  const int w = tid >> 6, lane = tid & 63;
  const int frow = lane & 15, fgrp = lane >> 4;
  const int srow = tid >> 3, sslot = tid & 7;
  const int scol = (sslot ^ (srow & 7)) * 8;
  char* ldsb = (char*)lds;

#define FC_STAGE(buf, kc) do {                                                    \
    _Pragma("unroll")                                                             \
    for (int ii = 0; ii < 2; ++ii) {                                              \
      __builtin_amdgcn_global_load_lds(                                           \
        (const __attribute__((address_space(1))) void*)(Ab + (ii * 32 + srow) * HD + (kc) + scol), \
        (__attribute__((address_space(3))) void*)(ldsb + (buf) * 8192 + ii * 4096 + tid * 16), \
        16, 0, 0);                                                                \
    }                                                                             \
    _Pragma("unroll")                                                             \
    for (int ii = 0; ii < 8; ++ii) {                                              \
      __builtin_amdgcn_global_load_lds(                                           \
        (const __attribute__((address_space(1))) void*)(Wbase + (long)(ii * 32 + srow) * HD + (kc) + scol), \
        (__attribute__((address_space(3))) void*)(ldsb + 16384 + (buf) * 32768 + ii * 4096 + tid * 16), \
        16, 0, 0);                                                                \
    }                                                                             \
  } while (0)

  f32x4 acc[4][4] = {};

  FC_STAGE(0, 0);
  asm volatile("s_waitcnt vmcnt(0)");
  __syncthreads();

  for (int kc = 0; kc < 8; ++kc) {
    const int cur = kc & 1;
    if (kc < 7) FC_STAGE(cur ^ 1, (kc + 1) * 64);
    const char* Abuf = ldsb + cur * 8192;
    const char* Wbuf = ldsb + 16384 + cur * 32768;
    #pragma unroll
    for (int ks = 0; ks < 2; ++ks) {
      const int slot = ((ks * 4 + fgrp) ^ (frow & 7)) * 16;
      short8v af[4], wf[4];
      #pragma unroll
      for (int m = 0; m < 4; ++m)
        af[m] = *reinterpret_cast<const short8v*>(Abuf + (m * 16 + frow) * 128 + slot);
      #pragma unroll
      for (int n = 0; n < 4; ++n)
        wf[n] = *reinterpret_cast<const short8v*>(Wbuf + (w * 64 + n * 16 + frow) * 128 + slot);
      #pragma unroll
      for (int m = 0; m < 4; ++m)
        #pragma unroll
        for (int n = 0; n < 4; ++n)
          acc[m][n] = __builtin_amdgcn_mfma_f32_16x16x32_bf16(af[m], wf[n], acc[m][n], 0, 0, 0);
    }
    asm volatile("s_waitcnt vmcnt(0)");
    __syncthreads();
  }

  #pragma unroll
  for (int n = 0; n < 4; ++n) {
    const int col = n0 + w * 64 + n * 16 + frow;
    const float bv = bias[col];
    #pragma unroll
    for (int m = 0; m < 4; ++m) {
      #pragma unroll
      for (int r = 0; r < 4; ++r) {
        int b = m * 16 + fgrp * 4 + r;
        out[((long)b * TT + (t + 1)) * VD + col] = acc[m][n][r] + bv;
      }
    }
  }
#undef FC_STAGE
}

// ---------------------------------------------------------------------------
// fc fallback (per-step) — only if ws can't hold Wbf (never observed).
// ---------------------------------------------------------------------------
__global__ __launch_bounds__(256) void fc_mfma_f32w(
    const u16* __restrict__ hb, const float* __restrict__ Wf,
    const float* __restrict__ bias, float* __restrict__ outp) {
  const int tid = threadIdx.x;
  const int n0 = blockIdx.x * 64;
  const int wv = tid >> 6, lane = tid & 63;
  const int frow = lane & 15, fgrp = lane >> 4;
  const float* Wrow = Wf + (long)(n0 + wv * 16 + frow) * HD;
  const u16*   Arow = hb + frow * HD;
  f32x4 acc[4] = {{0.f,0.f,0.f,0.f},{0.f,0.f,0.f,0.f},{0.f,0.f,0.f,0.f},{0.f,0.f,0.f,0.f}};
  #pragma unroll 2
  for (int ks = 0; ks < 16; ++ks) {
    const int k0 = ks * 32 + fgrp * 8;
    float4 w0 = *reinterpret_cast<const float4*>(Wrow + k0);
    float4 w1 = *reinterpret_cast<const float4*>(Wrow + k0 + 4);
    union { short8v v; u16 s[8]; } bf;
    bf.s[0] = f2bf(w0.x); bf.s[1] = f2bf(w0.y); bf.s[2] = f2bf(w0.z); bf.s[3] = f2bf(w0.w);
    bf.s[4] = f2bf(w1.x); bf.s[5] = f2bf(w1.y); bf.s[6] = f2bf(w1.z); bf.s[7] = f2bf(w1.w);
    #pragma unroll
    for (int m = 0; m < 4; ++m) {
      short8v afr = *reinterpret_cast<const short8v*>(Arow + m * 16 * HD + k0);
      acc[m] = __builtin_amdgcn_mfma_f32_16x16x32_bf16(afr, bf.v, acc[m], 0, 0, 0);
    }
  }
  const int col = n0 + wv * 16 + frow;
  const float bv = bias[col];
  #pragma unroll
  for (int m = 0; m < 4; ++m)
    #pragma unroll
    for (int r = 0; r < 4; ++r)
      outp[(long)(m * 16 + fgrp * 4 + r) * ((long)TT * VD) + col] = acc[m][r] + bv;
}

// ---------------------------------------------------------------------------
// Fused LSTM(t-1) + attention(t) + build_x(t); also emits x split (bf16 pair).
// ---------------------------------------------------------------------------
__global__ __launch_bounds__(512) void fused_attn_lstm(
    const float* __restrict__ proj, const float* __restrict__ enc,
    const float* __restrict__ emb, const int* __restrict__ caps, int t,
    const float* __restrict__ P, const float* __restrict__ b_ih,
    const float* __restrict__ b_hh, float* __restrict__ c,
    u16* __restrict__ hbuf_prev,
    float* __restrict__ attn_out, float* __restrict__ x,
    u16* __restrict__ xs_bf, u16* __restrict__ xs_er) {
  int b = blockIdx.x;
  __shared__ float sh[HD];
  __shared__ float sc[64];
  __shared__ float sw[64];
  int tid = threadIdx.x;
  if (t > 0) {
    int u = tid;
    float gi = b_ih[u]        + b_hh[u];
    float gf = b_ih[u + 512]  + b_hh[u + 512];
    float gg = b_ih[u + 1024] + b_hh[u + 1024];
    float go = b_ih[u + 1536] + b_hh[u + 1536];
    #pragma unroll
    for (int ks = 0; ks < 8; ++ks) {
      const float* p = P + ((long)ks * BB + b) * 2048;
      gi += p[u]; gf += p[u + 512]; gg += p[u + 1024]; go += p[u + 1536];
    }
    float si = 1.f / (1.f + __expf(-gi));
    float sf = 1.f / (1.f + __expf(-gf));
    float so = 1.f / (1.f + __expf(-go));
    float tg = tanhf(gg);
    float c2 = sf * c[b * HD + u] + si * tg;
    float h2 = so * tanhf(c2);
    c[b * HD + u] = c2;
    sh[u] = h2;
    hbuf_prev[b * HD + u] = f2bf(h2);
  } else {
    sh[tid] = 0.f;
  }
  __syncthreads();
  int wave = tid >> 6, lane = tid & 63;
  for (int s = wave; s < SS; s += 8) {
    const float* pr = proj + ((long)b * SS + s) * HD;
    float acc = 0.f;
    #pragma unroll
    for (int k = 0; k < HD / 64; ++k) acc += pr[lane + k * 64] * sh[lane + k * 64];
    #pragma unroll
    for (int off = 32; off; off >>= 1) acc += __shfl_down(acc, off);
    if (lane == 0) sc[s] = acc;
  }
  __syncthreads();
  if (wave == 0) {
    float v = (lane < SS) ? sc[lane] : -INFINITY;
    float m = v;
    #pragma unroll
    for (int off = 32; off; off >>= 1) m = fmaxf(m, __shfl_down(m, off));
    m = __shfl(m, 0);
    float e = (lane < SS) ? __expf(v - m) : 0.f;
    float sum = e;
    #pragma unroll
    for (int off = 32; off; off >>= 1) sum += __shfl_down(sum, off);
    sum = __shfl(sum, 0);
    float wv = e / sum;
    if (lane < SS) { sw[lane] = wv; attn_out[b * SS + lane] = wv; }
  }
  __syncthreads();
  float* xb = x + (long)b * 2048;
  u16* sb = xs_bf ? xs_bf + (long)b * 2048 : nullptr;
  u16* se = xs_er ? xs_er + (long)b * 2048 : nullptr;
  // ctx segment
  for (int e0 = tid; e0 < ENCD; e0 += 512) {
    float acc = 0.f;
    const float* ebp = enc + (long)b * SS * ENCD + e0;
    #pragma unroll
    for (int s = 0; s < SS; ++s) acc += sw[s] * ebp[(long)s * ENCD];
    xb[ED + e0] = acc;
    if (sb) {
      u16 bb = f2bf(acc);
      sb[ED + e0] = bb;
      se[ED + e0] = f2bf(acc - bf2f(bb));
    }
  }
  // emb + h segments
  int word = caps[b * TT + t];
  float ev = emb[(long)word * ED + tid];
  float hv = sh[tid];
  xb[tid] = ev;
  xb[1536 + tid] = hv;
  if (sb) {
    u16 eb16 = f2bf(ev);
    sb[tid] = eb16;
    se[tid] = f2bf(ev - bf2f(eb16));
    u16 hb16 = f2bf(hv);
    sb[1536 + tid] = hb16;
    se[1536 + tid] = f2bf(hv - bf2f(hb16));
  }
}

// ---------------------------------------------------------------------------
// LSTM pointwise (final step only)
// ---------------------------------------------------------------------------
__global__ __launch_bounds__(256) void lstm_pointwise(
    const float* __restrict__ P, const float* __restrict__ b_ih,
    const float* __restrict__ b_hh, float* __restrict__ h,
    float* __restrict__ c, u16* __restrict__ hb) {
  int idx = blockIdx.x * 256 + threadIdx.x;
  int b = idx >> 9, u = idx & 511;
  float gi = b_ih[u]        + b_hh[u];
  float gf = b_ih[u + 512]  + b_hh[u + 512];
  float gg = b_ih[u + 1024] + b_hh[u + 1024];
  float go = b_ih[u + 1536] + b_hh[u + 1536];
  #pragma unroll
  for (int ks = 0; ks < 8; ++ks) {
    const float* p = P + ((long)ks * BB + b) * 2048;
    gi += p[u]; gf += p[u + 512]; gg += p[u + 1024]; go += p[u + 1536];
  }
  float si = 1.f / (1.f + __expf(-gi));
  float sf = 1.f / (1.f + __expf(-gf));
  float so = 1.f / (1.f + __expf(-go));
  float tg = tanhf(gg);
  float c2 = sf * c[idx] + si * tg;
  float h2 = so * tanhf(c2);
  c[idx] = c2;
  h[idx] = h2;
  hb[idx] = f2bf(h2);
}

// ---------------------------------------------------------------------------
extern "C" void kernel_launch(void* const* d_in, const int* in_sizes, int n_in,
                              void* d_out_, int out_size, void* d_ws, size_t ws_size,
                              hipStream_t stream) {
  const float* enc   = (const float*)d_in[0];
  const int*   caps  = (const int*)d_in[1];
  const float* emb   = (const float*)d_in[2];
  const float* attnW = (const float*)d_in[3];
  const float* attnB = (const float*)d_in[4];
  const float* W_ih  = (const float*)d_in[5];
  const float* W_hh  = (const float*)d_in[6];
  const float* b_ih  = (const float*)d_in[7];
  const float* b_hh  = (const float*)d_in[8];
  const float* fcW   = (const float*)d_in[9];
  const float* fcb   = (const float*)d_in[10];

  float* out   = (float*)d_out_;                       // [B][T][V]
  float* attns = out + (long)BB * TT * VD;             // [T-1][B][S]

  // workspace layout (floats)
  float* ws    = (float*)d_ws;
  float* proj  = ws;                                   // [3840][512]
  float* h     = proj + (long)BB * SS * HD;
  float* c     = h + BB * HD;
  float* x     = c + BB * HD;                          // [64][2048]
  float* P     = x + BB * 2048;                        // [8][64][2048]
  u16*   hbuf  = (u16*)(P + (long)8 * BB * 2048);      // [19][64][512]
  u16*   Wbf   = hbuf + (long)(TT - 1) * BB * HD;      // [V][H]
  u16*   xs_bf = Wbf + (long)VD * HD;                  // [64][2048]
  u16*   xs_er = xs_bf + (long)BB * 2048;              // [64][2048]
  u16*   Wg_bf = xs_er + (long)BB * 2048;              // [2048][2048]
  u16*   Wg_er = Wg_bf + (long)2048 * 2048;            // [2048][2048]
  u16*   enc_bf = Wg_er + (long)2048 * 2048;           // [3840][1024]
  u16*   enc_er = enc_bf + (long)BB * SS * ENCD;       // [3840][1024]
  u16*   aW_bf  = enc_er + (long)BB * SS * ENCD;       // [512][1024]
  u16*   aW_er  = aW_bf + (long)HD * ENCD;             // [512][1024]
  size_t need1 = (size_t)((char*)xs_bf - (char*)d_ws);
  size_t need2 = (size_t)((char*)enc_bf - (char*)d_ws);
  size_t need3 = (size_t)((char*)(aW_er + (long)HD * ENCD) - (char*)d_ws);
  const bool use_wbf    = (ws_size >= need1);
  const bool use_split  = (ws_size >= need2);
  const bool use_psplit = (ws_size >= need3);

  init_kernel<<<(BB * VD + 255) / 256, 256, 0, stream>>>(out, h, c);

  if (use_wbf) {
    long n = (long)VD * HD;
    convert_bf16_k<<<(int)(n / 2048), 256, 0, stream>>>(fcW, Wbf, n);
  }
  if (use_split) {
    split_wg_k<<<2048, 256, 0, stream>>>(W_ih, W_hh, Wg_bf, Wg_er);
  }

  if (use_psplit) {
    long ne = (long)BB * SS * ENCD;                    // 3,932,160
    split_pair_k<<<(int)(ne / 2048), 256, 0, stream>>>(enc, enc_bf, enc_er, ne);
    long nw = (long)HD * ENCD;                         // 524,288
    split_pair_k<<<(int)(nw / 2048), 256, 0, stream>>>(attnW, aW_bf, aW_er, nw);
    proj_mfma<<<dim3(8, 60), 256, 0, stream>>>(enc_bf, enc_er, aW_bf, aW_er,
                                               attnB, proj);
  } else {
    gemm_nt<<<dim3(8, 60, 1), 256, 0, stream>>>(enc, ENCD, attnW, ENCD, attnB,
                                                proj, HD, 0, ENCD);
  }

  for (int t = 0; t < TT - 1; ++t) {
    u16* hbp = hbuf + (long)(t > 0 ? t - 1 : 0) * BB * HD;
    fused_attn_lstm<<<BB, 512, 0, stream>>>(proj, enc, emb, caps, t,
                                            P, b_ih, b_hh, c, hbp,
                                            attns + (long)t * BB * SS, x,
                                            use_split ? xs_bf : nullptr,
                                            use_split ? xs_er : nullptr);
    if (use_split) {
      gates_mfma<<<dim3(32, 1, 8), 256, 0, stream>>>(xs_bf, xs_er, Wg_bf, Wg_er, P);
    } else {
      gemm_gates<<<dim3(32, 1, 8), 256, 0, stream>>>(x, W_ih, W_hh, P);
    }
  }
  // final LSTM step (t = 18) -> hbuf[18]
  lstm_pointwise<<<128, 256, 0, stream>>>(P, b_ih, b_hh, h, c,
                                          hbuf + (long)(TT - 2) * BB * HD);

  if (use_wbf) {
    fc_tiled<<<125 * 19, 256, 0, stream>>>(hbuf, Wbf, fcb, out);
  } else {
    for (int t = 0; t < TT - 1; ++t)
      fc_mfma_f32w<<<VD / 64, 256, 0, stream>>>(hbuf + (long)t * BB * HD, fcW, fcb,
                                                out + (long)(t + 1) * VD);
  }
}

// Round 10
// 452.376 us; speedup vs baseline: 4.3164x; 2.0968x over previous
//
#include <hip/hip_runtime.h>
#include <math.h>
#include <stdint.h>

// Problem dims (fixed by reference)
#define BB   64
#define SS   60
#define ENCD 1024
#define ED   512
#define HD   512
#define VD   32000
#define TT   20
#define KT   32   // fp32 GEMM k-tile

typedef unsigned short u16;
typedef __attribute__((ext_vector_type(8))) short short8v;   // 8 bf16 = 4 VGPR
typedef __attribute__((ext_vector_type(4))) float f32x4;

__device__ __forceinline__ u16 f2bf(float x) {   // RNE float->bf16
  unsigned int u = __float_as_uint(x);
  return (u16)((u + 0x7FFFu + ((u >> 16) & 1u)) >> 16);
}
__device__ __forceinline__ float bf2f(u16 b) {
  return __uint_as_float((unsigned)b << 16);
}

// ---------------------------------------------------------------------------
// init: zero outputs[:,0,:] and h0/c0
// ---------------------------------------------------------------------------
__global__ __launch_bounds__(256) void init_kernel(float* __restrict__ out,
                                                   float* __restrict__ h,
                                                   float* __restrict__ c) {
  int i = blockIdx.x * 256 + threadIdx.x;
  if (i < BB * VD) {
    int b = i / VD, v = i - b * VD;
    out[(long)b * (TT * VD) + v] = 0.f;
  }
  if (i < BB * HD) { h[i] = 0.f; c[i] = 0.f; }
}

// ---------------------------------------------------------------------------
// fp32->bf16 bulk convert (8 elems/thread)
// ---------------------------------------------------------------------------
__global__ __launch_bounds__(256) void convert_bf16_k(const float* __restrict__ src,
                                                      u16* __restrict__ dst, long n) {
  long i = ((long)blockIdx.x * 256 + threadIdx.x) * 8;
  if (i + 8 <= n) {
    float4 a = *reinterpret_cast<const float4*>(src + i);
    float4 b = *reinterpret_cast<const float4*>(src + i + 4);
    uint4 o;
    o.x = (unsigned)f2bf(a.x) | ((unsigned)f2bf(a.y) << 16);
    o.y = (unsigned)f2bf(a.z) | ((unsigned)f2bf(a.w) << 16);
    o.z = (unsigned)f2bf(b.x) | ((unsigned)f2bf(b.y) << 16);
    o.w = (unsigned)f2bf(b.z) | ((unsigned)f2bf(b.w) << 16);
    *reinterpret_cast<uint4*>(dst + i) = o;
  }
}

// ---------------------------------------------------------------------------
// fp32 -> (bf16, bf16 err) split, 8 elems/thread
// ---------------------------------------------------------------------------
__global__ __launch_bounds__(256) void split_pair_k(const float* __restrict__ src,
                                                    u16* __restrict__ bf,
                                                    u16* __restrict__ er, long n) {
  long i = ((long)blockIdx.x * 256 + threadIdx.x) * 8;
  if (i + 8 <= n) {
    #pragma unroll
    for (int j = 0; j < 8; ++j) {
      float v = src[i + j];
      u16 b = f2bf(v);
      bf[i + j] = b;
      er[i + j] = f2bf(v - bf2f(b));
    }
  }
}

// ---------------------------------------------------------------------------
// Combined gates weight split: Wg[n][k] = k<1536 ? W_ih[n][k] : W_hh[n][k-1536]
// (cols 0..511 = emb part, 512..1535 = ctx part, 1536..2047 = h part)
// ---------------------------------------------------------------------------
__global__ __launch_bounds__(256) void split_wg_k(
    const float* __restrict__ Wih, const float* __restrict__ Whh,
    u16* __restrict__ wb, u16* __restrict__ we) {
  int n = blockIdx.x;
  int k0 = threadIdx.x * 8;
  #pragma unroll
  for (int j = 0; j < 8; ++j) {
    int k = k0 + j;
    float v = (k < 1536) ? Wih[(long)n * 1536 + k] : Whh[(long)n * 512 + (k - 1536)];
    u16 b = f2bf(v);
    wb[(long)n * 2048 + k] = b;
    we[(long)n * 2048 + k] = f2bf(v - bf2f(b));
  }
}

// ---------------------------------------------------------------------------
// Gather + split embedding rows for all (t,b): xemb[t*64+b][0:512]
// ---------------------------------------------------------------------------
__global__ __launch_bounds__(256) void gather_emb_split(
    const int* __restrict__ caps, const float* __restrict__ emb,
    u16* __restrict__ xb, u16* __restrict__ xe) {
  int r = blockIdx.x;                 // 0..1215
  int b = r & 63, t = r >> 6;
  int word = caps[b * TT + t];
  const float* src = emb + (long)word * ED;
  for (int k = threadIdx.x; k < ED; k += 256) {
    float v = src[k];
    u16 bb = f2bf(v);
    xb[(long)r * ED + k] = bb;
    xe[(long)r * ED + k] = f2bf(v - bf2f(bb));
  }
}

// ---------------------------------------------------------------------------
// Generic fp32 NT GEMM (proj fallback; gates fallback)
// ---------------------------------------------------------------------------
__global__ __launch_bounds__(256) void gemm_nt(
    const float* __restrict__ A, int lda,
    const float* __restrict__ Bw, int ldb,
    const float* __restrict__ bias,
    float* __restrict__ C, long ldc, long zstride,
    int kChunk) {
  __shared__ __align__(16) float As[KT][64];
  __shared__ __align__(16) float Ws[KT][64];
  const int tid = threadIdx.x;
  const int m0 = blockIdx.y * 64, n0 = blockIdx.x * 64;
  const int k0 = blockIdx.z * kChunk, k1 = k0 + kChunk;
  const int tm = tid & 15, tn = tid >> 4;
  const int lr = tid >> 3;
  const int lk = (tid & 7) * 4;
  float acc[4][4] = {};
  for (int kt = k0; kt < k1; kt += KT) {
    __syncthreads();
    #pragma unroll
    for (int p = 0; p < 2; ++p) {
      int m = p * 32 + lr;
      float4 av = *reinterpret_cast<const float4*>(A + (long)(m0 + m) * lda + kt + lk);
      As[lk + 0][m] = av.x; As[lk + 1][m] = av.y;
      As[lk + 2][m] = av.z; As[lk + 3][m] = av.w;
      float4 wv = *reinterpret_cast<const float4*>(Bw + (long)(n0 + m) * ldb + kt + lk);
      Ws[lk + 0][m] = wv.x; Ws[lk + 1][m] = wv.y;
      Ws[lk + 2][m] = wv.z; Ws[lk + 3][m] = wv.w;
    }
    __syncthreads();
    #pragma unroll
    for (int k = 0; k < KT; ++k) {
      float4 a = *reinterpret_cast<const float4*>(&As[k][tm * 4]);
      float4 w = *reinterpret_cast<const float4*>(&Ws[k][tn * 4]);
      acc[0][0] += a.x * w.x; acc[0][1] += a.x * w.y; acc[0][2] += a.x * w.z; acc[0][3] += a.x * w.w;
      acc[1][0] += a.y * w.x; acc[1][1] += a.y * w.y; acc[1][2] += a.y * w.z; acc[1][3] += a.y * w.w;
      acc[2][0] += a.z * w.x; acc[2][1] += a.z * w.y; acc[2][2] += a.z * w.z; acc[2][3] += a.z * w.w;
      acc[3][0] += a.w * w.x; acc[3][1] += a.w * w.y; acc[3][2] += a.w * w.z; acc[3][3] += a.w * w.w;
    }
  }
  float* Cz = C + (long)blockIdx.z * zstride;
  #pragma unroll
  for (int mi = 0; mi < 4; ++mi) {
    int row = m0 + tm * 4 + mi, col = n0 + tn * 4;
    float4 o;
    o.x = acc[mi][0]; o.y = acc[mi][1]; o.z = acc[mi][2]; o.w = acc[mi][3];
    if (bias) {
      o.x += bias[col]; o.y += bias[col + 1]; o.z += bias[col + 2]; o.w += bias[col + 3];
    }
    *reinterpret_cast<float4*>(Cz + (long)row * ldc + col) = o;
  }
}

// ---------------------------------------------------------------------------
// Gates fallback (fp32 vector GEMM) — legacy path only.
// ---------------------------------------------------------------------------
__global__ __launch_bounds__(256) void gemm_gates(
    const float* __restrict__ x,
    const float* __restrict__ Wih,
    const float* __restrict__ Whh,
    float* __restrict__ P) {
  __shared__ __align__(16) float As[KT][64];
  __shared__ __align__(16) float Ws[KT][64];
  const int tid = threadIdx.x;
  const int bz = blockIdx.z;
  const int n0 = blockIdx.x * 64;
  const float* A;
  const float* Bw;
  int ldb, k0;
  if (bz < 6) { A = x;        Bw = Wih; ldb = 1536; k0 = bz * 256; }
  else        { A = x + 1536; Bw = Whh; ldb = 512;  k0 = (bz - 6) * 256; }
  const int k1 = k0 + 256;
  const int tm = tid & 15, tn = tid >> 4;
  const int lr = tid >> 3;
  const int lk = (tid & 7) * 4;
  float acc[4][4] = {};
  for (int kt = k0; kt < k1; kt += KT) {
    __syncthreads();
    #pragma unroll
    for (int p = 0; p < 2; ++p) {
      int m = p * 32 + lr;
      float4 av = *reinterpret_cast<const float4*>(A + (long)m * 2048 + kt + lk);
      As[lk + 0][m] = av.x; As[lk + 1][m] = av.y;
      As[lk + 2][m] = av.z; As[lk + 3][m] = av.w;
      float4 wv = *reinterpret_cast<const float4*>(Bw + (long)(n0 + m) * ldb + kt + lk);
      Ws[lk + 0][m] = wv.x; Ws[lk + 1][m] = wv.y;
      Ws[lk + 2][m] = wv.z; Ws[lk + 3][m] = wv.w;
    }
    __syncthreads();
    #pragma unroll
    for (int k = 0; k < KT; ++k) {
      float4 a = *reinterpret_cast<const float4*>(&As[k][tm * 4]);
      float4 w = *reinterpret_cast<const float4*>(&Ws[k][tn * 4]);
      acc[0][0] += a.x * w.x; acc[0][1] += a.x * w.y; acc[0][2] += a.x * w.z; acc[0][3] += a.x * w.w;
      acc[1][0] += a.y * w.x; acc[1][1] += a.y * w.y; acc[1][2] += a.y * w.z; acc[1][3] += a.y * w.w;
      acc[2][0] += a.z * w.x; acc[2][1] += a.z * w.y; acc[2][2] += a.z * w.z; acc[2][3] += a.z * w.w;
      acc[3][0] += a.w * w.x; acc[3][1] += a.w * w.y; acc[3][2] += a.w * w.z; acc[3][3] += a.w * w.w;
    }
  }
  float* Cz = P + (long)bz * (BB * 2048);
  #pragma unroll
  for (int mi = 0; mi < 4; ++mi) {
    int row = tm * 4 + mi, col = n0 + tn * 4;
    float4 o;
    o.x = acc[mi][0]; o.y = acc[mi][1]; o.z = acc[mi][2]; o.w = acc[mi][3];
    *reinterpret_cast<float4*>(Cz + (long)row * 2048 + col) = o;
  }
}

// ---------------------------------------------------------------------------
// Gates GEMM, split-bf16 MFMA (proven R8).  A row stride 2048, B row stride
// 2048.  Host passes base pointers pre-offset (e.g. +512 cols) and grid.z
// selects the 256-col K chunk.  Output P[z][64][2048].
// ---------------------------------------------------------------------------
__global__ __launch_bounds__(256) void gates_mfma(
    const u16* __restrict__ xb, const u16* __restrict__ xe,
    const u16* __restrict__ wb, const u16* __restrict__ we,
    float* __restrict__ P) {
  __shared__ __align__(16) u16 lds[32768];   // 64 KB
  const int tid = threadIdx.x;
  const int n0 = blockIdx.x * 64;
  const int kz = blockIdx.z * 256;
  const int w = tid >> 6, lane = tid & 63;
  const int frow = lane & 15, fgrp = lane >> 4;
  const int srow = tid >> 3, sslot = tid & 7;
  const int scol = (sslot ^ (srow & 7)) * 8;
  char* L = (char*)lds;

#define GT_STAGE(buf, kc) do {                                                     \
    _Pragma("unroll")                                                              \
    for (int ii = 0; ii < 2; ++ii) {                                               \
      int r_ = ii * 32 + srow;                                                     \
      __builtin_amdgcn_global_load_lds(                                            \
        (const __attribute__((address_space(1))) void*)(xb + (long)r_ * 2048 + (kc) + scol), \
        (__attribute__((address_space(3))) void*)(L + (buf) * 8192 + ii * 4096 + tid * 16), 16, 0, 0); \
      __builtin_amdgcn_global_load_lds(                                            \
        (const __attribute__((address_space(1))) void*)(xe + (long)r_ * 2048 + (kc) + scol), \
        (__attribute__((address_space(3))) void*)(L + 16384 + (buf) * 8192 + ii * 4096 + tid * 16), 16, 0, 0); \
      __builtin_amdgcn_global_load_lds(                                            \
        (const __attribute__((address_space(1))) void*)(wb + (long)(n0 + r_) * 2048 + (kc) + scol), \
        (__attribute__((address_space(3))) void*)(L + 32768 + (buf) * 8192 + ii * 4096 + tid * 16), 16, 0, 0); \
      __builtin_amdgcn_global_load_lds(                                            \
        (const __attribute__((address_space(1))) void*)(we + (long)(n0 + r_) * 2048 + (kc) + scol), \
        (__attribute__((address_space(3))) void*)(L + 49152 + (buf) * 8192 + ii * 4096 + tid * 16), 16, 0, 0); \
    }                                                                              \
  } while (0)

  f32x4 acc[4] = {{0.f,0.f,0.f,0.f},{0.f,0.f,0.f,0.f},{0.f,0.f,0.f,0.f},{0.f,0.f,0.f,0.f}};

  GT_STAGE(0, kz);
  asm volatile("s_waitcnt vmcnt(0)");
  __syncthreads();

  for (int kc = 0; kc < 4; ++kc) {
    const int cur = kc & 1;
    if (kc < 3) GT_STAGE(cur ^ 1, kz + (kc + 1) * 64);
    const char* Ab = L + cur * 8192;
    const char* Ae = L + 16384 + cur * 8192;
    const char* Bb = L + 32768 + cur * 8192;
    const char* Be = L + 49152 + cur * 8192;
    #pragma unroll
    for (int ks = 0; ks < 2; ++ks) {
      const int slot = ((ks * 4 + fgrp) ^ (frow & 7)) * 16;
      const int brow = (w * 16 + frow) * 128 + slot;
      short8v bbf = *reinterpret_cast<const short8v*>(Bb + brow);
      short8v bef = *reinterpret_cast<const short8v*>(Be + brow);
      #pragma unroll
      for (int m = 0; m < 4; ++m) {
        const int arow = (m * 16 + frow) * 128 + slot;
        short8v abf = *reinterpret_cast<const short8v*>(Ab + arow);
        short8v aef = *reinterpret_cast<const short8v*>(Ae + arow);
        acc[m] = __builtin_amdgcn_mfma_f32_16x16x32_bf16(abf, bbf, acc[m], 0, 0, 0);
        acc[m] = __builtin_amdgcn_mfma_f32_16x16x32_bf16(aef, bbf, acc[m], 0, 0, 0);
        acc[m] = __builtin_amdgcn_mfma_f32_16x16x32_bf16(abf, bef, acc[m], 0, 0, 0);
      }
    }
    asm volatile("s_waitcnt vmcnt(0)");
    __syncthreads();
  }

  float* Pz = P + (long)blockIdx.z * (BB * 2048);
  const int col = n0 + w * 16 + frow;
  #pragma unroll
  for (int m = 0; m < 4; ++m)
    #pragma unroll
    for (int r = 0; r < 4; ++r)
      Pz[(long)(m * 16 + fgrp * 4 + r) * 2048 + col] = acc[m][r];
#undef GT_STAGE
}

// ---------------------------------------------------------------------------
// Pemb batched GEMM (split-bf16 MFMA): Pemb[t][b][n] = xemb[t*64+b]·Wg[n][0:512]
// grid (32 n-tiles, 19 t).  A row stride 512, B row stride 2048, K=512.
// ---------------------------------------------------------------------------
__global__ __launch_bounds__(256) void pemb_mfma(
    const u16* __restrict__ xb, const u16* __restrict__ xe,   // [1216][512]
    const u16* __restrict__ wb, const u16* __restrict__ we,   // [2048][2048] (cols 0..511)
    float* __restrict__ Pemb) {                               // [19][64][2048]
  __shared__ __align__(16) u16 lds[32768];
  const int tid = threadIdx.x;
  const int n0 = blockIdx.x * 64;
  const int t  = blockIdx.y;
  const u16* Ab_g = xb + (long)t * 64 * ED;
  const u16* Ae_g = xe + (long)t * 64 * ED;
  const int w = tid >> 6, lane = tid & 63;
  const int frow = lane & 15, fgrp = lane >> 4;
  const int srow = tid >> 3, sslot = tid & 7;
  const int scol = (sslot ^ (srow & 7)) * 8;
  char* L = (char*)lds;

#define PE_STAGE(buf, kc) do {                                                     \
    _Pragma("unroll")                                                              \
    for (int ii = 0; ii < 2; ++ii) {                                               \
      int r_ = ii * 32 + srow;                                                     \
      __builtin_amdgcn_global_load_lds(                                            \
        (const __attribute__((address_space(1))) void*)(Ab_g + (long)r_ * ED + (kc) + scol), \
        (__attribute__((address_space(3))) void*)(L + (buf) * 8192 + ii * 4096 + tid * 16), 16, 0, 0); \
      __builtin_amdgcn_global_load_lds(                                            \
        (const __attribute__((address_space(1))) void*)(Ae_g + (long)r_ * ED + (kc) + scol), \
        (__attribute__((address_space(3))) void*)(L + 16384 + (buf) * 8192 + ii * 4096 + tid * 16), 16, 0, 0); \
      __builtin_amdgcn_global_load_lds(                                            \
        (const __attribute__((address_space(1))) void*)(wb + (long)(n0 + r_) * 2048 + (kc) + scol), \
        (__attribute__((address_space(3))) void*)(L + 32768 + (buf) * 8192 + ii * 4096 + tid * 16), 16, 0, 0); \
      __builtin_amdgcn_global_load_lds(                                            \
        (const __attribute__((address_space(1))) void*)(we + (long)(n0 + r_) * 2048 + (kc) + scol), \
        (__attribute__((address_space(3))) void*)(L + 49152 + (buf) * 8192 + ii * 4096 + tid * 16), 16, 0, 0); \
    }                                                                              \
  } while (0)

  f32x4 acc[4] = {{0.f,0.f,0.f,0.f},{0.f,0.f,0.f,0.f},{0.f,0.f,0.f,0.f},{0.f,0.f,0.f,0.f}};

  PE_STAGE(0, 0);
  asm volatile("s_waitcnt vmcnt(0)");
  __syncthreads();

  for (int kc = 0; kc < 8; ++kc) {
    const int cur = kc & 1;
    if (kc < 7) PE_STAGE(cur ^ 1, (kc + 1) * 64);
    const char* Ab = L + cur * 8192;
    const char* Ae = L + 16384 + cur * 8192;
    const char* Bb = L + 32768 + cur * 8192;
    const char* Be = L + 49152 + cur * 8192;
    #pragma unroll
    for (int ks = 0; ks < 2; ++ks) {
      const int slot = ((ks * 4 + fgrp) ^ (frow & 7)) * 16;
      const int brow = (w * 16 + frow) * 128 + slot;
      short8v bbf = *reinterpret_cast<const short8v*>(Bb + brow);
      short8v bef = *reinterpret_cast<const short8v*>(Be + brow);
      #pragma unroll
      for (int m = 0; m < 4; ++m) {
        const int arow = (m * 16 + frow) * 128 + slot;
        short8v abf = *reinterpret_cast<const short8v*>(Ab + arow);
        short8v aef = *reinterpret_cast<const short8v*>(Ae + arow);
        acc[m] = __builtin_amdgcn_mfma_f32_16x16x32_bf16(abf, bbf, acc[m], 0, 0, 0);
        acc[m] = __builtin_amdgcn_mfma_f32_16x16x32_bf16(aef, bbf, acc[m], 0, 0, 0);
        acc[m] = __builtin_amdgcn_mfma_f32_16x16x32_bf16(abf, bef, acc[m], 0, 0, 0);
      }
    }
    asm volatile("s_waitcnt vmcnt(0)");
    __syncthreads();
  }

  float* Pz = Pemb + (long)t * (BB * 2048);
  const int col = n0 + w * 16 + frow;
  #pragma unroll
  for (int m = 0; m < 4; ++m)
    #pragma unroll
    for (int r = 0; r < 4; ++r)
      Pz[(long)(m * 16 + fgrp * 4 + r) * 2048 + col] = acc[m][r];
#undef PE_STAGE
}

// ---------------------------------------------------------------------------
// proj GEMM, split-bf16 MFMA (proven R9).
// ---------------------------------------------------------------------------
__global__ __launch_bounds__(256) void proj_mfma(
    const u16* __restrict__ eb, const u16* __restrict__ ee,   // [3840][1024]
    const u16* __restrict__ wb, const u16* __restrict__ we,   // [512][1024]
    const float* __restrict__ bias,
    float* __restrict__ proj) {                               // [3840][512]
  __shared__ __align__(16) u16 lds[32768];
  const int tid = threadIdx.x;
  const int n0 = blockIdx.x * 64;
  const int m0 = blockIdx.y * 64;
  const int w = tid >> 6, lane = tid & 63;
  const int frow = lane & 15, fgrp = lane >> 4;
  const int srow = tid >> 3, sslot = tid & 7;
  const int scol = (sslot ^ (srow & 7)) * 8;
  char* L = (char*)lds;

#define PJ_STAGE(buf, kc) do {                                                     \
    _Pragma("unroll")                                                              \
    for (int ii = 0; ii < 2; ++ii) {                                               \
      int r_ = ii * 32 + srow;                                                     \
      __builtin_amdgcn_global_load_lds(                                            \
        (const __attribute__((address_space(1))) void*)(eb + (long)(m0 + r_) * ENCD + (kc) + scol), \
        (__attribute__((address_space(3))) void*)(L + (buf) * 8192 + ii * 4096 + tid * 16), 16, 0, 0); \
      __builtin_amdgcn_global_load_lds(                                            \
        (const __attribute__((address_space(1))) void*)(ee + (long)(m0 + r_) * ENCD + (kc) + scol), \
        (__attribute__((address_space(3))) void*)(L + 16384 + (buf) * 8192 + ii * 4096 + tid * 16), 16, 0, 0); \
      __builtin_amdgcn_global_load_lds(                                            \
        (const __attribute__((address_space(1))) void*)(wb + (long)(n0 + r_) * ENCD + (kc) + scol), \
        (__attribute__((address_space(3))) void*)(L + 32768 + (buf) * 8192 + ii * 4096 + tid * 16), 16, 0, 0); \
      __builtin_amdgcn_global_load_lds(                                            \
        (const __attribute__((address_space(1))) void*)(we + (long)(n0 + r_) * ENCD + (kc) + scol), \
        (__attribute__((address_space(3))) void*)(L + 49152 + (buf) * 8192 + ii * 4096 + tid * 16), 16, 0, 0); \
    }                                                                              \
  } while (0)

  f32x4 acc[4] = {{0.f,0.f,0.f,0.f},{0.f,0.f,0.f,0.f},{0.f,0.f,0.f,0.f},{0.f,0.f,0.f,0.f}};

  PJ_STAGE(0, 0);
  asm volatile("s_waitcnt vmcnt(0)");
  __syncthreads();

  for (int kc = 0; kc < 16; ++kc) {
    const int cur = kc & 1;
    if (kc < 15) PJ_STAGE(cur ^ 1, (kc + 1) * 64);
    const char* Ab = L + cur * 8192;
    const char* Ae = L + 16384 + cur * 8192;
    const char* Bb = L + 32768 + cur * 8192;
    const char* Be = L + 49152 + cur * 8192;
    #pragma unroll
    for (int ks = 0; ks < 2; ++ks) {
      const int slot = ((ks * 4 + fgrp) ^ (frow & 7)) * 16;
      const int brow = (w * 16 + frow) * 128 + slot;
      short8v bbf = *reinterpret_cast<const short8v*>(Bb + brow);
      short8v bef = *reinterpret_cast<const short8v*>(Be + brow);
      #pragma unroll
      for (int m = 0; m < 4; ++m) {
        const int arow = (m * 16 + frow) * 128 + slot;
        short8v abf = *reinterpret_cast<const short8v*>(Ab + arow);
        short8v aef = *reinterpret_cast<const short8v*>(Ae + arow);
        acc[m] = __builtin_amdgcn_mfma_f32_16x16x32_bf16(abf, bbf, acc[m], 0, 0, 0);
        acc[m] = __builtin_amdgcn_mfma_f32_16x16x32_bf16(aef, bbf, acc[m], 0, 0, 0);
        acc[m] = __builtin_amdgcn_mfma_f32_16x16x32_bf16(abf, bef, acc[m], 0, 0, 0);
      }
    }
    asm volatile("s_waitcnt vmcnt(0)");
    __syncthreads();
  }

  const int col = n0 + w * 16 + frow;
  const float bv = bias[col];
  #pragma unroll
  for (int m = 0; m < 4; ++m)
    #pragma unroll
    for (int r = 0; r < 4; ++r)
      proj[(long)(m0 + m * 16 + fgrp * 4 + r) * HD + col] = acc[m][r] + bv;
#undef PJ_STAGE
}

// ---------------------------------------------------------------------------
// fc GEMM, m97-style (proven R7).
// ---------------------------------------------------------------------------
__global__ __launch_bounds__(256) void fc_tiled(
    const u16* __restrict__ hbuf, const u16* __restrict__ Wb,
    const float* __restrict__ bias, float* __restrict__ out) {
  __shared__ __align__(16) u16 lds[40960];   // 80 KB
  const int tid = threadIdx.x;
  const int bid = blockIdx.x;
  const int xcd = bid & 7, loc = bid >> 3;
  const int wg = (xcd < 7) ? (xcd * 297 + loc) : (2079 + loc);
  const int n_tile = wg / 19, t = wg - n_tile * 19;
  const int n0 = n_tile * 256;

  const u16* Ab = hbuf + (long)t * (BB * HD);
  const u16* Wbase = Wb + (long)n0 * HD;

  const int w = tid >> 6, lane = tid & 63;
  const int frow = lane & 15, fgrp = lane >> 4;
  const int srow = tid >> 3, sslot = tid & 7;
  const int scol = (sslot ^ (srow & 7)) * 8;
  char* ldsb = (char*)lds;

#define FC_STAGE(buf, kc) do {                                                    \
    _Pragma("unroll")                                                             \
    for (int ii = 0; ii < 2; ++ii) {                                              \
      __builtin_amdgcn_global_load_lds(                                           \
        (const __attribute__((address_space(1))) void*)(Ab + (ii * 32 + srow) * HD + (kc) + scol), \
        (__attribute__((address_space(3))) void*)(ldsb + (buf) * 8192 + ii * 4096 + tid * 16), \
        16, 0, 0);                                                                \
    }                                                                             \
    _Pragma("unroll")                                                             \
    for (int ii = 0; ii < 8; ++ii) {                                              \
      __builtin_amdgcn_global_load_lds(                                           \
        (const __attribute__((address_space(1))) void*)(Wbase + (long)(ii * 32 + srow) * HD + (kc) + scol), \
        (__attribute__((address_space(3))) void*)(ldsb + 16384 + (buf) * 32768 + ii * 4096 + tid * 16), \
        16, 0, 0);                                                                \
    }                                                                             \
  } while (0)

  f32x4 acc[4][4] = {};

  FC_STAGE(0, 0);
  asm volatile("s_waitcnt vmcnt(0)");
  __syncthreads();

  for (int kc = 0; kc < 8; ++kc) {
    const int cur = kc & 1;
    if (kc < 7) FC_STAGE(cur ^ 1, (kc + 1) * 64);
    const char* Abuf = ldsb + cur * 8192;
    const char* Wbuf = ldsb + 16384 + cur * 32768;
    #pragma unroll
    for (int ks = 0; ks < 2; ++ks) {
      const int slot = ((ks * 4 + fgrp) ^ (frow & 7)) * 16;
      short8v af[4], wf[4];
      #pragma unroll
      for (int m = 0; m < 4; ++m)
        af[m] = *reinterpret_cast<const short8v*>(Abuf + (m * 16 + frow) * 128 + slot);
      #pragma unroll
      for (int n = 0; n < 4; ++n)
        wf[n] = *reinterpret_cast<const short8v*>(Wbuf + (w * 64 + n * 16 + frow) * 128 + slot);
      #pragma unroll
      for (int m = 0; m < 4; ++m)
        #pragma unroll
        for (int n = 0; n < 4; ++n)
          acc[m][n] = __builtin_amdgcn_mfma_f32_16x16x32_bf16(af[m], wf[n], acc[m][n], 0, 0, 0);
    }
    asm volatile("s_waitcnt vmcnt(0)");
    __syncthreads();
  }

  #pragma unroll
  for (int n = 0; n < 4; ++n) {
    const int col = n0 + w * 64 + n * 16 + frow;
    const float bv = bias[col];
    #pragma unroll
    for (int m = 0; m < 4; ++m) {
      #pragma unroll
      for (int r = 0; r < 4; ++r) {
        int b = m * 16 + fgrp * 4 + r;
        out[((long)b * TT + (t + 1)) * VD + col] = acc[m][n][r] + bv;
      }
    }
  }
#undef FC_STAGE
}

// ---------------------------------------------------------------------------
// fc fallback (per-step) — legacy path only.
// ---------------------------------------------------------------------------
__global__ __launch_bounds__(256) void fc_mfma_f32w(
    const u16* __restrict__ hb, const float* __restrict__ Wf,
    const float* __restrict__ bias, float* __restrict__ outp) {
  const int tid = threadIdx.x;
  const int n0 = blockIdx.x * 64;
  const int wv = tid >> 6, lane = tid & 63;
  const int frow = lane & 15, fgrp = lane >> 4;
  const float* Wrow = Wf + (long)(n0 + wv * 16 + frow) * HD;
  const u16*   Arow = hb + frow * HD;
  f32x4 acc[4] = {{0.f,0.f,0.f,0.f},{0.f,0.f,0.f,0.f},{0.f,0.f,0.f,0.f},{0.f,0.f,0.f,0.f}};
  #pragma unroll 2
  for (int ks = 0; ks < 16; ++ks) {
    const int k0 = ks * 32 + fgrp * 8;
    float4 w0 = *reinterpret_cast<const float4*>(Wrow + k0);
    float4 w1 = *reinterpret_cast<const float4*>(Wrow + k0 + 4);
    union { short8v v; u16 s[8]; } bf;
    bf.s[0] = f2bf(w0.x); bf.s[1] = f2bf(w0.y); bf.s[2] = f2bf(w0.z); bf.s[3] = f2bf(w0.w);
    bf.s[4] = f2bf(w1.x); bf.s[5] = f2bf(w1.y); bf.s[6] = f2bf(w1.z); bf.s[7] = f2bf(w1.w);
    #pragma unroll
    for (int m = 0; m < 4; ++m) {
      short8v afr = *reinterpret_cast<const short8v*>(Arow + m * 16 * HD + k0);
      acc[m] = __builtin_amdgcn_mfma_f32_16x16x32_bf16(afr, bf.v, acc[m], 0, 0, 0);
    }
  }
  const int col = n0 + wv * 16 + frow;
  const float bv = bias[col];
  #pragma unroll
  for (int m = 0; m < 4; ++m)
    #pragma unroll
    for (int r = 0; r < 4; ++r)
      outp[(long)(m * 16 + fgrp * 4 + r) * ((long)TT * VD) + col] = acc[m][r] + bv;
}

// ---------------------------------------------------------------------------
// v2 fused step kernel.  grid (64 b, 4 seg), 512 thr.
// All segs: LSTM(t-1) [redundant, reads c_in, 6 P partials + Pemb_prev],
// scores+softmax [redundant].  seg0 writes c_out/hbuf/attn/xs-h.
// Each seg: ctx for its 256 ENCD cols -> xs ctx split.
// ---------------------------------------------------------------------------
__global__ __launch_bounds__(512) void fused_attn_lstm2(
    const float* __restrict__ proj, const float* __restrict__ enc,
    int t,
    const float* __restrict__ P,          // [6][64][2048]
    const float* __restrict__ Pemb_prev,  // [64][2048] (t>0)
    const float* __restrict__ b_ih, const float* __restrict__ b_hh,
    const float* __restrict__ c_in, float* __restrict__ c_out,
    u16* __restrict__ hbuf_prev,
    float* __restrict__ attn_out,
    u16* __restrict__ xs_bf, u16* __restrict__ xs_er) {
  int b = blockIdx.x, seg = blockIdx.y;
  __shared__ float sh[HD];
  __shared__ float sc[64];
  __shared__ float sw[64];
  int tid = threadIdx.x;
  if (t > 0) {
    int u = tid;
    const float* pe = Pemb_prev + (long)b * 2048;
    float gi = b_ih[u]        + b_hh[u]        + pe[u];
    float gf = b_ih[u + 512]  + b_hh[u + 512]  + pe[u + 512];
    float gg = b_ih[u + 1024] + b_hh[u + 1024] + pe[u + 1024];
    float go = b_ih[u + 1536] + b_hh[u + 1536] + pe[u + 1536];
    #pragma unroll
    for (int ks = 0; ks < 6; ++ks) {
      const float* p = P + ((long)ks * BB + b) * 2048;
      gi += p[u]; gf += p[u + 512]; gg += p[u + 1024]; go += p[u + 1536];
    }
    float si = 1.f / (1.f + __expf(-gi));
    float sf = 1.f / (1.f + __expf(-gf));
    float so = 1.f / (1.f + __expf(-go));
    float tg = tanhf(gg);
    float c2 = sf * c_in[b * HD + u] + si * tg;
    float h2 = so * tanhf(c2);
    sh[u] = h2;
    if (seg == 0) {
      c_out[b * HD + u] = c2;
      u16 hb16 = f2bf(h2);
      hbuf_prev[b * HD + u] = hb16;
      xs_bf[(long)b * 2048 + 1536 + u] = hb16;
      xs_er[(long)b * 2048 + 1536 + u] = f2bf(h2 - bf2f(hb16));
    }
  } else {
    sh[tid] = 0.f;
    if (seg == 0) {
      xs_bf[(long)b * 2048 + 1536 + tid] = 0;
      xs_er[(long)b * 2048 + 1536 + tid] = 0;
    }
  }
  __syncthreads();
  int wave = tid >> 6, lane = tid & 63;
  for (int s = wave; s < SS; s += 8) {
    const float* pr = proj + ((long)b * SS + s) * HD;
    float acc = 0.f;
    #pragma unroll
    for (int k = 0; k < HD / 64; ++k) acc += pr[lane + k * 64] * sh[lane + k * 64];
    #pragma unroll
    for (int off = 32; off; off >>= 1) acc += __shfl_down(acc, off);
    if (lane == 0) sc[s] = acc;
  }
  __syncthreads();
  if (wave == 0) {
    float v = (lane < SS) ? sc[lane] : -INFINITY;
    float m = v;
    #pragma unroll
    for (int off = 32; off; off >>= 1) m = fmaxf(m, __shfl_down(m, off));
    m = __shfl(m, 0);
    float e = (lane < SS) ? __expf(v - m) : 0.f;
    float sum = e;
    #pragma unroll
    for (int off = 32; off; off >>= 1) sum += __shfl_down(sum, off);
    sum = __shfl(sum, 0);
    float wv = e / sum;
    if (lane < SS) {
      sw[lane] = wv;
      if (seg == 0) attn_out[b * SS + lane] = wv;
    }
  }
  __syncthreads();
  if (tid < 256) {
    int e0 = (seg << 8) + tid;
    float acc = 0.f;
    const float* ebp = enc + (long)b * SS * ENCD + e0;
    #pragma unroll
    for (int s = 0; s < SS; ++s) acc += sw[s] * ebp[(long)s * ENCD];
    u16 bb = f2bf(acc);
    xs_bf[(long)b * 2048 + 512 + e0] = bb;
    xs_er[(long)b * 2048 + 512 + e0] = f2bf(acc - bf2f(bb));
  }
}

// ---------------------------------------------------------------------------
// v2 final LSTM (step 18): 6 partials + Pemb[18] + biases -> hbuf[18]
// ---------------------------------------------------------------------------
__global__ __launch_bounds__(256) void lstm_final2(
    const float* __restrict__ P, const float* __restrict__ Pemb18,
    const float* __restrict__ b_ih, const float* __restrict__ b_hh,
    const float* __restrict__ c_in, u16* __restrict__ hb) {
  int idx = blockIdx.x * 256 + threadIdx.x;
  int b = idx >> 9, u = idx & 511;
  const float* pe = Pemb18 + (long)b * 2048;
  float gi = b_ih[u]        + b_hh[u]        + pe[u];
  float gf = b_ih[u + 512]  + b_hh[u + 512]  + pe[u + 512];
  float gg = b_ih[u + 1024] + b_hh[u + 1024] + pe[u + 1024];
  float go = b_ih[u + 1536] + b_hh[u + 1536] + pe[u + 1536];
  #pragma unroll
  for (int ks = 0; ks < 6; ++ks) {
    const float* p = P + ((long)ks * BB + b) * 2048;
    gi += p[u]; gf += p[u + 512]; gg += p[u + 1024]; go += p[u + 1536];
  }
  float si = 1.f / (1.f + __expf(-gi));
  float sf = 1.f / (1.f + __expf(-gf));
  float so = 1.f / (1.f + __expf(-go));
  float tg = tanhf(gg);
  float c2 = sf * c_in[idx] + si * tg;
  float h2 = so * tanhf(c2);
  hb[idx] = f2bf(h2);
}

// ---------------------------------------------------------------------------
// Legacy fused kernel (fallback path only, unchanged from R9)
// ---------------------------------------------------------------------------
__global__ __launch_bounds__(512) void fused_attn_lstm(
    const float* __restrict__ proj, const float* __restrict__ enc,
    const float* __restrict__ emb, const int* __restrict__ caps, int t,
    const float* __restrict__ P, const float* __restrict__ b_ih,
    const float* __restrict__ b_hh, float* __restrict__ c,
    u16* __restrict__ hbuf_prev,
    float* __restrict__ attn_out, float* __restrict__ x,
    u16* __restrict__ xs_bf, u16* __restrict__ xs_er) {
  int b = blockIdx.x;
  __shared__ float sh[HD];
  __shared__ float sc[64];
  __shared__ float sw[64];
  int tid = threadIdx.x;
  if (t > 0) {
    int u = tid;
    float gi = b_ih[u]        + b_hh[u];
    float gf = b_ih[u + 512]  + b_hh[u + 512];
    float gg = b_ih[u + 1024] + b_hh[u + 1024];
    float go = b_ih[u + 1536] + b_hh[u + 1536];
    #pragma unroll
    for (int ks = 0; ks < 8; ++ks) {
      const float* p = P + ((long)ks * BB + b) * 2048;
      gi += p[u]; gf += p[u + 512]; gg += p[u + 1024]; go += p[u + 1536];
    }
    float si = 1.f / (1.f + __expf(-gi));
    float sf = 1.f / (1.f + __expf(-gf));
    float so = 1.f / (1.f + __expf(-go));
    float tg = tanhf(gg);
    float c2 = sf * c[b * HD + u] + si * tg;
    float h2 = so * tanhf(c2);
    c[b * HD + u] = c2;
    sh[u] = h2;
    hbuf_prev[b * HD + u] = f2bf(h2);
  } else {
    sh[tid] = 0.f;
  }
  __syncthreads();
  int wave = tid >> 6, lane = tid & 63;
  for (int s = wave; s < SS; s += 8) {
    const float* pr = proj + ((long)b * SS + s) * HD;
    float acc = 0.f;
    #pragma unroll
    for (int k = 0; k < HD / 64; ++k) acc += pr[lane + k * 64] * sh[lane + k * 64];
    #pragma unroll
    for (int off = 32; off; off >>= 1) acc += __shfl_down(acc, off);
    if (lane == 0) sc[s] = acc;
  }
  __syncthreads();
  if (wave == 0) {
    float v = (lane < SS) ? sc[lane] : -INFINITY;
    float m = v;
    #pragma unroll
    for (int off = 32; off; off >>= 1) m = fmaxf(m, __shfl_down(m, off));
    m = __shfl(m, 0);
    float e = (lane < SS) ? __expf(v - m) : 0.f;
    float sum = e;
    #pragma unroll
    for (int off = 32; off; off >>= 1) sum += __shfl_down(sum, off);
    sum = __shfl(sum, 0);
    float wv = e / sum;
    if (lane < SS) { sw[lane] = wv; attn_out[b * SS + lane] = wv; }
  }
  __syncthreads();
  float* xb = x + (long)b * 2048;
  u16* sb = xs_bf ? xs_bf + (long)b * 2048 : nullptr;
  u16* se = xs_er ? xs_er + (long)b * 2048 : nullptr;
  for (int e0 = tid; e0 < ENCD; e0 += 512) {
    float acc = 0.f;
    const float* ebp = enc + (long)b * SS * ENCD + e0;
    #pragma unroll
    for (int s = 0; s < SS; ++s) acc += sw[s] * ebp[(long)s * ENCD];
    xb[ED + e0] = acc;
    if (sb) {
      u16 bb = f2bf(acc);
      sb[ED + e0] = bb;
      se[ED + e0] = f2bf(acc - bf2f(bb));
    }
  }
  int word = caps[b * TT + t];
  float ev = emb[(long)word * ED + tid];
  float hv = sh[tid];
  xb[tid] = ev;
  xb[1536 + tid] = hv;
  if (sb) {
    u16 eb16 = f2bf(ev);
    sb[tid] = eb16;
    se[tid] = f2bf(ev - bf2f(eb16));
    u16 hb16 = f2bf(hv);
    sb[1536 + tid] = hb16;
    se[1536 + tid] = f2bf(hv - bf2f(hb16));
  }
}

// ---------------------------------------------------------------------------
// Legacy LSTM pointwise (fallback path)
// ---------------------------------------------------------------------------
__global__ __launch_bounds__(256) void lstm_pointwise(
    const float* __restrict__ P, const float* __restrict__ b_ih,
    const float* __restrict__ b_hh, float* __restrict__ h,
    float* __restrict__ c, u16* __restrict__ hb) {
  int idx = blockIdx.x * 256 + threadIdx.x;
  int b = idx >> 9, u = idx & 511;
  float gi = b_ih[u]        + b_hh[u];
  float gf = b_ih[u + 512]  + b_hh[u + 512];
  float gg = b_ih[u + 1024] + b_hh[u + 1024];
  float go = b_ih[u + 1536] + b_hh[u + 1536];
  #pragma unroll
  for (int ks = 0; ks < 8; ++ks) {
    const float* p = P + ((long)ks * BB + b) * 2048;
    gi += p[u]; gf += p[u + 512]; gg += p[u + 1024]; go += p[u + 1536];
  }
  float si = 1.f / (1.f + __expf(-gi));
  float sf = 1.f / (1.f + __expf(-gf));
  float so = 1.f / (1.f + __expf(-go));
  float tg = tanhf(gg);
  float c2 = sf * c[idx] + si * tg;
  float h2 = so * tanhf(c2);
  c[idx] = c2;
  h[idx] = h2;
  hb[idx] = f2bf(h2);
}

// ---------------------------------------------------------------------------
extern "C" void kernel_launch(void* const* d_in, const int* in_sizes, int n_in,
                              void* d_out_, int out_size, void* d_ws, size_t ws_size,
                              hipStream_t stream) {
  const float* enc   = (const float*)d_in[0];
  const int*   caps  = (const int*)d_in[1];
  const float* emb   = (const float*)d_in[2];
  const float* attnW = (const float*)d_in[3];
  const float* attnB = (const float*)d_in[4];
  const float* W_ih  = (const float*)d_in[5];
  const float* W_hh  = (const float*)d_in[6];
  const float* b_ih  = (const float*)d_in[7];
  const float* b_hh  = (const float*)d_in[8];
  const float* fcW   = (const float*)d_in[9];
  const float* fcb   = (const float*)d_in[10];

  float* out   = (float*)d_out_;                       // [B][T][V]
  float* attns = out + (long)BB * TT * VD;             // [T-1][B][S]

  // workspace layout (floats / u16)
  float* ws    = (float*)d_ws;
  float* proj  = ws;                                   // [3840][512]
  float* h     = proj + (long)BB * SS * HD;
  float* c     = h + BB * HD;                          // cbuf[0]
  float* x     = c + BB * HD;                          // [64][2048] (legacy)
  float* P     = x + BB * 2048;                        // [8][64][2048]
  u16*   hbuf  = (u16*)(P + (long)8 * BB * 2048);      // [19][64][512]
  u16*   Wbf   = hbuf + (long)(TT - 1) * BB * HD;      // [V][H]
  u16*   xs_bf = Wbf + (long)VD * HD;                  // [64][2048]
  u16*   xs_er = xs_bf + (long)BB * 2048;              // [64][2048]
  u16*   Wg_bf = xs_er + (long)BB * 2048;              // [2048][2048]
  u16*   Wg_er = Wg_bf + (long)2048 * 2048;            // [2048][2048]
  u16*   enc_bf = Wg_er + (long)2048 * 2048;           // [3840][1024]
  u16*   enc_er = enc_bf + (long)BB * SS * ENCD;       // [3840][1024]
  u16*   aW_bf  = enc_er + (long)BB * SS * ENCD;       // [512][1024]
  u16*   aW_er  = aW_bf + (long)HD * ENCD;             // [512][1024]
  // v2 region (aligned up to 16B)
  uintptr_t p9 = (uintptr_t)(aW_er + (long)HD * ENCD);
  p9 = (p9 + 15) & ~(uintptr_t)15;
  float* cbuf1   = (float*)p9;                         // [64][512]
  u16*   xemb_bf = (u16*)(cbuf1 + BB * HD);            // [1216][512]
  u16*   xemb_er = xemb_bf + (long)(TT - 1) * BB * ED; // [1216][512]
  uintptr_t pA = (uintptr_t)(xemb_er + (long)(TT - 1) * BB * ED);
  pA = (pA + 15) & ~(uintptr_t)15;
  float* Pemb = (float*)pA;                            // [19][64][2048]
  size_t need1 = (size_t)((char*)xs_bf - (char*)d_ws);
  size_t need2 = (size_t)((char*)enc_bf - (char*)d_ws);
  size_t need3 = (size_t)((char*)(aW_er + (long)HD * ENCD) - (char*)d_ws);
  size_t need4 = (size_t)((char*)(Pemb + (long)(TT - 1) * BB * 2048) - (char*)d_ws);
  const bool use_wbf    = (ws_size >= need1);
  const bool use_split  = (ws_size >= need2);
  const bool use_psplit = (ws_size >= need3);
  const bool use_v2     = (ws_size >= need4);          // observed ws ~656 MB >> need4

  init_kernel<<<(BB * VD + 255) / 256, 256, 0, stream>>>(out, h, c);

  if (use_wbf) {
    long n = (long)VD * HD;
    convert_bf16_k<<<(int)(n / 2048), 256, 0, stream>>>(fcW, Wbf, n);
  }
  if (use_split) {
    split_wg_k<<<2048, 256, 0, stream>>>(W_ih, W_hh, Wg_bf, Wg_er);
  }

  if (use_psplit) {
    long ne = (long)BB * SS * ENCD;
    split_pair_k<<<(int)(ne / 2048), 256, 0, stream>>>(enc, enc_bf, enc_er, ne);
    long nw = (long)HD * ENCD;
    split_pair_k<<<(int)(nw / 2048), 256, 0, stream>>>(attnW, aW_bf, aW_er, nw);
    proj_mfma<<<dim3(8, 60), 256, 0, stream>>>(enc_bf, enc_er, aW_bf, aW_er,
                                               attnB, proj);
  } else {
    gemm_nt<<<dim3(8, 60, 1), 256, 0, stream>>>(enc, ENCD, attnW, ENCD, attnB,
                                                proj, HD, 0, ENCD);
  }

  if (use_v2) {
    // Precompute emb contribution for all steps: Pemb[t] = xemb[t]·Wg[:, :512]^T
    gather_emb_split<<<(TT - 1) * BB, 256, 0, stream>>>(caps, emb, xemb_bf, xemb_er);
    pemb_mfma<<<dim3(32, TT - 1), 256, 0, stream>>>(xemb_bf, xemb_er, Wg_bf, Wg_er,
                                                    Pemb);
    for (int t = 0; t < TT - 1; ++t) {
      // lstm inside kernel t is step s=t-1: c_in = cbuf[(t-1)&1], c_out = cbuf[t&1]
      const float* c_in = ((t - 1) & 1) ? cbuf1 : c;
      float* c_out = (t & 1) ? cbuf1 : c;
      u16* hbp = hbuf + (long)(t > 0 ? t - 1 : 0) * BB * HD;
      fused_attn_lstm2<<<dim3(BB, 4), 512, 0, stream>>>(
          proj, enc, t, P,
          Pemb + (long)(t > 0 ? t - 1 : 0) * BB * 2048,
          b_ih, b_hh, c_in, c_out, hbp,
          attns + (long)t * BB * SS, xs_bf, xs_er);
      // gates over [ctx|h] = cols 512..2047, K=1536 in 6 chunks
      gates_mfma<<<dim3(32, 1, 6), 256, 0, stream>>>(
          xs_bf + 512, xs_er + 512, Wg_bf + 512, Wg_er + 512, P);
    }
    // final LSTM (s=18): c_in = cbuf[0] = c
    lstm_final2<<<128, 256, 0, stream>>>(P, Pemb + (long)18 * BB * 2048,
                                         b_ih, b_hh, c,
                                         hbuf + (long)(TT - 2) * BB * HD);
  } else {
    for (int t = 0; t < TT - 1; ++t) {
      u16* hbp = hbuf + (long)(t > 0 ? t - 1 : 0) * BB * HD;
      fused_attn_lstm<<<BB, 512, 0, stream>>>(proj, enc, emb, caps, t,
                                              P, b_ih, b_hh, c, hbp,
                                              attns + (long)t * BB * SS, x,
                                              use_split ? xs_bf : nullptr,
                                              use_split ? xs_er : nullptr);
      if (use_split) {
        gates_mfma<<<dim3(32, 1, 8), 256, 0, stream>>>(xs_bf, xs_er, Wg_bf, Wg_er, P);
      } else {
        gemm_gates<<<dim3(32, 1, 8), 256, 0, stream>>>(x, W_ih, W_hh, P);
      }
    }
    lstm_pointwise<<<128, 256, 0, stream>>>(P, b_ih, b_hh, h, c,
                                            hbuf + (long)(TT - 2) * BB * HD);
  }

  if (use_wbf) {
    fc_tiled<<<125 * 19, 256, 0, stream>>>(hbuf, Wbf, fcb, out);
  } else {
    for (int t = 0; t < TT - 1; ++t)
      fc_mfma_f32w<<<VD / 64, 256, 0, stream>>>(hbuf + (long)t * BB * HD, fcW, fcb,
                                                out + (long)(t + 1) * VD);
  }
}